// Round 1
// baseline (165.180 us; speedup 1.0000x reference)
//
#include <hip/hip_runtime.h>
#include <math.h>

#define BB 16
#define LL 4096
#define CC 64
#define HD 128

__constant__ float c_lo[8] = {
    -0.010597401784997278f, 0.032883011666982945f, 0.030841381835986965f,
    -0.18703481171888114f, -0.02798376941698385f, 0.6308807679295904f,
    0.7148465705525415f, 0.23037781330885523f};
__constant__ float c_hi[8] = {
    -0.23037781330885523f, 0.7148465705525415f, -0.6308807679295904f,
    -0.02798376941698385f, 0.18703481171888114f, 0.030841381835986965f,
    -0.032883011666982945f, -0.010597401784997278f};

__device__ __forceinline__ float gelu_exact(float x) {
    return 0.5f * x * (1.0f + erff(x * 0.70710678118654752440f));
}

// ---------------- tiny precompute kernels ----------------

__global__ void transpose_w_kernel(const float* __restrict__ W, float* __restrict__ WT) {
    int i = blockIdx.x * 256 + threadIdx.x;   // 16384 total
    int h = i >> 7, g = i & 127;
    WT[i] = W[g * HD + h];                    // WT[h][g] = W[g][h]
}

__global__ void film_kernel(const float* __restrict__ flow, const float* __restrict__ Wgb,
                            const float* __restrict__ bgb, const float* __restrict__ Wg,
                            const float* __restrict__ bg, float* __restrict__ film_ws,
                            float* __restrict__ gate_ws) {
    int bf = blockIdx.x;          // b*4 + f
    int f = bf & 3;
    int b = bf >> 2;
    int row = threadIdx.x;        // 0..255 : rows of gb (gamma 0..127, beta 128..255)
    const float* fl = flow + b * 24;
    const float* wrow = Wgb + ((size_t)(f * 256 + row)) * 24;
    float acc = bgb[f * 256 + row];
#pragma unroll
    for (int j = 0; j < 24; ++j) acc = fmaf(wrow[j], fl[j], acc);
    film_ws[(size_t)bf * 256 + row] = acc;
    if (row == 0) {
        float g = bg[f];
#pragma unroll
        for (int j = 0; j < 24; ++j) g = fmaf(Wg[f * 24 + j], fl[j], g);
        gate_ws[bf] = 1.0f / (1.0f + expf(-g));
    }
}

__global__ void denom_kernel(const float* __restrict__ mask, float* __restrict__ denom) {
    int b = blockIdx.x, tid = threadIdx.x;
    __shared__ float red[256];
    float s = 0.f;
    for (int i = tid; i < LL; i += 256) s += mask[(size_t)b * LL + i];
    red[tid] = s; __syncthreads();
    for (int st = 128; st > 0; st >>= 1) {
        if (tid < st) red[tid] += red[tid + st];
        __syncthreads();
    }
    if (tid == 0) denom[b] = fmaxf(red[0], 1.0f);
}

// ---------------- z projection: z[b][h][l] = mask*(W_in @ x) + b_in ----------------

__global__ __launch_bounds__(256) void zproj_kernel(const float* __restrict__ x,
                                                    const float* __restrict__ mask,
                                                    const float* __restrict__ W_in,
                                                    const float* __restrict__ b_in,
                                                    float* __restrict__ z) {
    __shared__ float Wl[HD * CC];       // [h][c], broadcast reads
    __shared__ float xt[64][CC + 1];    // padded, per-lane row reads
    int blk = blockIdx.x;
    int b = blk >> 6;
    int l0 = (blk & 63) << 6;
    int tid = threadIdx.x;
    for (int i = tid; i < HD * CC; i += 256) Wl[i] = W_in[i];
    for (int i = tid; i < 64 * CC; i += 256) {
        int ll = i >> 6, c = i & 63;
        float mk = mask[(size_t)b * LL + l0 + ll];
        xt[ll][c] = x[((size_t)b * LL + l0 + ll) * CC + c] * mk;
    }
    __syncthreads();
    int ll = tid & 63;
    int hg = tid >> 6;
    for (int h = hg; h < HD; h += 4) {
        const float* wr = &Wl[h * CC];
        const float* xr = &xt[ll][0];
        float a0 = 0.f, a1 = 0.f, a2 = 0.f, a3 = 0.f;
#pragma unroll
        for (int c = 0; c < CC; c += 4) {
            a0 = fmaf(wr[c + 0], xr[c + 0], a0);
            a1 = fmaf(wr[c + 1], xr[c + 1], a1);
            a2 = fmaf(wr[c + 2], xr[c + 2], a2);
            a3 = fmaf(wr[c + 3], xr[c + 3], a3);
        }
        z[((size_t)b * HD + h) * LL + l0 + ll] = (a0 + a1) + (a2 + a3) + b_in[h];
    }
}

// ---------------- per-row wavelet: decompose + FiLM + soft-threshold + reconstruct ----------------
// one block per (b,h) row; writes s = z + z_rec in place; writes lam per band.

__global__ __launch_bounds__(256) void wavelet_kernel(float* __restrict__ z,
                                                      const float* __restrict__ film_ws,
                                                      const float* __restrict__ gate_ws,
                                                      const float* __restrict__ lam_raw,
                                                      float* __restrict__ lam_ws) {
    __shared__ float zrow[4096];
    __shared__ float d1[2048];
    __shared__ float d2[1024];
    __shared__ float d3[512];
    __shared__ float Aq[2048];   // ping (approx1, then approx3 in [0:512], then recon 2048)
    __shared__ float Bq[1024];   // pong (approx2, then recon 1024)
    __shared__ float red[256];

    int blk = blockIdx.x;
    int b = blk >> 7;
    int h = blk & 127;
    int tid = threadIdx.x;
    float* zg = z + ((size_t)b * HD + h) * LL;

    for (int i = tid; i < 4096; i += 256) zrow[i] = zg[i];
    __syncthreads();

    // level 1: zrow[4096] -> Aq[2048] (lo), d1[2048] (hi)
    for (int n = tid; n < 2048; n += 256) {
        float lo = 0.f, hi = 0.f;
#pragma unroll
        for (int k = 0; k < 8; ++k) {
            float v = zrow[(2 * n + k) & 4095];
            lo = fmaf(c_lo[k], v, lo);
            hi = fmaf(c_hi[k], v, hi);
        }
        Aq[n] = lo; d1[n] = hi;
    }
    __syncthreads();
    // level 2: Aq[2048] -> Bq[1024], d2[1024]
    for (int n = tid; n < 1024; n += 256) {
        float lo = 0.f, hi = 0.f;
#pragma unroll
        for (int k = 0; k < 8; ++k) {
            float v = Aq[(2 * n + k) & 2047];
            lo = fmaf(c_lo[k], v, lo);
            hi = fmaf(c_hi[k], v, hi);
        }
        Bq[n] = lo; d2[n] = hi;
    }
    __syncthreads();
    // level 3: Bq[1024] -> Aq[0:512] (approx3), d3[512]
    for (int n = tid; n < 512; n += 256) {
        float lo = 0.f, hi = 0.f;
#pragma unroll
        for (int k = 0; k < 8; ++k) {
            float v = Bq[(2 * n + k) & 1023];
            lo = fmaf(c_lo[k], v, lo);
            hi = fmaf(c_hi[k], v, hi);
        }
        Aq[n] = lo; d3[n] = hi;
    }
    __syncthreads();

    // bands: 0=approx3 (Aq,512), 1=d1(2048), 2=d2(1024), 3=d3(512); film/lam index == band
#pragma unroll
    for (int band = 0; band < 4; ++band) {
        float* arr = (band == 0) ? Aq : (band == 1) ? d1 : (band == 2) ? d2 : d3;
        int len = (band == 0) ? 512 : (band == 1) ? 2048 : (band == 2) ? 1024 : 512;
        float ga = film_ws[((size_t)(b * 4 + band)) * 256 + h];
        float be = film_ws[((size_t)(b * 4 + band)) * 256 + 128 + h];
        float gt = gate_ws[b * 4 + band];
        float sc = 1.0f + gt * ga;
        float sh = gt * be;
        float local = 0.f;
        for (int i = tid; i < len; i += 256) {
            float v = fmaf(arr[i], sc, sh);
            arr[i] = v;
            local += fabsf(v);
        }
        red[tid] = local; __syncthreads();
        for (int st = 128; st > 0; st >>= 1) {
            if (tid < st) red[tid] += red[tid + st];
            __syncthreads();
        }
        float lam = log1pf(expf(lam_raw[band])) * (red[0] / (float)len);
        if (tid == 0) lam_ws[((size_t)(b * 4 + band)) * 128 + h] = lam;
        __syncthreads();
        for (int i = tid; i < len; i += 256) {
            float v = arr[i];
            float av = fabsf(v) - lam;
            arr[i] = (av > 0.f) ? copysignf(av, v) : 0.f;
        }
        __syncthreads();
    }

    // recon step 1: Aq[0:512] (approx_t) + d3 -> Bq[0:1024]
    for (int i = tid; i < 1024; i += 256) {
        int par = i & 1;
        float s = 0.f;
#pragma unroll
        for (int j = 0; j < 4; ++j) {
            int k = 2 * j + par;
            int idx = ((i - k) & 1023) >> 1;
            s = fmaf(c_lo[k], Aq[idx], s);
            s = fmaf(c_hi[k], d3[idx], s);
        }
        Bq[i] = s;
    }
    __syncthreads();
    // recon step 2: Bq[0:1024] + d2 -> Aq[0:2048]
    for (int i = tid; i < 2048; i += 256) {
        int par = i & 1;
        float s = 0.f;
#pragma unroll
        for (int j = 0; j < 4; ++j) {
            int k = 2 * j + par;
            int idx = ((i - k) & 2047) >> 1;
            s = fmaf(c_lo[k], Bq[idx], s);
            s = fmaf(c_hi[k], d2[idx], s);
        }
        Aq[i] = s;
    }
    __syncthreads();
    // recon step 3: Aq[0:2048] + d1 -> s = zrow + rec -> global (in place)
    for (int i = tid; i < 4096; i += 256) {
        int par = i & 1;
        float s = 0.f;
#pragma unroll
        for (int j = 0; j < 4; ++j) {
            int k = 2 * j + par;
            int idx = ((i - k) & 4095) >> 1;
            s = fmaf(c_lo[k], Aq[idx], s);
            s = fmaf(c_hi[k], d1[idx], s);
        }
        zg[i] = zrow[i] + s;
    }
}

// ---------------- mix: out = gelu(W_mix @ s + b_mix) * mask, + pool partials ----------------

__global__ __launch_bounds__(256) void mix_kernel(const float* __restrict__ s,
                                                  const float* __restrict__ WmT_g,
                                                  const float* __restrict__ b_mix,
                                                  const float* __restrict__ mask,
                                                  float* __restrict__ out,
                                                  float* __restrict__ pool_part) {
    __shared__ float Wl[HD * HD];      // [h][g]
    __shared__ float stT[64 * 132];    // [l][h], stride 132 (16B-aligned rows)
    __shared__ float4 plds[8][32];

    int bi = blockIdx.x;
    int b = bi >> 6;
    int blkl = bi & 63;
    int l0 = blkl << 6;
    int tid = threadIdx.x;

    for (int i = tid; i < HD * HD; i += 256) Wl[i] = WmT_g[i];
    for (int i = tid; i < HD * 64; i += 256) {
        int h = i >> 6, l = i & 63;
        stT[l * 132 + h] = s[((size_t)b * HD + h) * LL + l0 + l];
    }
    __syncthreads();

    int gq = tid & 31, lq = tid >> 5;
    int g0 = gq << 2, lb = lq << 3;

    float4 acc[8];
#pragma unroll
    for (int j = 0; j < 8; ++j) acc[j] = make_float4(0.f, 0.f, 0.f, 0.f);

#pragma unroll 2
    for (int h0 = 0; h0 < HD; h0 += 4) {
        float4 wv0 = *(const float4*)&Wl[(h0 + 0) * HD + g0];
        float4 wv1 = *(const float4*)&Wl[(h0 + 1) * HD + g0];
        float4 wv2 = *(const float4*)&Wl[(h0 + 2) * HD + g0];
        float4 wv3 = *(const float4*)&Wl[(h0 + 3) * HD + g0];
#pragma unroll
        for (int j = 0; j < 8; ++j) {
            float4 s4 = *(const float4*)&stT[(lb + j) * 132 + h0];
            float4 a = acc[j];
            a.x = fmaf(wv0.x, s4.x, a.x); a.y = fmaf(wv0.y, s4.x, a.y);
            a.z = fmaf(wv0.z, s4.x, a.z); a.w = fmaf(wv0.w, s4.x, a.w);
            a.x = fmaf(wv1.x, s4.y, a.x); a.y = fmaf(wv1.y, s4.y, a.y);
            a.z = fmaf(wv1.z, s4.y, a.z); a.w = fmaf(wv1.w, s4.y, a.w);
            a.x = fmaf(wv2.x, s4.z, a.x); a.y = fmaf(wv2.y, s4.z, a.y);
            a.z = fmaf(wv2.z, s4.z, a.z); a.w = fmaf(wv2.w, s4.z, a.w);
            a.x = fmaf(wv3.x, s4.w, a.x); a.y = fmaf(wv3.y, s4.w, a.y);
            a.z = fmaf(wv3.z, s4.w, a.z); a.w = fmaf(wv3.w, s4.w, a.w);
            acc[j] = a;
        }
    }

    float4 bm = *(const float4*)&b_mix[g0];
    float4 pacc = make_float4(0.f, 0.f, 0.f, 0.f);
#pragma unroll
    for (int j = 0; j < 8; ++j) {
        int l = l0 + lb + j;
        float mk = mask[(size_t)b * LL + l];
        float4 v = acc[j];
        v.x = gelu_exact(v.x + bm.x) * mk;
        v.y = gelu_exact(v.y + bm.y) * mk;
        v.z = gelu_exact(v.z + bm.z) * mk;
        v.w = gelu_exact(v.w + bm.w) * mk;
        *(float4*)&out[((size_t)b * LL + l) * HD + g0] = v;
        pacc.x = fmaf(v.x, mk, pacc.x);
        pacc.y = fmaf(v.y, mk, pacc.y);
        pacc.z = fmaf(v.z, mk, pacc.z);
        pacc.w = fmaf(v.w, mk, pacc.w);
    }
    plds[lq][gq] = pacc;
    __syncthreads();
    if (tid < 32) {
        float4 sum = plds[0][tid];
#pragma unroll
        for (int q = 1; q < 8; ++q) {
            float4 p = plds[q][tid];
            sum.x += p.x; sum.y += p.y; sum.z += p.z; sum.w += p.w;
        }
        *(float4*)&pool_part[((size_t)(b * 64 + blkl)) * HD + (tid << 2)] = sum;
    }
}

// ---------------- finalize: pool + lam mean/max ----------------

__global__ void finalize_kernel(const float* __restrict__ pool_part,
                                const float* __restrict__ denom,
                                const float* __restrict__ lam_ws,
                                float* __restrict__ d_out) {
    const size_t OUT1 = (size_t)BB * LL * HD;
    const size_t OUT2 = OUT1 + (size_t)BB * HD;
    const size_t OUT3 = OUT2 + BB;
    int b = blockIdx.x, tid = threadIdx.x;
    __shared__ float rsum[256], rmax[256];
    if (tid < 128) {
        float s = 0.f;
        for (int blk = 0; blk < 64; ++blk)
            s += pool_part[((size_t)(b * 64 + blk)) * HD + tid];
        d_out[OUT1 + (size_t)b * HD + tid] = s / denom[b];
    }
    float v0 = lam_ws[(size_t)b * 512 + tid];
    float v1 = lam_ws[(size_t)b * 512 + 256 + tid];
    rsum[tid] = v0 + v1;
    rmax[tid] = fmaxf(v0, v1);
    __syncthreads();
    for (int st = 128; st > 0; st >>= 1) {
        if (tid < st) {
            rsum[tid] += rsum[tid + st];
            rmax[tid] = fmaxf(rmax[tid], rmax[tid + st]);
        }
        __syncthreads();
    }
    if (tid == 0) {
        d_out[OUT2 + b] = rsum[0] / 512.0f;
        d_out[OUT3 + b] = rmax[0];
    }
}

// ---------------- launch ----------------

extern "C" void kernel_launch(void* const* d_in, const int* in_sizes, int n_in,
                              void* d_out, int out_size, void* d_ws, size_t ws_size,
                              hipStream_t stream) {
    (void)in_sizes; (void)n_in; (void)out_size; (void)ws_size;
    const float* x      = (const float*)d_in[0];
    const float* mask   = (const float*)d_in[1];
    const float* flow   = (const float*)d_in[2];
    const float* W_in   = (const float*)d_in[3];
    const float* b_in   = (const float*)d_in[4];
    const float* W_mix  = (const float*)d_in[5];
    const float* b_mix  = (const float*)d_in[6];
    const float* lam_raw= (const float*)d_in[7];
    const float* Wgb    = (const float*)d_in[8];
    const float* bgb    = (const float*)d_in[9];
    const float* Wg     = (const float*)d_in[10];
    const float* bg     = (const float*)d_in[11];

    float* ws = (float*)d_ws;
    float* z         = ws;                                   // B*H*L = 8388608
    float* film_ws   = z + (size_t)BB * HD * LL;             // B*4*256 = 16384
    float* gate_ws   = film_ws + (size_t)BB * 4 * 256;       // 64
    float* lam_ws    = gate_ws + 64;                         // B*4*128 = 8192
    float* denom_ws  = lam_ws + (size_t)BB * 4 * 128;        // 16
    float* pool_part = denom_ws + 16;                        // B*64*128 = 131072
    float* WmT       = pool_part + (size_t)BB * 64 * HD;     // 16384

    float* out = (float*)d_out;

    hipLaunchKernelGGL(transpose_w_kernel, dim3(64), dim3(256), 0, stream, W_mix, WmT);
    hipLaunchKernelGGL(film_kernel, dim3(BB * 4), dim3(256), 0, stream,
                       flow, Wgb, bgb, Wg, bg, film_ws, gate_ws);
    hipLaunchKernelGGL(denom_kernel, dim3(BB), dim3(256), 0, stream, mask, denom_ws);
    hipLaunchKernelGGL(zproj_kernel, dim3(BB * (LL / 64)), dim3(256), 0, stream,
                       x, mask, W_in, b_in, z);
    hipLaunchKernelGGL(wavelet_kernel, dim3(BB * HD), dim3(256), 0, stream,
                       z, film_ws, gate_ws, lam_raw, lam_ws);
    hipLaunchKernelGGL(mix_kernel, dim3(BB * (LL / 64)), dim3(256), 0, stream,
                       z, WmT, b_mix, mask, out, pool_part);
    hipLaunchKernelGGL(finalize_kernel, dim3(BB), dim3(256), 0, stream,
                       pool_part, denom_ws, lam_ws, out);
}

// Round 2
// 125.772 us; speedup vs baseline: 1.3133x; 1.3133x over previous
//
#include <hip/hip_runtime.h>
#include <math.h>

#define BB 16
#define LL 4096
#define CC 64
#define HD 128

__constant__ float c_lo[8] = {
    -0.010597401784997278f, 0.032883011666982945f, 0.030841381835986965f,
    -0.18703481171888114f, -0.02798376941698385f, 0.6308807679295904f,
    0.7148465705525415f, 0.23037781330885523f};
__constant__ float c_hi[8] = {
    -0.23037781330885523f, 0.7148465705525415f, -0.6308807679295904f,
    -0.02798376941698385f, 0.18703481171888114f, 0.030841381835986965f,
    -0.032883011666982945f, -0.010597401784997278f};

__device__ __forceinline__ float gelu_exact(float x) {
    return 0.5f * x * (1.0f + erff(x * 0.70710678118654752440f));
}

// ---------------- fused prep: W_mix transpose + FiLM + denom ----------------

__global__ __launch_bounds__(256) void prep_kernel(
    const float* __restrict__ W_mix, float* __restrict__ WmT,
    const float* __restrict__ flow, const float* __restrict__ Wgb,
    const float* __restrict__ bgb, const float* __restrict__ Wg,
    const float* __restrict__ bg, float* __restrict__ film_ws,
    float* __restrict__ gate_ws,
    const float* __restrict__ mask, float* __restrict__ denom) {
    __shared__ float red[256];
    int blk = blockIdx.x;
    int tid = threadIdx.x;
    if (blk < 64) {
        int i = blk * 256 + tid;          // 16384 total
        int h = i >> 7, g = i & 127;
        WmT[i] = W_mix[g * HD + h];       // WmT[h][g] = W[g][h]
    } else if (blk < 128) {
        int bf = blk - 64;                // b*4 + f
        int f = bf & 3;
        int b = bf >> 2;
        const float* fl = flow + b * 24;
        const float* wrow = Wgb + ((size_t)(f * 256 + tid)) * 24;
        float acc = bgb[f * 256 + tid];
#pragma unroll
        for (int j = 0; j < 24; ++j) acc = fmaf(wrow[j], fl[j], acc);
        film_ws[(size_t)bf * 256 + tid] = acc;
        if (tid == 0) {
            float g = bg[f];
#pragma unroll
            for (int j = 0; j < 24; ++j) g = fmaf(Wg[f * 24 + j], fl[j], g);
            gate_ws[bf] = 1.0f / (1.0f + expf(-g));
        }
    } else {
        int b = blk - 128;
        float s = 0.f;
        for (int i = tid; i < LL; i += 256) s += mask[(size_t)b * LL + i];
        red[tid] = s; __syncthreads();
        for (int st = 128; st > 0; st >>= 1) {
            if (tid < st) red[tid] += red[tid + st];
            __syncthreads();
        }
        if (tid == 0) denom[b] = fmaxf(red[0], 1.0f);
    }
}

// ---------------- z projection: z[b][h][l] = W_in @ (x*mask) + b_in ----------------

__global__ __launch_bounds__(256) void zproj_kernel(const float* __restrict__ x,
                                                    const float* __restrict__ mask,
                                                    const float* __restrict__ W_in,
                                                    const float* __restrict__ b_in,
                                                    float* __restrict__ z) {
    __shared__ float Wl[HD * CC];       // [h][c], broadcast reads
    __shared__ float xt[64][CC + 1];    // stride 65 -> conflict-free lane reads
    int blk = blockIdx.x;
    int b = blk >> 6;
    int l0 = (blk & 63) << 6;
    int tid = threadIdx.x;
    for (int i = tid; i < HD * CC; i += 256) Wl[i] = W_in[i];
    for (int i = tid; i < 64 * 16; i += 256) {
        int ll = i >> 4, c4 = (i & 15) << 2;
        float mk = mask[(size_t)b * LL + l0 + ll];
        float4 xv = *(const float4*)&x[((size_t)b * LL + l0 + ll) * CC + c4];
        float* dst = &xt[ll][c4];
        dst[0] = xv.x * mk; dst[1] = xv.y * mk; dst[2] = xv.z * mk; dst[3] = xv.w * mk;
    }
    __syncthreads();
    int ll = tid & 63;
    int hg = tid >> 6;
    for (int h = hg; h < HD; h += 4) {
        const float* wr = &Wl[h * CC];
        const float* xr = &xt[ll][0];
        float a0 = 0.f, a1 = 0.f, a2 = 0.f, a3 = 0.f;
#pragma unroll
        for (int c = 0; c < CC; c += 4) {
            a0 = fmaf(wr[c + 0], xr[c + 0], a0);
            a1 = fmaf(wr[c + 1], xr[c + 1], a1);
            a2 = fmaf(wr[c + 2], xr[c + 2], a2);
            a3 = fmaf(wr[c + 3], xr[c + 3], a3);
        }
        z[((size_t)b * HD + h) * LL + l0 + ll] = (a0 + a1) + (a2 + a3) + b_in[h];
    }
}

// ---------------- per-row wavelet: decompose + FiLM + soft-threshold + reconstruct ----------------
// One block per (b,h) row; s = z + z_rec written in place.  LDS = exactly 40 KB:
//   zrow 16K | d1 8K | d2 4K | Aq 8K (approx1 -> approx3[0:512]+d3[512:1024] -> recon2048) | Bq 4K
//   (Bq doubles as the reduction scratch during the band phase.)

__global__ __launch_bounds__(256) void wavelet_kernel(float* __restrict__ z,
                                                      const float* __restrict__ film_ws,
                                                      const float* __restrict__ gate_ws,
                                                      const float* __restrict__ lam_raw,
                                                      float* __restrict__ lam_ws) {
    __shared__ float zrow[4096];
    __shared__ float d1[2048];
    __shared__ float d2[1024];
    __shared__ float Aq[2048];
    __shared__ float Bq[1024];

    int blk = blockIdx.x;
    int b = blk >> 7;
    int h = blk & 127;
    int tid = threadIdx.x;
    float* zg = z + ((size_t)b * HD + h) * LL;

    for (int i = tid; i < 1024; i += 256)
        *(float4*)&zrow[i << 2] = *(const float4*)&zg[i << 2];
    __syncthreads();

    // analysis level 1: zrow[4096] -> Aq[2048] (lo), d1[2048] (hi)
    for (int n = tid; n < 2048; n += 256) {
        float lo = 0.f, hi = 0.f;
#pragma unroll
        for (int k = 0; k < 8; ++k) {
            float v = zrow[(2 * n + k) & 4095];
            lo = fmaf(c_lo[k], v, lo);
            hi = fmaf(c_hi[k], v, hi);
        }
        Aq[n] = lo; d1[n] = hi;
    }
    __syncthreads();
    // level 2: Aq[2048] -> Bq[1024], d2[1024]
    for (int n = tid; n < 1024; n += 256) {
        float lo = 0.f, hi = 0.f;
#pragma unroll
        for (int k = 0; k < 8; ++k) {
            float v = Aq[(2 * n + k) & 2047];
            lo = fmaf(c_lo[k], v, lo);
            hi = fmaf(c_hi[k], v, hi);
        }
        Bq[n] = lo; d2[n] = hi;
    }
    __syncthreads();
    // level 3: Bq[1024] -> Aq[0:512] (approx3), Aq[512:1024] (d3)
    for (int n = tid; n < 512; n += 256) {
        float lo = 0.f, hi = 0.f;
#pragma unroll
        for (int k = 0; k < 8; ++k) {
            float v = Bq[(2 * n + k) & 1023];
            lo = fmaf(c_lo[k], v, lo);
            hi = fmaf(c_hi[k], v, hi);
        }
        Aq[n] = lo; Aq[512 + n] = hi;
    }
    __syncthreads();

    // FiLM apply + |.| partial sums, all 4 bands in one sweep
    // band0 = approx3 (Aq[0:512]), band1 = d1, band2 = d2, band3 = d3 (Aq[512:1024])
    float sc0, sh0, sc1, sh1, sc2, sh2, sc3, sh3;
    {
        int base = b * 4;
#define FILM_COEF(bd, SC, SH)                                              \
        {   float ga = film_ws[((size_t)(base + bd)) * 256 + h];           \
            float be = film_ws[((size_t)(base + bd)) * 256 + 128 + h];     \
            float gt = gate_ws[base + bd];                                 \
            SC = 1.0f + gt * ga; SH = gt * be; }
        FILM_COEF(0, sc0, sh0) FILM_COEF(1, sc1, sh1)
        FILM_COEF(2, sc2, sh2) FILM_COEF(3, sc3, sh3)
#undef FILM_COEF
    }
    float s0 = 0.f, s1 = 0.f, s2 = 0.f, s3 = 0.f;
    for (int i = tid; i < 512; i += 256) {
        float v = fmaf(Aq[i], sc0, sh0); Aq[i] = v; s0 += fabsf(v);
    }
    for (int i = tid; i < 2048; i += 256) {
        float v = fmaf(d1[i], sc1, sh1); d1[i] = v; s1 += fabsf(v);
    }
    for (int i = tid; i < 1024; i += 256) {
        float v = fmaf(d2[i], sc2, sh2); d2[i] = v; s2 += fabsf(v);
    }
    for (int i = tid; i < 512; i += 256) {
        float v = fmaf(Aq[512 + i], sc3, sh3); Aq[512 + i] = v; s3 += fabsf(v);
    }
    // wave-level reduce (64 lanes), then cross-wave via Bq scratch
#pragma unroll
    for (int off = 32; off > 0; off >>= 1) {
        s0 += __shfl_xor(s0, off);
        s1 += __shfl_xor(s1, off);
        s2 += __shfl_xor(s2, off);
        s3 += __shfl_xor(s3, off);
    }
    if ((tid & 63) == 0)
        ((float4*)Bq)[tid >> 6] = make_float4(s0, s1, s2, s3);
    __syncthreads();
    float4 r0 = ((const float4*)Bq)[0];
    float4 r1 = ((const float4*)Bq)[1];
    float4 r2 = ((const float4*)Bq)[2];
    float4 r3 = ((const float4*)Bq)[3];
    float lam0 = log1pf(expf(lam_raw[0])) * ((r0.x + r1.x + r2.x + r3.x) * (1.0f / 512.f));
    float lam1 = log1pf(expf(lam_raw[1])) * ((r0.y + r1.y + r2.y + r3.y) * (1.0f / 2048.f));
    float lam2 = log1pf(expf(lam_raw[2])) * ((r0.z + r1.z + r2.z + r3.z) * (1.0f / 1024.f));
    float lam3 = log1pf(expf(lam_raw[3])) * ((r0.w + r1.w + r2.w + r3.w) * (1.0f / 512.f));
    if (tid < 4) {
        float lam = (tid == 0) ? lam0 : (tid == 1) ? lam1 : (tid == 2) ? lam2 : lam3;
        lam_ws[((size_t)(b * 4 + tid)) * 128 + h] = lam;
    }
    // soft threshold (same indices as the sweep above -> no barrier needed before)
#define STHR(p, lam) { float v = (p); float av = fabsf(v) - (lam); (p) = (av > 0.f) ? copysignf(av, v) : 0.f; }
    for (int i = tid; i < 512; i += 256)  STHR(Aq[i], lam0)
    for (int i = tid; i < 2048; i += 256) STHR(d1[i], lam1)
    for (int i = tid; i < 1024; i += 256) STHR(d2[i], lam2)
    for (int i = tid; i < 512; i += 256)  STHR(Aq[512 + i], lam3)
#undef STHR
    __syncthreads();

    // recon step 1: Aq[0:512] + d3(Aq[512:1024]) -> Bq[0:1024]
    for (int i = tid; i < 1024; i += 256) {
        int par = i & 1;
        float s = 0.f;
#pragma unroll
        for (int j = 0; j < 4; ++j) {
            int k = 2 * j + par;
            int idx = ((i - k) & 1023) >> 1;
            s = fmaf(c_lo[k], Aq[idx], s);
            s = fmaf(c_hi[k], Aq[512 + idx], s);
        }
        Bq[i] = s;
    }
    __syncthreads();
    // recon step 2: Bq[0:1024] + d2 -> Aq[0:2048]
    for (int i = tid; i < 2048; i += 256) {
        int par = i & 1;
        float s = 0.f;
#pragma unroll
        for (int j = 0; j < 4; ++j) {
            int k = 2 * j + par;
            int idx = ((i - k) & 2047) >> 1;
            s = fmaf(c_lo[k], Bq[idx], s);
            s = fmaf(c_hi[k], d2[idx], s);
        }
        Aq[i] = s;
    }
    __syncthreads();
    // recon step 3: Aq[0:2048] + d1 -> s = zrow + rec -> global (in place)
    for (int i = tid; i < 4096; i += 256) {
        int par = i & 1;
        float s = 0.f;
#pragma unroll
        for (int j = 0; j < 4; ++j) {
            int k = 2 * j + par;
            int idx = ((i - k) & 4095) >> 1;
            s = fmaf(c_lo[k], Aq[idx], s);
            s = fmaf(c_hi[k], d1[idx], s);
        }
        zg[i] = zrow[i] + s;
    }
}

// ---------------- mix: out = gelu(W_mix @ s + b_mix) * mask, + pool partials ----------------
// LDS = 36 KB -> 4 blocks/CU. W_mix read from global (L1/L2 broadcast).
// stT layout [h][l]: staging writes conflict-free, compute reads broadcast.

__global__ __launch_bounds__(256) void mix_kernel(const float* __restrict__ s,
                                                  const float* __restrict__ WmT_g,
                                                  const float* __restrict__ b_mix,
                                                  const float* __restrict__ mask,
                                                  float* __restrict__ out,
                                                  float* __restrict__ pool_part) {
    __shared__ float stT[HD * 64];     // [h][l]  32 KB
    __shared__ float4 plds[8][32];     // 4 KB

    int bi = blockIdx.x;
    int b = bi >> 6;
    int blkl = bi & 63;
    int l0 = blkl << 6;
    int tid = threadIdx.x;

    for (int i = tid; i < HD * 64; i += 256) {
        int hh = i >> 6, l = i & 63;
        stT[i] = s[((size_t)b * HD + hh) * LL + l0 + l];
    }
    __syncthreads();

    int gq = tid & 31, lq = tid >> 5;
    int g0 = gq << 2, lb = lq << 3;

    float4 acc[8];
#pragma unroll
    for (int j = 0; j < 8; ++j) acc[j] = make_float4(0.f, 0.f, 0.f, 0.f);

#pragma unroll 2
    for (int h0 = 0; h0 < HD; h0 += 4) {
        const float4 wv0 = *(const float4*)&WmT_g[(h0 + 0) * HD + g0];
        const float4 wv1 = *(const float4*)&WmT_g[(h0 + 1) * HD + g0];
        const float4 wv2 = *(const float4*)&WmT_g[(h0 + 2) * HD + g0];
        const float4 wv3 = *(const float4*)&WmT_g[(h0 + 3) * HD + g0];
        const float* sp0 = &stT[(h0 + 0) * 64 + lb];
#pragma unroll
        for (int jp = 0; jp < 4; ++jp) {
            float2 t0 = *(const float2*)(sp0 + 2 * jp);
            float2 t1 = *(const float2*)(sp0 + 64 + 2 * jp);
            float2 t2 = *(const float2*)(sp0 + 128 + 2 * jp);
            float2 t3 = *(const float2*)(sp0 + 192 + 2 * jp);
            float4 a = acc[2 * jp];
            a.x = fmaf(wv0.x, t0.x, a.x); a.y = fmaf(wv0.y, t0.x, a.y);
            a.z = fmaf(wv0.z, t0.x, a.z); a.w = fmaf(wv0.w, t0.x, a.w);
            a.x = fmaf(wv1.x, t1.x, a.x); a.y = fmaf(wv1.y, t1.x, a.y);
            a.z = fmaf(wv1.z, t1.x, a.z); a.w = fmaf(wv1.w, t1.x, a.w);
            a.x = fmaf(wv2.x, t2.x, a.x); a.y = fmaf(wv2.y, t2.x, a.y);
            a.z = fmaf(wv2.z, t2.x, a.z); a.w = fmaf(wv2.w, t2.x, a.w);
            a.x = fmaf(wv3.x, t3.x, a.x); a.y = fmaf(wv3.y, t3.x, a.y);
            a.z = fmaf(wv3.z, t3.x, a.z); a.w = fmaf(wv3.w, t3.x, a.w);
            acc[2 * jp] = a;
            float4 c = acc[2 * jp + 1];
            c.x = fmaf(wv0.x, t0.y, c.x); c.y = fmaf(wv0.y, t0.y, c.y);
            c.z = fmaf(wv0.z, t0.y, c.z); c.w = fmaf(wv0.w, t0.y, c.w);
            c.x = fmaf(wv1.x, t1.y, c.x); c.y = fmaf(wv1.y, t1.y, c.y);
            c.z = fmaf(wv1.z, t1.y, c.z); c.w = fmaf(wv1.w, t1.y, c.w);
            c.x = fmaf(wv2.x, t2.y, c.x); c.y = fmaf(wv2.y, t2.y, c.y);
            c.z = fmaf(wv2.z, t2.y, c.z); c.w = fmaf(wv2.w, t2.y, c.w);
            c.x = fmaf(wv3.x, t3.y, c.x); c.y = fmaf(wv3.y, t3.y, c.y);
            c.z = fmaf(wv3.z, t3.y, c.z); c.w = fmaf(wv3.w, t3.y, c.w);
            acc[2 * jp + 1] = c;
        }
    }

    float4 bm = *(const float4*)&b_mix[g0];
    float4 pacc = make_float4(0.f, 0.f, 0.f, 0.f);
#pragma unroll
    for (int j = 0; j < 8; ++j) {
        int l = l0 + lb + j;
        float mk = mask[(size_t)b * LL + l];
        float4 v = acc[j];
        v.x = gelu_exact(v.x + bm.x) * mk;
        v.y = gelu_exact(v.y + bm.y) * mk;
        v.z = gelu_exact(v.z + bm.z) * mk;
        v.w = gelu_exact(v.w + bm.w) * mk;
        *(float4*)&out[((size_t)b * LL + l) * HD + g0] = v;
        pacc.x = fmaf(v.x, mk, pacc.x);
        pacc.y = fmaf(v.y, mk, pacc.y);
        pacc.z = fmaf(v.z, mk, pacc.z);
        pacc.w = fmaf(v.w, mk, pacc.w);
    }
    plds[lq][gq] = pacc;
    __syncthreads();
    if (tid < 32) {
        float4 sum = plds[0][tid];
#pragma unroll
        for (int q = 1; q < 8; ++q) {
            float4 p = plds[q][tid];
            sum.x += p.x; sum.y += p.y; sum.z += p.z; sum.w += p.w;
        }
        *(float4*)&pool_part[((size_t)(b * 64 + blkl)) * HD + (tid << 2)] = sum;
    }
}

// ---------------- finalize: pool + lam mean/max ----------------

__global__ void finalize_kernel(const float* __restrict__ pool_part,
                                const float* __restrict__ denom,
                                const float* __restrict__ lam_ws,
                                float* __restrict__ d_out) {
    const size_t OUT1 = (size_t)BB * LL * HD;
    const size_t OUT2 = OUT1 + (size_t)BB * HD;
    const size_t OUT3 = OUT2 + BB;
    int b = blockIdx.x, tid = threadIdx.x;
    __shared__ float rsum[256], rmax[256];
    if (tid < 128) {
        float s = 0.f;
        for (int blk = 0; blk < 64; ++blk)
            s += pool_part[((size_t)(b * 64 + blk)) * HD + tid];
        d_out[OUT1 + (size_t)b * HD + tid] = s / denom[b];
    }
    float v0 = lam_ws[(size_t)b * 512 + tid];
    float v1 = lam_ws[(size_t)b * 512 + 256 + tid];
    rsum[tid] = v0 + v1;
    rmax[tid] = fmaxf(v0, v1);
    __syncthreads();
    for (int st = 128; st > 0; st >>= 1) {
        if (tid < st) {
            rsum[tid] += rsum[tid + st];
            rmax[tid] = fmaxf(rmax[tid], rmax[tid + st]);
        }
        __syncthreads();
    }
    if (tid == 0) {
        d_out[OUT2 + b] = rsum[0] / 512.0f;
        d_out[OUT3 + b] = rmax[0];
    }
}

// ---------------- launch ----------------

extern "C" void kernel_launch(void* const* d_in, const int* in_sizes, int n_in,
                              void* d_out, int out_size, void* d_ws, size_t ws_size,
                              hipStream_t stream) {
    (void)in_sizes; (void)n_in; (void)out_size; (void)ws_size;
    const float* x      = (const float*)d_in[0];
    const float* mask   = (const float*)d_in[1];
    const float* flow   = (const float*)d_in[2];
    const float* W_in   = (const float*)d_in[3];
    const float* b_in   = (const float*)d_in[4];
    const float* W_mix  = (const float*)d_in[5];
    const float* b_mix  = (const float*)d_in[6];
    const float* lam_raw= (const float*)d_in[7];
    const float* Wgb    = (const float*)d_in[8];
    const float* bgb    = (const float*)d_in[9];
    const float* Wg     = (const float*)d_in[10];
    const float* bg     = (const float*)d_in[11];

    float* ws = (float*)d_ws;
    float* z         = ws;                                   // B*H*L = 8388608
    float* film_ws   = z + (size_t)BB * HD * LL;             // B*4*256 = 16384
    float* gate_ws   = film_ws + (size_t)BB * 4 * 256;       // 64
    float* lam_ws    = gate_ws + 64;                         // B*4*128 = 8192
    float* denom_ws  = lam_ws + (size_t)BB * 4 * 128;        // 16
    float* pool_part = denom_ws + 16;                        // B*64*128 = 131072
    float* WmT       = pool_part + (size_t)BB * 64 * HD;     // 16384

    float* out = (float*)d_out;

    hipLaunchKernelGGL(prep_kernel, dim3(144), dim3(256), 0, stream,
                       W_mix, WmT, flow, Wgb, bgb, Wg, bg, film_ws, gate_ws,
                       mask, denom_ws);
    hipLaunchKernelGGL(zproj_kernel, dim3(BB * (LL / 64)), dim3(256), 0, stream,
                       x, mask, W_in, b_in, z);
    hipLaunchKernelGGL(wavelet_kernel, dim3(BB * HD), dim3(256), 0, stream,
                       z, film_ws, gate_ws, lam_raw, lam_ws);
    hipLaunchKernelGGL(mix_kernel, dim3(BB * (LL / 64)), dim3(256), 0, stream,
                       z, WmT, b_mix, mask, out, pool_part);
    hipLaunchKernelGGL(finalize_kernel, dim3(BB), dim3(256), 0, stream,
                       pool_part, denom_ws, lam_ws, out);
}

// Round 3
// 118.861 us; speedup vs baseline: 1.3897x; 1.0581x over previous
//
#include <hip/hip_runtime.h>
#include <math.h>

#define BB 16
#define LL 4096
#define CC 64
#define HD 128

__constant__ float c_lo[8] = {
    -0.010597401784997278f, 0.032883011666982945f, 0.030841381835986965f,
    -0.18703481171888114f, -0.02798376941698385f, 0.6308807679295904f,
    0.7148465705525415f, 0.23037781330885523f};
__constant__ float c_hi[8] = {
    -0.23037781330885523f, 0.7148465705525415f, -0.6308807679295904f,
    -0.02798376941698385f, 0.18703481171888114f, 0.030841381835986965f,
    -0.032883011666982945f, -0.010597401784997278f};

__device__ __forceinline__ float gelu_exact(float x) {
    return 0.5f * x * (1.0f + erff(x * 0.70710678118654752440f));
}

// ---------------- fused prep: transposes + FiLM + denom ----------------

__global__ __launch_bounds__(256) void prep_kernel(
    const float* __restrict__ W_mix, float* __restrict__ WmT,
    const float* __restrict__ W_in, float* __restrict__ WinT,
    const float* __restrict__ flow, const float* __restrict__ Wgb,
    const float* __restrict__ bgb, const float* __restrict__ Wg,
    const float* __restrict__ bg, float* __restrict__ film_ws,
    float* __restrict__ gate_ws,
    const float* __restrict__ mask, float* __restrict__ denom) {
    __shared__ float red[256];
    int blk = blockIdx.x;
    int tid = threadIdx.x;
    if (blk < 64) {
        int i = blk * 256 + tid;          // 16384 total
        int h = i >> 7, g = i & 127;
        WmT[i] = W_mix[g * HD + h];       // WmT[h][g] = W[g][h]
    } else if (blk < 96) {
        int i = (blk - 64) * 256 + tid;   // 8192 total
        int c = i >> 7, h = i & 127;
        WinT[i] = W_in[h * CC + c];       // WinT[c][h] = W_in[h][c]
    } else if (blk < 160) {
        int bf = blk - 96;                // b*4 + f
        int f = bf & 3;
        int b = bf >> 2;
        const float* fl = flow + b * 24;
        const float* wrow = Wgb + ((size_t)(f * 256 + tid)) * 24;
        float acc = bgb[f * 256 + tid];
#pragma unroll
        for (int j = 0; j < 24; ++j) acc = fmaf(wrow[j], fl[j], acc);
        film_ws[(size_t)bf * 256 + tid] = acc;
        if (tid == 0) {
            float g = bg[f];
#pragma unroll
            for (int j = 0; j < 24; ++j) g = fmaf(Wg[f * 24 + j], fl[j], g);
            gate_ws[bf] = 1.0f / (1.0f + expf(-g));
        }
    } else {
        int b = blk - 160;
        float s = 0.f;
        for (int i = tid; i < LL; i += 256) s += mask[(size_t)b * LL + i];
        red[tid] = s; __syncthreads();
        for (int st = 128; st > 0; st >>= 1) {
            if (tid < st) red[tid] += red[tid + st];
            __syncthreads();
        }
        if (tid == 0) denom[b] = fmaxf(red[0], 1.0f);
    }
}

// ---------------- z projection (register-tiled GEMM) ----------------
// z[b][h][l] = W_in @ (x*mask) + b_in.  Block: 128 h x 64 l tile.
// LDS: xs[l][c] 16 KB (direct coalesced copy). W_inT [c][h] from global,
// broadcast float4 reads with 1-step prefetch.

__global__ __launch_bounds__(256) void zproj_kernel(const float* __restrict__ x,
                                                    const float* __restrict__ mask,
                                                    const float* __restrict__ WinT,
                                                    const float* __restrict__ b_in,
                                                    float* __restrict__ z) {
    __shared__ float xs[64 * CC];       // [l][c] 16 KB
    int blk = blockIdx.x;
    int b = blk >> 6;
    int l0 = (blk & 63) << 6;
    int tid = threadIdx.x;

    for (int i = tid; i < 64 * 16; i += 256) {
        int ll = i >> 4, c4 = (i & 15) << 2;
        float mk = mask[(size_t)b * LL + l0 + ll];
        float4 xv = *(const float4*)&x[((size_t)b * LL + l0 + ll) * CC + c4];
        xv.x *= mk; xv.y *= mk; xv.z *= mk; xv.w *= mk;
        *(float4*)&xs[ll * CC + c4] = xv;
    }
    __syncthreads();

    int gq = tid & 31, lq = tid >> 5;
    int g0 = gq << 2, lb = lq << 3;

    float4 acc[8];
#pragma unroll
    for (int j = 0; j < 8; ++j) acc[j] = make_float4(0.f, 0.f, 0.f, 0.f);

    float4 nw0 = *(const float4*)&WinT[0 * HD + g0];
    float4 nw1 = *(const float4*)&WinT[1 * HD + g0];
    float4 nw2 = *(const float4*)&WinT[2 * HD + g0];
    float4 nw3 = *(const float4*)&WinT[3 * HD + g0];
#pragma unroll
    for (int c0 = 0; c0 < CC; c0 += 4) {
        float4 w0 = nw0, w1 = nw1, w2 = nw2, w3 = nw3;
        if (c0 + 4 < CC) {
            nw0 = *(const float4*)&WinT[(c0 + 4) * HD + g0];
            nw1 = *(const float4*)&WinT[(c0 + 5) * HD + g0];
            nw2 = *(const float4*)&WinT[(c0 + 6) * HD + g0];
            nw3 = *(const float4*)&WinT[(c0 + 7) * HD + g0];
        }
#pragma unroll
        for (int j = 0; j < 8; ++j) {
            float4 t = *(const float4*)&xs[(lb + j) * CC + c0];
            float4 a = acc[j];
            a.x = fmaf(w0.x, t.x, a.x); a.y = fmaf(w0.y, t.x, a.y);
            a.z = fmaf(w0.z, t.x, a.z); a.w = fmaf(w0.w, t.x, a.w);
            a.x = fmaf(w1.x, t.y, a.x); a.y = fmaf(w1.y, t.y, a.y);
            a.z = fmaf(w1.z, t.y, a.z); a.w = fmaf(w1.w, t.y, a.w);
            a.x = fmaf(w2.x, t.z, a.x); a.y = fmaf(w2.y, t.z, a.y);
            a.z = fmaf(w2.z, t.z, a.z); a.w = fmaf(w2.w, t.z, a.w);
            a.x = fmaf(w3.x, t.w, a.x); a.y = fmaf(w3.y, t.w, a.y);
            a.z = fmaf(w3.z, t.w, a.z); a.w = fmaf(w3.w, t.w, a.w);
            acc[j] = a;
        }
    }

    float4 bv = *(const float4*)&b_in[g0];
#define ZWRITE(K, COMP)                                                         \
    {                                                                           \
        float* zr = z + ((size_t)b * HD + g0 + K) * LL + l0 + lb;               \
        float4 v0 = make_float4(acc[0].COMP + bv.COMP, acc[1].COMP + bv.COMP,   \
                                acc[2].COMP + bv.COMP, acc[3].COMP + bv.COMP);  \
        float4 v1 = make_float4(acc[4].COMP + bv.COMP, acc[5].COMP + bv.COMP,   \
                                acc[6].COMP + bv.COMP, acc[7].COMP + bv.COMP);  \
        *(float4*)zr = v0;                                                      \
        *(float4*)(zr + 4) = v1;                                                \
    }
    ZWRITE(0, x) ZWRITE(1, y) ZWRITE(2, z) ZWRITE(3, w)
#undef ZWRITE
}

// ---------------- per-row wavelet (unchanged structure, 40 KB LDS) ----------------

__global__ __launch_bounds__(256) void wavelet_kernel(float* __restrict__ z,
                                                      const float* __restrict__ film_ws,
                                                      const float* __restrict__ gate_ws,
                                                      const float* __restrict__ lam_raw,
                                                      float* __restrict__ lam_ws) {
    __shared__ float zrow[4096];
    __shared__ float d1[2048];
    __shared__ float d2[1024];
    __shared__ float Aq[2048];
    __shared__ float Bq[1024];

    int blk = blockIdx.x;
    int b = blk >> 7;
    int h = blk & 127;
    int tid = threadIdx.x;
    float* zg = z + ((size_t)b * HD + h) * LL;

    for (int i = tid; i < 1024; i += 256)
        *(float4*)&zrow[i << 2] = *(const float4*)&zg[i << 2];
    __syncthreads();

    for (int n = tid; n < 2048; n += 256) {
        float lo = 0.f, hi = 0.f;
#pragma unroll
        for (int k = 0; k < 8; ++k) {
            float v = zrow[(2 * n + k) & 4095];
            lo = fmaf(c_lo[k], v, lo);
            hi = fmaf(c_hi[k], v, hi);
        }
        Aq[n] = lo; d1[n] = hi;
    }
    __syncthreads();
    for (int n = tid; n < 1024; n += 256) {
        float lo = 0.f, hi = 0.f;
#pragma unroll
        for (int k = 0; k < 8; ++k) {
            float v = Aq[(2 * n + k) & 2047];
            lo = fmaf(c_lo[k], v, lo);
            hi = fmaf(c_hi[k], v, hi);
        }
        Bq[n] = lo; d2[n] = hi;
    }
    __syncthreads();
    for (int n = tid; n < 512; n += 256) {
        float lo = 0.f, hi = 0.f;
#pragma unroll
        for (int k = 0; k < 8; ++k) {
            float v = Bq[(2 * n + k) & 1023];
            lo = fmaf(c_lo[k], v, lo);
            hi = fmaf(c_hi[k], v, hi);
        }
        Aq[n] = lo; Aq[512 + n] = hi;
    }
    __syncthreads();

    float sc0, sh0, sc1, sh1, sc2, sh2, sc3, sh3;
    {
        int base = b * 4;
#define FILM_COEF(bd, SC, SH)                                              \
        {   float ga = film_ws[((size_t)(base + bd)) * 256 + h];           \
            float be = film_ws[((size_t)(base + bd)) * 256 + 128 + h];     \
            float gt = gate_ws[base + bd];                                 \
            SC = 1.0f + gt * ga; SH = gt * be; }
        FILM_COEF(0, sc0, sh0) FILM_COEF(1, sc1, sh1)
        FILM_COEF(2, sc2, sh2) FILM_COEF(3, sc3, sh3)
#undef FILM_COEF
    }
    float s0 = 0.f, s1 = 0.f, s2 = 0.f, s3 = 0.f;
    for (int i = tid; i < 512; i += 256) {
        float v = fmaf(Aq[i], sc0, sh0); Aq[i] = v; s0 += fabsf(v);
    }
    for (int i = tid; i < 2048; i += 256) {
        float v = fmaf(d1[i], sc1, sh1); d1[i] = v; s1 += fabsf(v);
    }
    for (int i = tid; i < 1024; i += 256) {
        float v = fmaf(d2[i], sc2, sh2); d2[i] = v; s2 += fabsf(v);
    }
    for (int i = tid; i < 512; i += 256) {
        float v = fmaf(Aq[512 + i], sc3, sh3); Aq[512 + i] = v; s3 += fabsf(v);
    }
#pragma unroll
    for (int off = 32; off > 0; off >>= 1) {
        s0 += __shfl_xor(s0, off);
        s1 += __shfl_xor(s1, off);
        s2 += __shfl_xor(s2, off);
        s3 += __shfl_xor(s3, off);
    }
    if ((tid & 63) == 0)
        ((float4*)Bq)[tid >> 6] = make_float4(s0, s1, s2, s3);
    __syncthreads();
    float4 r0 = ((const float4*)Bq)[0];
    float4 r1 = ((const float4*)Bq)[1];
    float4 r2 = ((const float4*)Bq)[2];
    float4 r3 = ((const float4*)Bq)[3];
    float lam0 = log1pf(expf(lam_raw[0])) * ((r0.x + r1.x + r2.x + r3.x) * (1.0f / 512.f));
    float lam1 = log1pf(expf(lam_raw[1])) * ((r0.y + r1.y + r2.y + r3.y) * (1.0f / 2048.f));
    float lam2 = log1pf(expf(lam_raw[2])) * ((r0.z + r1.z + r2.z + r3.z) * (1.0f / 1024.f));
    float lam3 = log1pf(expf(lam_raw[3])) * ((r0.w + r1.w + r2.w + r3.w) * (1.0f / 512.f));
    if (tid < 4) {
        float lam = (tid == 0) ? lam0 : (tid == 1) ? lam1 : (tid == 2) ? lam2 : lam3;
        lam_ws[((size_t)(b * 4 + tid)) * 128 + h] = lam;
    }
#define STHR(p, lam) { float v = (p); float av = fabsf(v) - (lam); (p) = (av > 0.f) ? copysignf(av, v) : 0.f; }
    for (int i = tid; i < 512; i += 256)  STHR(Aq[i], lam0)
    for (int i = tid; i < 2048; i += 256) STHR(d1[i], lam1)
    for (int i = tid; i < 1024; i += 256) STHR(d2[i], lam2)
    for (int i = tid; i < 512; i += 256)  STHR(Aq[512 + i], lam3)
#undef STHR
    __syncthreads();

    for (int i = tid; i < 1024; i += 256) {
        int par = i & 1;
        float s = 0.f;
#pragma unroll
        for (int j = 0; j < 4; ++j) {
            int k = 2 * j + par;
            int idx = ((i - k) & 1023) >> 1;
            s = fmaf(c_lo[k], Aq[idx], s);
            s = fmaf(c_hi[k], Aq[512 + idx], s);
        }
        Bq[i] = s;
    }
    __syncthreads();
    for (int i = tid; i < 2048; i += 256) {
        int par = i & 1;
        float s = 0.f;
#pragma unroll
        for (int j = 0; j < 4; ++j) {
            int k = 2 * j + par;
            int idx = ((i - k) & 2047) >> 1;
            s = fmaf(c_lo[k], Bq[idx], s);
            s = fmaf(c_hi[k], d2[idx], s);
        }
        Aq[i] = s;
    }
    __syncthreads();
    for (int i = tid; i < 4096; i += 256) {
        int par = i & 1;
        float s = 0.f;
#pragma unroll
        for (int j = 0; j < 4; ++j) {
            int k = 2 * j + par;
            int idx = ((i - k) & 4095) >> 1;
            s = fmaf(c_lo[k], Aq[idx], s);
            s = fmaf(c_hi[k], d1[idx], s);
        }
        zg[i] = zrow[i] + s;
    }
}

// ---------------- mix: out = gelu(W_mix @ s + b_mix) * mask, + pool partials ----------------
// LDS exactly 32 KB (stT reused for the pool reduction) -> 5 blocks/CU.
// W_mixT from global with explicit 1-step prefetch.

__global__ __launch_bounds__(256) void mix_kernel(const float* __restrict__ s,
                                                  const float* __restrict__ WmT_g,
                                                  const float* __restrict__ b_mix,
                                                  const float* __restrict__ mask,
                                                  float* __restrict__ out,
                                                  float* __restrict__ pool_part) {
    __shared__ float stT[HD * 64];     // [h][l]  32 KB (reused for pool reduce)

    int bi = blockIdx.x;
    int b = bi >> 6;
    int blkl = bi & 63;
    int l0 = blkl << 6;
    int tid = threadIdx.x;

    for (int i = tid; i < HD * 16; i += 256) {
        int hh = i >> 4, l4 = (i & 15) << 2;
        float4 sv = *(const float4*)&s[((size_t)b * HD + hh) * LL + l0 + l4];
        *(float4*)&stT[hh * 64 + l4] = sv;
    }
    __syncthreads();

    int gq = tid & 31, lq = tid >> 5;
    int g0 = gq << 2, lb = lq << 3;

    float4 acc[8];
#pragma unroll
    for (int j = 0; j < 8; ++j) acc[j] = make_float4(0.f, 0.f, 0.f, 0.f);

    float4 nw0 = *(const float4*)&WmT_g[0 * HD + g0];
    float4 nw1 = *(const float4*)&WmT_g[1 * HD + g0];
    float4 nw2 = *(const float4*)&WmT_g[2 * HD + g0];
    float4 nw3 = *(const float4*)&WmT_g[3 * HD + g0];
#pragma unroll 4
    for (int h0 = 0; h0 < HD; h0 += 4) {
        float4 wv0 = nw0, wv1 = nw1, wv2 = nw2, wv3 = nw3;
        if (h0 + 4 < HD) {
            nw0 = *(const float4*)&WmT_g[(h0 + 4) * HD + g0];
            nw1 = *(const float4*)&WmT_g[(h0 + 5) * HD + g0];
            nw2 = *(const float4*)&WmT_g[(h0 + 6) * HD + g0];
            nw3 = *(const float4*)&WmT_g[(h0 + 7) * HD + g0];
        }
        const float* sp0 = &stT[h0 * 64 + lb];
#pragma unroll
        for (int jp = 0; jp < 4; ++jp) {
            float2 t0 = *(const float2*)(sp0 + 2 * jp);
            float2 t1 = *(const float2*)(sp0 + 64 + 2 * jp);
            float2 t2 = *(const float2*)(sp0 + 128 + 2 * jp);
            float2 t3 = *(const float2*)(sp0 + 192 + 2 * jp);
            float4 a = acc[2 * jp];
            a.x = fmaf(wv0.x, t0.x, a.x); a.y = fmaf(wv0.y, t0.x, a.y);
            a.z = fmaf(wv0.z, t0.x, a.z); a.w = fmaf(wv0.w, t0.x, a.w);
            a.x = fmaf(wv1.x, t1.x, a.x); a.y = fmaf(wv1.y, t1.x, a.y);
            a.z = fmaf(wv1.z, t1.x, a.z); a.w = fmaf(wv1.w, t1.x, a.w);
            a.x = fmaf(wv2.x, t2.x, a.x); a.y = fmaf(wv2.y, t2.x, a.y);
            a.z = fmaf(wv2.z, t2.x, a.z); a.w = fmaf(wv2.w, t2.x, a.w);
            a.x = fmaf(wv3.x, t3.x, a.x); a.y = fmaf(wv3.y, t3.x, a.y);
            a.z = fmaf(wv3.z, t3.x, a.z); a.w = fmaf(wv3.w, t3.x, a.w);
            acc[2 * jp] = a;
            float4 c = acc[2 * jp + 1];
            c.x = fmaf(wv0.x, t0.y, c.x); c.y = fmaf(wv0.y, t0.y, c.y);
            c.z = fmaf(wv0.z, t0.y, c.z); c.w = fmaf(wv0.w, t0.y, c.w);
            c.x = fmaf(wv1.x, t1.y, c.x); c.y = fmaf(wv1.y, t1.y, c.y);
            c.z = fmaf(wv1.z, t1.y, c.z); c.w = fmaf(wv1.w, t1.y, c.w);
            c.x = fmaf(wv2.x, t2.y, c.x); c.y = fmaf(wv2.y, t2.y, c.y);
            c.z = fmaf(wv2.z, t2.y, c.z); c.w = fmaf(wv2.w, t2.y, c.w);
            c.x = fmaf(wv3.x, t3.y, c.x); c.y = fmaf(wv3.y, t3.y, c.y);
            c.z = fmaf(wv3.z, t3.y, c.z); c.w = fmaf(wv3.w, t3.y, c.w);
            acc[2 * jp + 1] = c;
        }
    }

    float4 bm = *(const float4*)&b_mix[g0];
    float4 pacc = make_float4(0.f, 0.f, 0.f, 0.f);
#pragma unroll
    for (int j = 0; j < 8; ++j) {
        int l = l0 + lb + j;
        float mk = mask[(size_t)b * LL + l];
        float4 v = acc[j];
        v.x = gelu_exact(v.x + bm.x) * mk;
        v.y = gelu_exact(v.y + bm.y) * mk;
        v.z = gelu_exact(v.z + bm.z) * mk;
        v.w = gelu_exact(v.w + bm.w) * mk;
        *(float4*)&out[((size_t)b * LL + l) * HD + g0] = v;
        pacc.x = fmaf(v.x, mk, pacc.x);
        pacc.y = fmaf(v.y, mk, pacc.y);
        pacc.z = fmaf(v.z, mk, pacc.z);
        pacc.w = fmaf(v.w, mk, pacc.w);
    }
    __syncthreads();   // all stT reads done; reuse for pool reduction
    ((float4*)stT)[lq * 32 + gq] = pacc;
    __syncthreads();
    if (tid < 32) {
        float4 sum = ((float4*)stT)[tid];
#pragma unroll
        for (int q = 1; q < 8; ++q) {
            float4 p = ((float4*)stT)[q * 32 + tid];
            sum.x += p.x; sum.y += p.y; sum.z += p.z; sum.w += p.w;
        }
        *(float4*)&pool_part[((size_t)(b * 64 + blkl)) * HD + (tid << 2)] = sum;
    }
}

// ---------------- finalize: pool + lam mean/max ----------------

__global__ void finalize_kernel(const float* __restrict__ pool_part,
                                const float* __restrict__ denom,
                                const float* __restrict__ lam_ws,
                                float* __restrict__ d_out) {
    const size_t OUT1 = (size_t)BB * LL * HD;
    const size_t OUT2 = OUT1 + (size_t)BB * HD;
    const size_t OUT3 = OUT2 + BB;
    int b = blockIdx.x, tid = threadIdx.x;
    __shared__ float rsum[256], rmax[256];
    if (tid < 128) {
        float s = 0.f;
        for (int blk = 0; blk < 64; ++blk)
            s += pool_part[((size_t)(b * 64 + blk)) * HD + tid];
        d_out[OUT1 + (size_t)b * HD + tid] = s / denom[b];
    }
    float v0 = lam_ws[(size_t)b * 512 + tid];
    float v1 = lam_ws[(size_t)b * 512 + 256 + tid];
    rsum[tid] = v0 + v1;
    rmax[tid] = fmaxf(v0, v1);
    __syncthreads();
    for (int st = 128; st > 0; st >>= 1) {
        if (tid < st) {
            rsum[tid] += rsum[tid + st];
            rmax[tid] = fmaxf(rmax[tid], rmax[tid + st]);
        }
        __syncthreads();
    }
    if (tid == 0) {
        d_out[OUT2 + b] = rsum[0] / 512.0f;
        d_out[OUT3 + b] = rmax[0];
    }
}

// ---------------- launch ----------------

extern "C" void kernel_launch(void* const* d_in, const int* in_sizes, int n_in,
                              void* d_out, int out_size, void* d_ws, size_t ws_size,
                              hipStream_t stream) {
    (void)in_sizes; (void)n_in; (void)out_size; (void)ws_size;
    const float* x      = (const float*)d_in[0];
    const float* mask   = (const float*)d_in[1];
    const float* flow   = (const float*)d_in[2];
    const float* W_in   = (const float*)d_in[3];
    const float* b_in   = (const float*)d_in[4];
    const float* W_mix  = (const float*)d_in[5];
    const float* b_mix  = (const float*)d_in[6];
    const float* lam_raw= (const float*)d_in[7];
    const float* Wgb    = (const float*)d_in[8];
    const float* bgb    = (const float*)d_in[9];
    const float* Wg     = (const float*)d_in[10];
    const float* bg     = (const float*)d_in[11];

    float* ws = (float*)d_ws;
    float* z         = ws;                                   // B*H*L = 8388608
    float* film_ws   = z + (size_t)BB * HD * LL;             // B*4*256 = 16384
    float* gate_ws   = film_ws + (size_t)BB * 4 * 256;       // 64
    float* lam_ws    = gate_ws + 64;                         // B*4*128 = 8192
    float* denom_ws  = lam_ws + (size_t)BB * 4 * 128;        // 16
    float* pool_part = denom_ws + 16;                        // B*64*128 = 131072
    float* WmT       = pool_part + (size_t)BB * 64 * HD;     // 16384
    float* WinT      = WmT + HD * HD;                        // 8192

    float* out = (float*)d_out;

    hipLaunchKernelGGL(prep_kernel, dim3(176), dim3(256), 0, stream,
                       W_mix, WmT, W_in, WinT, flow, Wgb, bgb, Wg, bg,
                       film_ws, gate_ws, mask, denom_ws);
    hipLaunchKernelGGL(zproj_kernel, dim3(BB * (LL / 64)), dim3(256), 0, stream,
                       x, mask, WinT, b_in, z);
    hipLaunchKernelGGL(wavelet_kernel, dim3(BB * HD), dim3(256), 0, stream,
                       z, film_ws, gate_ws, lam_raw, lam_ws);
    hipLaunchKernelGGL(mix_kernel, dim3(BB * (LL / 64)), dim3(256), 0, stream,
                       z, WmT, b_mix, mask, out, pool_part);
    hipLaunchKernelGGL(finalize_kernel, dim3(BB), dim3(256), 0, stream,
                       pool_part, denom_ws, lam_ws, out);
}

// Round 4
// 83.395 us; speedup vs baseline: 1.9807x; 1.4253x over previous
//
#include <hip/hip_runtime.h>
#include <math.h>

#define BB 16
#define LL 4096
#define CC 64
#define HD 128

typedef __attribute__((ext_vector_type(8))) short short8;
typedef __attribute__((ext_vector_type(8))) unsigned short ushort8;
typedef __attribute__((ext_vector_type(4))) float floatx4;

__constant__ float c_lo[8] = {
    -0.010597401784997278f, 0.032883011666982945f, 0.030841381835986965f,
    -0.18703481171888114f, -0.02798376941698385f, 0.6308807679295904f,
    0.7148465705525415f, 0.23037781330885523f};
__constant__ float c_hi[8] = {
    -0.23037781330885523f, 0.7148465705525415f, -0.6308807679295904f,
    -0.02798376941698385f, 0.18703481171888114f, 0.030841381835986965f,
    -0.032883011666982945f, -0.010597401784997278f};

__device__ __forceinline__ float gelu_exact(float x) {
    return 0.5f * x * (1.0f + erff(x * 0.70710678118654752440f));
}
__device__ __forceinline__ unsigned short f2b(float f) {   // f32 -> bf16 RNE
    unsigned int u = __float_as_uint(f);
    u = u + 0x7FFFu + ((u >> 16) & 1u);
    return (unsigned short)(u >> 16);
}
__device__ __forceinline__ float b2f(unsigned short s) {
    return __uint_as_float(((unsigned int)s) << 16);
}

// ---------------- prep: W packs (MFMA frag layout) + FiLM + denom ----------------
// Ain  (zproj A, A[m=h][k=c]):  idx = ((c>>3)*128 + h)*8 + (c&7)
// Bmix (mix  B, B[k=h][n=g]):   idx = ((h>>3)*128 + g)*8 + (h&7)

__global__ __launch_bounds__(256) void prep_kernel(
    const float* __restrict__ W_in, unsigned short* __restrict__ Ain,
    const float* __restrict__ W_mix, unsigned short* __restrict__ Bmix,
    const float* __restrict__ flow, const float* __restrict__ Wgb,
    const float* __restrict__ bgb, const float* __restrict__ Wg,
    const float* __restrict__ bg, float* __restrict__ film_ws,
    float* __restrict__ gate_ws,
    const float* __restrict__ mask, float* __restrict__ denom) {
    __shared__ float red[256];
    int blk = blockIdx.x;
    int tid = threadIdx.x;
    if (blk < 32) {
        int q = blk * 256 + tid;                    // 8192
        int h = (q >> 3) & 127;
        int c = ((q >> 10) << 3) | (q & 7);
        Ain[q] = f2b(W_in[h * CC + c]);
    } else if (blk < 96) {
        int q = (blk - 32) * 256 + tid;             // 16384
        int g = (q >> 3) & 127;
        int h = ((q >> 10) << 3) | (q & 7);
        Bmix[q] = f2b(W_mix[g * HD + h]);
    } else if (blk < 160) {
        int bf = blk - 96;                          // b*4 + f
        int f = bf & 3;
        int b = bf >> 2;
        const float* fl = flow + b * 24;
        const float* wrow = Wgb + ((size_t)(f * 256 + tid)) * 24;
        float acc = bgb[f * 256 + tid];
#pragma unroll
        for (int j = 0; j < 24; ++j) acc = fmaf(wrow[j], fl[j], acc);
        film_ws[(size_t)bf * 256 + tid] = acc;
        if (tid == 0) {
            float g = bg[f];
#pragma unroll
            for (int j = 0; j < 24; ++j) g = fmaf(Wg[f * 24 + j], fl[j], g);
            gate_ws[bf] = 1.0f / (1.0f + expf(-g));
        }
    } else {
        int b = blk - 160;
        float s = 0.f;
        for (int i = tid; i < LL; i += 256) s += mask[(size_t)b * LL + i];
        red[tid] = s; __syncthreads();
        for (int st = 128; st > 0; st >>= 1) {
            if (tid < st) red[tid] += red[tid + st];
            __syncthreads();
        }
        if (tid == 0) denom[b] = fmaxf(red[0], 1.0f);
    }
}

// ---------------- zproj: MFMA GEMM, z_bf[b][h][l] = bf16(W_in @ (x*mask) + b_in) ----------------
// LDS-free. Block = 128h x 64l tile, 4 waves (2h-halves x 2l-quarters).
// B-frags built on the fly from x (c = K dim is contiguous in x[b][l][c]).

__global__ __launch_bounds__(256) void zproj_kernel(const float* __restrict__ x,
                                                    const float* __restrict__ mask,
                                                    const unsigned short* __restrict__ Ain,
                                                    const float* __restrict__ b_in,
                                                    unsigned short* __restrict__ z_bf) {
    int blk = blockIdx.x;
    int b = blk >> 6;
    int l0 = (blk & 63) << 6;
    int tid = threadIdx.x;
    int lane = tid & 63;
    int w = tid >> 6;
    int h_half = w >> 1;
    int l_q = w & 1;
    int ln15 = lane & 15, lq4 = lane >> 4;

    int lr0 = l0 + l_q * 32 + ln15;
    int lr1 = lr0 + 16;
    float mk0 = mask[(size_t)b * LL + lr0];
    float mk1 = mask[(size_t)b * LL + lr1];

    floatx4 acc[4][2];
#pragma unroll
    for (int i = 0; i < 4; ++i)
#pragma unroll
        for (int j = 0; j < 2; ++j) acc[i][j] = (floatx4){0.f, 0.f, 0.f, 0.f};

#pragma unroll
    for (int ks = 0; ks < 2; ++ks) {
        int c0 = ks * 32 + (lq4 << 3);
        short8 bf0, bf1;
        {
            const float* xp = x + ((size_t)b * LL + lr0) * CC + c0;
            float4 xa = *(const float4*)xp;
            float4 xb = *(const float4*)(xp + 4);
            bf0[0] = (short)f2b(xa.x * mk0); bf0[1] = (short)f2b(xa.y * mk0);
            bf0[2] = (short)f2b(xa.z * mk0); bf0[3] = (short)f2b(xa.w * mk0);
            bf0[4] = (short)f2b(xb.x * mk0); bf0[5] = (short)f2b(xb.y * mk0);
            bf0[6] = (short)f2b(xb.z * mk0); bf0[7] = (short)f2b(xb.w * mk0);
        }
        {
            const float* xp = x + ((size_t)b * LL + lr1) * CC + c0;
            float4 xa = *(const float4*)xp;
            float4 xb = *(const float4*)(xp + 4);
            bf1[0] = (short)f2b(xa.x * mk1); bf1[1] = (short)f2b(xa.y * mk1);
            bf1[2] = (short)f2b(xa.z * mk1); bf1[3] = (short)f2b(xa.w * mk1);
            bf1[4] = (short)f2b(xb.x * mk1); bf1[5] = (short)f2b(xb.y * mk1);
            bf1[6] = (short)f2b(xb.z * mk1); bf1[7] = (short)f2b(xb.w * mk1);
        }
        int koct = ks * 4 + lq4;
#pragma unroll
        for (int ht = 0; ht < 4; ++ht) {
            short8 af = *(const short8*)(Ain + (size_t)koct * 1024 +
                                         (h_half * 64 + ht * 16 + ln15) * 8);
            acc[ht][0] = __builtin_amdgcn_mfma_f32_16x16x32_bf16(af, bf0, acc[ht][0], 0, 0, 0);
            acc[ht][1] = __builtin_amdgcn_mfma_f32_16x16x32_bf16(af, bf1, acc[ht][1], 0, 0, 0);
        }
    }

#pragma unroll
    for (int ht = 0; ht < 4; ++ht) {
#pragma unroll
        for (int r = 0; r < 4; ++r) {
            int h = h_half * 64 + ht * 16 + (lq4 << 2) + r;
            float bi = b_in[h];
            z_bf[((size_t)(b * HD + h)) * LL + lr0] = f2b(acc[ht][0][r] + bi);
            z_bf[((size_t)(b * HD + h)) * LL + lr1] = f2b(acc[ht][1][r] + bi);
        }
    }
}

// ---------------- per-row wavelet (bf16 I/O), writes s_bf = bf16(z + z_rec) ----------------

__global__ __launch_bounds__(256) void wavelet_kernel(const unsigned short* __restrict__ z_bf,
                                                      unsigned short* __restrict__ s_bf,
                                                      const float* __restrict__ film_ws,
                                                      const float* __restrict__ gate_ws,
                                                      const float* __restrict__ lam_raw,
                                                      float* __restrict__ lam_ws) {
    __shared__ float zrow[4096];
    __shared__ float d1[2048];
    __shared__ float d2[1024];
    __shared__ float Aq[2048];
    __shared__ float Bq[1024];

    int blk = blockIdx.x;
    int b = blk >> 7;
    int h = blk & 127;
    int tid = threadIdx.x;
    const unsigned short* zg = z_bf + ((size_t)(b * HD + h)) * LL;
    unsigned short* sg = s_bf + ((size_t)(b * HD + h)) * LL;

    for (int i = tid; i < 512; i += 256) {
        ushort8 v = *(const ushort8*)(zg + (i << 3));
#pragma unroll
        for (int j = 0; j < 8; ++j) zrow[(i << 3) + j] = b2f(v[j]);
    }
    __syncthreads();

    for (int n = tid; n < 2048; n += 256) {
        float lo = 0.f, hi = 0.f;
#pragma unroll
        for (int k = 0; k < 8; ++k) {
            float v = zrow[(2 * n + k) & 4095];
            lo = fmaf(c_lo[k], v, lo);
            hi = fmaf(c_hi[k], v, hi);
        }
        Aq[n] = lo; d1[n] = hi;
    }
    __syncthreads();
    for (int n = tid; n < 1024; n += 256) {
        float lo = 0.f, hi = 0.f;
#pragma unroll
        for (int k = 0; k < 8; ++k) {
            float v = Aq[(2 * n + k) & 2047];
            lo = fmaf(c_lo[k], v, lo);
            hi = fmaf(c_hi[k], v, hi);
        }
        Bq[n] = lo; d2[n] = hi;
    }
    __syncthreads();
    for (int n = tid; n < 512; n += 256) {
        float lo = 0.f, hi = 0.f;
#pragma unroll
        for (int k = 0; k < 8; ++k) {
            float v = Bq[(2 * n + k) & 1023];
            lo = fmaf(c_lo[k], v, lo);
            hi = fmaf(c_hi[k], v, hi);
        }
        Aq[n] = lo; Aq[512 + n] = hi;
    }
    __syncthreads();

    float sc0, sh0, sc1, sh1, sc2, sh2, sc3, sh3;
    {
        int base = b * 4;
#define FILM_COEF(bd, SC, SH)                                              \
        {   float ga = film_ws[((size_t)(base + bd)) * 256 + h];           \
            float be = film_ws[((size_t)(base + bd)) * 256 + 128 + h];     \
            float gt = gate_ws[base + bd];                                 \
            SC = 1.0f + gt * ga; SH = gt * be; }
        FILM_COEF(0, sc0, sh0) FILM_COEF(1, sc1, sh1)
        FILM_COEF(2, sc2, sh2) FILM_COEF(3, sc3, sh3)
#undef FILM_COEF
    }
    float s0 = 0.f, s1 = 0.f, s2 = 0.f, s3 = 0.f;
    for (int i = tid; i < 512; i += 256) {
        float v = fmaf(Aq[i], sc0, sh0); Aq[i] = v; s0 += fabsf(v);
    }
    for (int i = tid; i < 2048; i += 256) {
        float v = fmaf(d1[i], sc1, sh1); d1[i] = v; s1 += fabsf(v);
    }
    for (int i = tid; i < 1024; i += 256) {
        float v = fmaf(d2[i], sc2, sh2); d2[i] = v; s2 += fabsf(v);
    }
    for (int i = tid; i < 512; i += 256) {
        float v = fmaf(Aq[512 + i], sc3, sh3); Aq[512 + i] = v; s3 += fabsf(v);
    }
#pragma unroll
    for (int off = 32; off > 0; off >>= 1) {
        s0 += __shfl_xor(s0, off);
        s1 += __shfl_xor(s1, off);
        s2 += __shfl_xor(s2, off);
        s3 += __shfl_xor(s3, off);
    }
    if ((tid & 63) == 0)
        ((float4*)Bq)[tid >> 6] = make_float4(s0, s1, s2, s3);
    __syncthreads();
    float4 r0 = ((const float4*)Bq)[0];
    float4 r1 = ((const float4*)Bq)[1];
    float4 r2 = ((const float4*)Bq)[2];
    float4 r3 = ((const float4*)Bq)[3];
    float lam0 = log1pf(expf(lam_raw[0])) * ((r0.x + r1.x + r2.x + r3.x) * (1.0f / 512.f));
    float lam1 = log1pf(expf(lam_raw[1])) * ((r0.y + r1.y + r2.y + r3.y) * (1.0f / 2048.f));
    float lam2 = log1pf(expf(lam_raw[2])) * ((r0.z + r1.z + r2.z + r3.z) * (1.0f / 1024.f));
    float lam3 = log1pf(expf(lam_raw[3])) * ((r0.w + r1.w + r2.w + r3.w) * (1.0f / 512.f));
    if (tid < 4) {
        float lam = (tid == 0) ? lam0 : (tid == 1) ? lam1 : (tid == 2) ? lam2 : lam3;
        lam_ws[((size_t)(b * 4 + tid)) * 128 + h] = lam;
    }
#define STHR(p, lam) { float v = (p); float av = fabsf(v) - (lam); (p) = (av > 0.f) ? copysignf(av, v) : 0.f; }
    for (int i = tid; i < 512; i += 256)  STHR(Aq[i], lam0)
    for (int i = tid; i < 2048; i += 256) STHR(d1[i], lam1)
    for (int i = tid; i < 1024; i += 256) STHR(d2[i], lam2)
    for (int i = tid; i < 512; i += 256)  STHR(Aq[512 + i], lam3)
#undef STHR
    __syncthreads();

    for (int i = tid; i < 1024; i += 256) {
        int par = i & 1;
        float s = 0.f;
#pragma unroll
        for (int j = 0; j < 4; ++j) {
            int k = 2 * j + par;
            int idx = ((i - k) & 1023) >> 1;
            s = fmaf(c_lo[k], Aq[idx], s);
            s = fmaf(c_hi[k], Aq[512 + idx], s);
        }
        Bq[i] = s;
    }
    __syncthreads();
    for (int i = tid; i < 2048; i += 256) {
        int par = i & 1;
        float s = 0.f;
#pragma unroll
        for (int j = 0; j < 4; ++j) {
            int k = 2 * j + par;
            int idx = ((i - k) & 2047) >> 1;
            s = fmaf(c_lo[k], Bq[idx], s);
            s = fmaf(c_hi[k], d2[idx], s);
        }
        Aq[i] = s;
    }
    __syncthreads();
    for (int i = tid; i < 4096; i += 256) {
        int par = i & 1;
        float s = 0.f;
#pragma unroll
        for (int j = 0; j < 4; ++j) {
            int k = 2 * j + par;
            int idx = ((i - k) & 4095) >> 1;
            s = fmaf(c_lo[k], Aq[idx], s);
            s = fmaf(c_hi[k], d1[idx], s);
        }
        sg[i] = f2b(zrow[i] + s);
    }
}

// ---------------- repack: s_bf[h][l] -> P (A-frag layout, h-octs per lane) ----------------
// P per b: panel p = l>>4 (256 panels x 2048): idx = (h>>3)*128 + (l&15)*8 + (h&7).
// Block = 32l x 128h chunk; LDS transpose with XOR word-swizzle.

__global__ __launch_bounds__(256) void repack_kernel(const unsigned short* __restrict__ s_bf,
                                                     unsigned short* __restrict__ P) {
    __shared__ unsigned int T[128 * 16];
    int blk = blockIdx.x;
    int b = blk >> 7;
    int lc = blk & 127;
    int l0 = lc << 5;
    int tid = threadIdx.x;
    const unsigned int* src = (const unsigned int*)s_bf;
#pragma unroll
    for (int r = 0; r < 8; ++r) {
        int idx = tid + (r << 8);                 // 0..2047
        int h = idx >> 4, lp = idx & 15;
        unsigned int v = src[(size_t)(b * HD + h) * (LL / 2) + (l0 >> 1) + lp];
        T[(h << 4) + (lp ^ (h & 15))] = v;
    }
    __syncthreads();
    unsigned short* Pb = P + (size_t)b * (HD * LL) + (size_t)(lc << 1) * 2048;
#pragma unroll
    for (int c = 0; c < 2; ++c) {
        int q = tid + (c << 8);                   // 0..511
        int pi = q >> 8, o8 = q & 255;
        int hoct = o8 >> 4, lidx = o8 & 15;
        int l = (pi << 4) + lidx;                 // 0..31
        ushort8 ov;
#pragma unroll
        for (int j = 0; j < 8; ++j) {
            int hh = (hoct << 3) + j;
            unsigned int w2 = T[(hh << 4) + ((l >> 1) ^ (hh & 15))];
            ov[j] = (l & 1) ? (unsigned short)(w2 >> 16) : (unsigned short)(w2 & 0xffffu);
        }
        *(ushort8*)(Pb + (size_t)pi * 2048 + (hoct << 7) + (lidx << 3)) = ov;
    }
}

// ---------------- mix: MFMA GEMM, out = gelu(W_mix @ s + b_mix) * mask, + pool ----------------
// LDS-free (1 KB pool buf). A = P (M=l), B = Bmix (N=g): D rows=l, cols=g ->
// out[b][l][g] writes g-contiguous.

__global__ __launch_bounds__(256) void mix_kernel(const unsigned short* __restrict__ P,
                                                  const unsigned short* __restrict__ Bmix,
                                                  const float* __restrict__ b_mix,
                                                  const float* __restrict__ mask,
                                                  float* __restrict__ out,
                                                  float* __restrict__ pool_part) {
    __shared__ float pbuf[2][HD];
    int blk = blockIdx.x;
    int b = blk >> 5;
    int lt128 = blk & 31;
    int l0 = lt128 << 7;
    int tid = threadIdx.x;
    int lane = tid & 63;
    int w = tid >> 6;
    int l_half = w >> 1, g_half = w & 1;
    int ln15 = lane & 15, lq4 = lane >> 4;

    floatx4 acc[4][4];
#pragma unroll
    for (int i = 0; i < 4; ++i)
#pragma unroll
        for (int j = 0; j < 4; ++j) acc[i][j] = (floatx4){0.f, 0.f, 0.f, 0.f};

    const unsigned short* Pb = P + (size_t)b * (HD * LL) +
                               (size_t)((l0 >> 4) + l_half * 4) * 2048 + ln15 * 8;
    const unsigned short* Bb = Bmix + (g_half * 64 + ln15) * 8;

#pragma unroll 2
    for (int ks = 0; ks < 4; ++ks) {
        int koct = ks * 4 + lq4;
        short8 a[4], bb[4];
#pragma unroll
        for (int lt = 0; lt < 4; ++lt)
            a[lt] = *(const short8*)(Pb + (size_t)lt * 2048 + (koct << 7));
#pragma unroll
        for (int gt = 0; gt < 4; ++gt)
            bb[gt] = *(const short8*)(Bb + (size_t)koct * 1024 + gt * 128);
#pragma unroll
        for (int lt = 0; lt < 4; ++lt)
#pragma unroll
            for (int gt = 0; gt < 4; ++gt)
                acc[lt][gt] = __builtin_amdgcn_mfma_f32_16x16x32_bf16(a[lt], bb[gt], acc[lt][gt], 0, 0, 0);
    }

    int gcol[4]; float bmv[4]; float pacc[4];
#pragma unroll
    for (int gt = 0; gt < 4; ++gt) {
        gcol[gt] = g_half * 64 + gt * 16 + ln15;
        bmv[gt] = b_mix[gcol[gt]];
        pacc[gt] = 0.f;
    }
#pragma unroll
    for (int lt = 0; lt < 4; ++lt) {
#pragma unroll
        for (int r = 0; r < 4; ++r) {
            int l = l0 + l_half * 64 + lt * 16 + (lq4 << 2) + r;
            float mkv = mask[(size_t)b * LL + l];
            float* orow = out + ((size_t)b * LL + l) * HD;
#pragma unroll
            for (int gt = 0; gt < 4; ++gt) {
                float v = gelu_exact(acc[lt][gt][r] + bmv[gt]) * mkv;
                orow[gcol[gt]] = v;
                pacc[gt] = fmaf(v, mkv, pacc[gt]);
            }
        }
    }
#pragma unroll
    for (int gt = 0; gt < 4; ++gt) {
        pacc[gt] += __shfl_xor(pacc[gt], 16);
        pacc[gt] += __shfl_xor(pacc[gt], 32);
    }
    if (lane < 16) {
#pragma unroll
        for (int gt = 0; gt < 4; ++gt)
            pbuf[l_half][g_half * 64 + gt * 16 + lane] = pacc[gt];
    }
    __syncthreads();
    if (tid < HD)
        pool_part[((size_t)(b * 32 + lt128)) * HD + tid] = pbuf[0][tid] + pbuf[1][tid];
}

// ---------------- finalize: pool + lam mean/max ----------------

__global__ void finalize_kernel(const float* __restrict__ pool_part,
                                const float* __restrict__ denom,
                                const float* __restrict__ lam_ws,
                                float* __restrict__ d_out) {
    const size_t OUT1 = (size_t)BB * LL * HD;
    const size_t OUT2 = OUT1 + (size_t)BB * HD;
    const size_t OUT3 = OUT2 + BB;
    int b = blockIdx.x, tid = threadIdx.x;
    __shared__ float rsum[256], rmax[256];
    if (tid < 128) {
        float s = 0.f;
        for (int blk = 0; blk < 32; ++blk)
            s += pool_part[((size_t)(b * 32 + blk)) * HD + tid];
        d_out[OUT1 + (size_t)b * HD + tid] = s / denom[b];
    }
    float v0 = lam_ws[(size_t)b * 512 + tid];
    float v1 = lam_ws[(size_t)b * 512 + 256 + tid];
    rsum[tid] = v0 + v1;
    rmax[tid] = fmaxf(v0, v1);
    __syncthreads();
    for (int st = 128; st > 0; st >>= 1) {
        if (tid < st) {
            rsum[tid] += rsum[tid + st];
            rmax[tid] = fmaxf(rmax[tid], rmax[tid + st]);
        }
        __syncthreads();
    }
    if (tid == 0) {
        d_out[OUT2 + b] = rsum[0] / 512.0f;
        d_out[OUT3 + b] = rmax[0];
    }
}

// ---------------- launch ----------------

extern "C" void kernel_launch(void* const* d_in, const int* in_sizes, int n_in,
                              void* d_out, int out_size, void* d_ws, size_t ws_size,
                              hipStream_t stream) {
    (void)in_sizes; (void)n_in; (void)out_size; (void)ws_size;
    const float* x      = (const float*)d_in[0];
    const float* mask   = (const float*)d_in[1];
    const float* flow   = (const float*)d_in[2];
    const float* W_in   = (const float*)d_in[3];
    const float* b_in   = (const float*)d_in[4];
    const float* W_mix  = (const float*)d_in[5];
    const float* b_mix  = (const float*)d_in[6];
    const float* lam_raw= (const float*)d_in[7];
    const float* Wgb    = (const float*)d_in[8];
    const float* bgb    = (const float*)d_in[9];
    const float* Wg     = (const float*)d_in[10];
    const float* bg     = (const float*)d_in[11];

    // ws layout (bytes): [0,16M) z_bf, later reused as P; [16M,32M) s_bf; then f32 + packs
    unsigned short* zP   = (unsigned short*)d_ws;                 // 8388608 ushort
    unsigned short* s_bf = zP + (size_t)BB * HD * LL;             // 8388608 ushort
    float* film_ws   = (float*)(s_bf + (size_t)BB * HD * LL);     // 16384
    float* gate_ws   = film_ws + BB * 4 * 256;                    // 64
    float* lam_ws    = gate_ws + 64;                              // 8192
    float* denom_ws  = lam_ws + BB * 4 * 128;                     // 16
    float* pool_part = denom_ws + 16;                             // 16*32*128 = 65536
    unsigned short* Ain  = (unsigned short*)(pool_part + BB * 32 * HD);  // 8192 ushort
    unsigned short* Bmix = Ain + HD * CC;                                // 16384 ushort

    float* out = (float*)d_out;

    hipLaunchKernelGGL(prep_kernel, dim3(176), dim3(256), 0, stream,
                       W_in, Ain, W_mix, Bmix, flow, Wgb, bgb, Wg, bg,
                       film_ws, gate_ws, mask, denom_ws);
    hipLaunchKernelGGL(zproj_kernel, dim3(BB * (LL / 64)), dim3(256), 0, stream,
                       x, mask, Ain, b_in, zP);
    hipLaunchKernelGGL(wavelet_kernel, dim3(BB * HD), dim3(256), 0, stream,
                       zP, s_bf, film_ws, gate_ws, lam_raw, lam_ws);
    hipLaunchKernelGGL(repack_kernel, dim3(BB * (LL / 32)), dim3(256), 0, stream,
                       s_bf, zP);   // P overwrites z_bf (wavelet already consumed it)
    hipLaunchKernelGGL(mix_kernel, dim3(BB * (LL / 128)), dim3(256), 0, stream,
                       zP, Bmix, b_mix, mask, out, pool_part);
    hipLaunchKernelGGL(finalize_kernel, dim3(BB), dim3(256), 0, stream,
                       pool_part, denom_ws, lam_ws, out);
}

// Round 5
// 75.001 us; speedup vs baseline: 2.2024x; 1.1119x over previous
//
#include <hip/hip_runtime.h>
#include <math.h>

#define BB 16
#define LL 4096
#define CC 64
#define HD 128

typedef __attribute__((ext_vector_type(8))) short short8;
typedef __attribute__((ext_vector_type(8))) unsigned short ushort8;
typedef __attribute__((ext_vector_type(4))) float floatx4;

__constant__ float c_lo[8] = {
    -0.010597401784997278f, 0.032883011666982945f, 0.030841381835986965f,
    -0.18703481171888114f, -0.02798376941698385f, 0.6308807679295904f,
    0.7148465705525415f, 0.23037781330885523f};
__constant__ float c_hi[8] = {
    -0.23037781330885523f, 0.7148465705525415f, -0.6308807679295904f,
    -0.02798376941698385f, 0.18703481171888114f, 0.030841381835986965f,
    -0.032883011666982945f, -0.010597401784997278f};

__device__ __forceinline__ float gelu_exact(float x) {
    return 0.5f * x * (1.0f + erff(x * 0.70710678118654752440f));
}
__device__ __forceinline__ unsigned short f2b(float f) {   // f32 -> bf16 RNE
    unsigned int u = __float_as_uint(f);
    u = u + 0x7FFFu + ((u >> 16) & 1u);
    return (unsigned short)(u >> 16);
}
__device__ __forceinline__ float b2f(unsigned short s) {
    return __uint_as_float(((unsigned int)s) << 16);
}

// ---------------- prep: W packs (MFMA frag layout) + FiLM + denom ----------------
// Ain  (zproj A, A[m=h][k=c]):  idx = ((c>>3)*128 + h)*8 + (c&7)
// Bmix (mix  B, B[k=h][n=g]):   idx = ((h>>3)*128 + g)*8 + (h&7)

__global__ __launch_bounds__(256) void prep_kernel(
    const float* __restrict__ W_in, unsigned short* __restrict__ Ain,
    const float* __restrict__ W_mix, unsigned short* __restrict__ Bmix,
    const float* __restrict__ flow, const float* __restrict__ Wgb,
    const float* __restrict__ bgb, const float* __restrict__ Wg,
    const float* __restrict__ bg, float* __restrict__ film_ws,
    float* __restrict__ gate_ws,
    const float* __restrict__ mask, float* __restrict__ denom) {
    __shared__ float red[256];
    int blk = blockIdx.x;
    int tid = threadIdx.x;
    if (blk < 32) {
        int q = blk * 256 + tid;                    // 8192
        int h = (q >> 3) & 127;
        int c = ((q >> 10) << 3) | (q & 7);
        Ain[q] = f2b(W_in[h * CC + c]);
    } else if (blk < 96) {
        int q = (blk - 32) * 256 + tid;             // 16384
        int g = (q >> 3) & 127;
        int h = ((q >> 10) << 3) | (q & 7);
        Bmix[q] = f2b(W_mix[g * HD + h]);
    } else if (blk < 160) {
        int bf = blk - 96;                          // b*4 + f
        int f = bf & 3;
        int b = bf >> 2;
        const float* fl = flow + b * 24;
        const float* wrow = Wgb + ((size_t)(f * 256 + tid)) * 24;
        float acc = bgb[f * 256 + tid];
#pragma unroll
        for (int j = 0; j < 24; ++j) acc = fmaf(wrow[j], fl[j], acc);
        film_ws[(size_t)bf * 256 + tid] = acc;
        if (tid == 0) {
            float g = bg[f];
#pragma unroll
            for (int j = 0; j < 24; ++j) g = fmaf(Wg[f * 24 + j], fl[j], g);
            gate_ws[bf] = 1.0f / (1.0f + expf(-g));
        }
    } else {
        int b = blk - 160;
        float s = 0.f;
        for (int i = tid; i < LL; i += 256) s += mask[(size_t)b * LL + i];
        red[tid] = s; __syncthreads();
        for (int st = 128; st > 0; st >>= 1) {
            if (tid < st) red[tid] += red[tid + st];
            __syncthreads();
        }
        if (tid == 0) denom[b] = fmaxf(red[0], 1.0f);
    }
}

// ---------------- zproj: MFMA GEMM, z_bf[b][h][l] = bf16(W_in @ (x*mask) + b_in) ----------------

__global__ __launch_bounds__(256) void zproj_kernel(const float* __restrict__ x,
                                                    const float* __restrict__ mask,
                                                    const unsigned short* __restrict__ Ain,
                                                    const float* __restrict__ b_in,
                                                    unsigned short* __restrict__ z_bf) {
    int blk = blockIdx.x;
    int b = blk >> 6;
    int l0 = (blk & 63) << 6;
    int tid = threadIdx.x;
    int lane = tid & 63;
    int w = tid >> 6;
    int h_half = w >> 1;
    int l_q = w & 1;
    int ln15 = lane & 15, lq4 = lane >> 4;

    int lr0 = l0 + l_q * 32 + ln15;
    int lr1 = lr0 + 16;
    float mk0 = mask[(size_t)b * LL + lr0];
    float mk1 = mask[(size_t)b * LL + lr1];

    floatx4 acc[4][2];
#pragma unroll
    for (int i = 0; i < 4; ++i)
#pragma unroll
        for (int j = 0; j < 2; ++j) acc[i][j] = (floatx4){0.f, 0.f, 0.f, 0.f};

#pragma unroll
    for (int ks = 0; ks < 2; ++ks) {
        int c0 = ks * 32 + (lq4 << 3);
        short8 bf0, bf1;
        {
            const float* xp = x + ((size_t)b * LL + lr0) * CC + c0;
            float4 xa = *(const float4*)xp;
            float4 xb = *(const float4*)(xp + 4);
            bf0[0] = (short)f2b(xa.x * mk0); bf0[1] = (short)f2b(xa.y * mk0);
            bf0[2] = (short)f2b(xa.z * mk0); bf0[3] = (short)f2b(xa.w * mk0);
            bf0[4] = (short)f2b(xb.x * mk0); bf0[5] = (short)f2b(xb.y * mk0);
            bf0[6] = (short)f2b(xb.z * mk0); bf0[7] = (short)f2b(xb.w * mk0);
        }
        {
            const float* xp = x + ((size_t)b * LL + lr1) * CC + c0;
            float4 xa = *(const float4*)xp;
            float4 xb = *(const float4*)(xp + 4);
            bf1[0] = (short)f2b(xa.x * mk1); bf1[1] = (short)f2b(xa.y * mk1);
            bf1[2] = (short)f2b(xa.z * mk1); bf1[3] = (short)f2b(xa.w * mk1);
            bf1[4] = (short)f2b(xb.x * mk1); bf1[5] = (short)f2b(xb.y * mk1);
            bf1[6] = (short)f2b(xb.z * mk1); bf1[7] = (short)f2b(xb.w * mk1);
        }
        int koct = ks * 4 + lq4;
#pragma unroll
        for (int ht = 0; ht < 4; ++ht) {
            short8 af = *(const short8*)(Ain + (size_t)koct * 1024 +
                                         (h_half * 64 + ht * 16 + ln15) * 8);
            acc[ht][0] = __builtin_amdgcn_mfma_f32_16x16x32_bf16(af, bf0, acc[ht][0], 0, 0, 0);
            acc[ht][1] = __builtin_amdgcn_mfma_f32_16x16x32_bf16(af, bf1, acc[ht][1], 0, 0, 0);
        }
    }

#pragma unroll
    for (int ht = 0; ht < 4; ++ht) {
#pragma unroll
        for (int r = 0; r < 4; ++r) {
            int h = h_half * 64 + ht * 16 + (lq4 << 2) + r;
            float bi = b_in[h];
            z_bf[((size_t)(b * HD + h)) * LL + lr0] = f2b(acc[ht][0][r] + bi);
            z_bf[((size_t)(b * HD + h)) * LL + lr1] = f2b(acc[ht][1][r] + bi);
        }
    }
}

// ---------------- wavelet helpers: vectorized analysis / synthesis ----------------
// analysis: out_lo[n] = sum_k c_lo[k] src[(2n+k) mod len], same for hi. half = output len.
__device__ __forceinline__ void analysis_step(const float* __restrict__ src,
                                              float* __restrict__ lo_dst,
                                              float* __restrict__ hi_dst,
                                              int half, int tid) {
    int len = half << 1;
    for (int q = tid; q < (half >> 2); q += 256) {
        int n0 = q << 2;
        float lo[4], hi[4];
        if (n0 + 4 == half) {                       // only quad that wraps
#pragma unroll
            for (int i = 0; i < 4; ++i) {
                float l = 0.f, hh = 0.f;
#pragma unroll
                for (int k = 0; k < 8; ++k) {
                    float v = src[(2 * (n0 + i) + k) & (len - 1)];
                    l = fmaf(c_lo[k], v, l);
                    hh = fmaf(c_hi[k], v, hh);
                }
                lo[i] = l; hi[i] = hh;
            }
        } else {
            float sv[16];
            const float* sp = src + (n0 << 1);
            *(float4*)&sv[0]  = *(const float4*)(sp);
            *(float4*)&sv[4]  = *(const float4*)(sp + 4);
            *(float4*)&sv[8]  = *(const float4*)(sp + 8);
            *(float4*)&sv[12] = *(const float4*)(sp + 12);
#pragma unroll
            for (int i = 0; i < 4; ++i) {
                float l = 0.f, hh = 0.f;
#pragma unroll
                for (int k = 0; k < 8; ++k) {
                    l = fmaf(c_lo[k], sv[2 * i + k], l);
                    hh = fmaf(c_hi[k], sv[2 * i + k], hh);
                }
                lo[i] = l; hi[i] = hh;
            }
        }
        *(float4*)&lo_dst[n0] = make_float4(lo[0], lo[1], lo[2], lo[3]);
        *(float4*)&hi_dst[n0] = make_float4(hi[0], hi[1], hi[2], hi[3]);
    }
}

// synthesis oct: ov[t] = out[8*(m0/4)+t], out[2m+par] = sum_j c_*[2j+par]*X[m-j]
__device__ __forceinline__ void synth_oct(const float* __restrict__ A,
                                          const float* __restrict__ D,
                                          int m0, int half, float* ov) {
    if (m0 == 0) {                                  // only oct that wraps (backward)
        int mask2 = (half << 1) - 1;
#pragma unroll
        for (int t = 0; t < 8; ++t) {
            int par = t & 1;
            float s = 0.f;
#pragma unroll
            for (int j = 0; j < 4; ++j) {
                int k = 2 * j + par;
                int idx = ((t - k) & mask2) >> 1;
                s = fmaf(c_lo[k], A[idx], s);
                s = fmaf(c_hi[k], D[idx], s);
            }
            ov[t] = s;
        }
    } else {
        float av[8], dv[8];
        *(float4*)&av[0] = *(const float4*)(A + m0 - 4);
        *(float4*)&av[4] = *(const float4*)(A + m0);
        *(float4*)&dv[0] = *(const float4*)(D + m0 - 4);
        *(float4*)&dv[4] = *(const float4*)(D + m0);
#pragma unroll
        for (int t = 0; t < 4; ++t) {
            float e = 0.f, o = 0.f;
#pragma unroll
            for (int j = 0; j < 4; ++j) {
                float xa = av[t + 4 - j], xd = dv[t + 4 - j];
                e = fmaf(c_lo[2 * j], xa, e);     e = fmaf(c_hi[2 * j], xd, e);
                o = fmaf(c_lo[2 * j + 1], xa, o); o = fmaf(c_hi[2 * j + 1], xd, o);
            }
            ov[2 * t] = e;
            ov[2 * t + 1] = o;
        }
    }
}

__device__ __forceinline__ void synth_step(const float* __restrict__ A,
                                           const float* __restrict__ D,
                                           float* __restrict__ dst,
                                           int half, int tid) {
    for (int q = tid; q < (half >> 2); q += 256) {
        int m0 = q << 2;
        int i0 = m0 << 1;
        float ov[8];
        synth_oct(A, D, m0, half, ov);
        *(float4*)&dst[i0]     = make_float4(ov[0], ov[1], ov[2], ov[3]);
        *(float4*)&dst[i0 + 4] = make_float4(ov[4], ov[5], ov[6], ov[7]);
    }
}

// ---------------- per-row wavelet (bf16 I/O), writes s_bf = bf16(z + z_rec) ----------------

__global__ __launch_bounds__(256) void wavelet_kernel(const unsigned short* __restrict__ z_bf,
                                                      unsigned short* __restrict__ s_bf,
                                                      const float* __restrict__ film_ws,
                                                      const float* __restrict__ gate_ws,
                                                      const float* __restrict__ lam_raw,
                                                      float* __restrict__ lam_ws) {
    __shared__ float zrow[4096];
    __shared__ float d1[2048];
    __shared__ float d2[1024];
    __shared__ float Aq[2048];
    __shared__ float Bq[1024];

    int blk = blockIdx.x;
    int b = blk >> 7;
    int h = blk & 127;
    int tid = threadIdx.x;
    const unsigned short* zg = z_bf + ((size_t)(b * HD + h)) * LL;
    unsigned short* sg = s_bf + ((size_t)(b * HD + h)) * LL;

    for (int i = tid; i < 512; i += 256) {
        ushort8 v = *(const ushort8*)(zg + (i << 3));
        *(float4*)&zrow[i << 3] =
            make_float4(b2f(v[0]), b2f(v[1]), b2f(v[2]), b2f(v[3]));
        *(float4*)&zrow[(i << 3) + 4] =
            make_float4(b2f(v[4]), b2f(v[5]), b2f(v[6]), b2f(v[7]));
    }
    __syncthreads();

    analysis_step(zrow, Aq, d1, 2048, tid);      // L1
    __syncthreads();
    analysis_step(Aq, Bq, d2, 1024, tid);        // L2
    __syncthreads();
    analysis_step(Bq, Aq, Aq + 512, 512, tid);   // L3: approx3 -> Aq[0:512], d3 -> Aq[512:1024]
    __syncthreads();

    float sc0, sh0, sc1, sh1, sc2, sh2, sc3, sh3;
    {
        int base = b * 4;
#define FILM_COEF(bd, SC, SH)                                              \
        {   float ga = film_ws[((size_t)(base + bd)) * 256 + h];           \
            float be = film_ws[((size_t)(base + bd)) * 256 + 128 + h];     \
            float gt = gate_ws[base + bd];                                 \
            SC = 1.0f + gt * ga; SH = gt * be; }
        FILM_COEF(0, sc0, sh0) FILM_COEF(1, sc1, sh1)
        FILM_COEF(2, sc2, sh2) FILM_COEF(3, sc3, sh3)
#undef FILM_COEF
    }
    float s0 = 0.f, s1 = 0.f, s2 = 0.f, s3 = 0.f;
#define FILM4(P, LEN, SC, SH, SUM)                                         \
    for (int qq = tid; qq < ((LEN) >> 2); qq += 256) {                     \
        float4 v = *(float4*)&(P)[qq << 2];                                \
        v.x = fmaf(v.x, SC, SH); v.y = fmaf(v.y, SC, SH);                  \
        v.z = fmaf(v.z, SC, SH); v.w = fmaf(v.w, SC, SH);                  \
        *(float4*)&(P)[qq << 2] = v;                                       \
        SUM += fabsf(v.x) + fabsf(v.y) + fabsf(v.z) + fabsf(v.w);          \
    }
    FILM4(Aq, 512, sc0, sh0, s0)
    FILM4(d1, 2048, sc1, sh1, s1)
    FILM4(d2, 1024, sc2, sh2, s2)
    FILM4((Aq + 512), 512, sc3, sh3, s3)
#undef FILM4
#pragma unroll
    for (int off = 32; off > 0; off >>= 1) {
        s0 += __shfl_xor(s0, off);
        s1 += __shfl_xor(s1, off);
        s2 += __shfl_xor(s2, off);
        s3 += __shfl_xor(s3, off);
    }
    if ((tid & 63) == 0)
        ((float4*)Bq)[tid >> 6] = make_float4(s0, s1, s2, s3);   // Bq dead after L3
    __syncthreads();
    float4 r0 = ((const float4*)Bq)[0];
    float4 r1 = ((const float4*)Bq)[1];
    float4 r2 = ((const float4*)Bq)[2];
    float4 r3 = ((const float4*)Bq)[3];
    float lam0 = log1pf(expf(lam_raw[0])) * ((r0.x + r1.x + r2.x + r3.x) * (1.0f / 512.f));
    float lam1 = log1pf(expf(lam_raw[1])) * ((r0.y + r1.y + r2.y + r3.y) * (1.0f / 2048.f));
    float lam2 = log1pf(expf(lam_raw[2])) * ((r0.z + r1.z + r2.z + r3.z) * (1.0f / 1024.f));
    float lam3 = log1pf(expf(lam_raw[3])) * ((r0.w + r1.w + r2.w + r3.w) * (1.0f / 512.f));
    if (tid < 4) {
        float lam = (tid == 0) ? lam0 : (tid == 1) ? lam1 : (tid == 2) ? lam2 : lam3;
        lam_ws[((size_t)(b * 4 + tid)) * 128 + h] = lam;
    }
#define STHR4(P, LEN, LAM)                                                 \
    for (int qq = tid; qq < ((LEN) >> 2); qq += 256) {                     \
        float4 v = *(float4*)&(P)[qq << 2];                                \
        float a;                                                           \
        a = fabsf(v.x) - (LAM); v.x = (a > 0.f) ? copysignf(a, v.x) : 0.f; \
        a = fabsf(v.y) - (LAM); v.y = (a > 0.f) ? copysignf(a, v.y) : 0.f; \
        a = fabsf(v.z) - (LAM); v.z = (a > 0.f) ? copysignf(a, v.z) : 0.f; \
        a = fabsf(v.w) - (LAM); v.w = (a > 0.f) ? copysignf(a, v.w) : 0.f; \
        *(float4*)&(P)[qq << 2] = v;                                       \
    }
    STHR4(Aq, 512, lam0)
    STHR4(d1, 2048, lam1)
    STHR4(d2, 1024, lam2)
    STHR4((Aq + 512), 512, lam3)
#undef STHR4
    __syncthreads();

    synth_step(Aq, Aq + 512, Bq, 512, tid);      // R1 -> Bq[0:1024]
    __syncthreads();
    synth_step(Bq, d2, Aq, 1024, tid);           // R2 -> Aq[0:2048]
    __syncthreads();
    // R3 fused with zrow add + bf16 store
    for (int q = tid; q < 512; q += 256) {
        int m0 = q << 2;
        int i0 = m0 << 1;
        float ov[8];
        synth_oct(Aq, d1, m0, 2048, ov);
        float zr[8];
        *(float4*)&zr[0] = *(float4*)&zrow[i0];
        *(float4*)&zr[4] = *(float4*)&zrow[i0 + 4];
        ushort8 o8;
#pragma unroll
        for (int t = 0; t < 8; ++t) o8[t] = f2b(ov[t] + zr[t]);
        *(ushort8*)(sg + i0) = o8;
    }
}

// ---------------- mix: MFMA GEMM with fused in-LDS transpose ----------------
// s_bf[h][l] staged as u32 pairs into swizzled T[h][lp ^ (h&31)]; A-frags
// assembled from 8 swizzled reads (2-lane broadcast, conflict-free).

union U32x4S8 { unsigned int u[4]; short8 s; };

__global__ __launch_bounds__(256) void mix_kernel(const unsigned short* __restrict__ s_bf,
                                                  const unsigned short* __restrict__ Bmix,
                                                  const float* __restrict__ b_mix,
                                                  const float* __restrict__ mask,
                                                  float* __restrict__ out,
                                                  float* __restrict__ pool_part) {
    __shared__ unsigned int T[HD * 64];   // 32 KB, [h][lp] swizzled
    __shared__ float pbuf[2][HD];

    int blk = blockIdx.x;
    int b = blk >> 5;
    int lt128 = blk & 31;
    int l0 = lt128 << 7;
    int tid = threadIdx.x;
    int lane = tid & 63;
    int w = tid >> 6;
    int l_half = w >> 1, g_half = w & 1;
    int ln15 = lane & 15, lq4 = lane >> 4;

    // stage 128h x 128l bf16 tile (as 64 u32/row), swizzled
    {
        const unsigned int* src = (const unsigned int*)s_bf;
#pragma unroll
        for (int r = 0; r < 8; ++r) {
            int q = (r << 8) + tid;              // 0..2047
            int hh = q >> 4;                     // 0..127
            int k = q & 15;                      // 16B chunk
            const unsigned int* gp = src + (size_t)(b * HD + hh) * (LL / 2) +
                                     (l0 >> 1) + (k << 2);
            uint4 v = *(const uint4*)gp;
            int sw = hh & 31;
            unsigned int* tp = T + hh * 64;
            tp[(4 * k + 0) ^ sw] = v.x;
            tp[(4 * k + 1) ^ sw] = v.y;
            tp[(4 * k + 2) ^ sw] = v.z;
            tp[(4 * k + 3) ^ sw] = v.w;
        }
    }
    __syncthreads();

    floatx4 acc[4][4];
#pragma unroll
    for (int i = 0; i < 4; ++i)
#pragma unroll
        for (int j = 0; j < 4; ++j) acc[i][j] = (floatx4){0.f, 0.f, 0.f, 0.f};

    const unsigned short* Bb = Bmix + (g_half * 64 + ln15) * 8;

#pragma unroll 2
    for (int ks = 0; ks < 4; ++ks) {
        int koct = ks * 4 + lq4;
        short8 a[4], bb[4];
#pragma unroll
        for (int lt = 0; lt < 4; ++lt) {
            int l_loc = l_half * 64 + lt * 16 + ln15;
            int lp = l_loc >> 1;
            int odd = l_loc & 1;
            U32x4S8 cv;
#pragma unroll
            for (int qq = 0; qq < 4; ++qq) {
                int h0 = koct * 8 + 2 * qq;
                unsigned int w0 = T[h0 * 64 + (lp ^ (h0 & 31))];
                unsigned int w1 = T[(h0 + 1) * 64 + (lp ^ ((h0 + 1) & 31))];
                unsigned int e0 = odd ? (w0 >> 16) : (w0 & 0xffffu);
                unsigned int e1 = odd ? (w1 >> 16) : (w1 & 0xffffu);
                cv.u[qq] = e0 | (e1 << 16);
            }
            a[lt] = cv.s;
        }
#pragma unroll
        for (int gt = 0; gt < 4; ++gt)
            bb[gt] = *(const short8*)(Bb + (size_t)koct * 1024 + gt * 128);
#pragma unroll
        for (int lt = 0; lt < 4; ++lt)
#pragma unroll
            for (int gt = 0; gt < 4; ++gt)
                acc[lt][gt] = __builtin_amdgcn_mfma_f32_16x16x32_bf16(a[lt], bb[gt], acc[lt][gt], 0, 0, 0);
    }

    int gcol[4]; float bmv[4]; float pacc[4];
#pragma unroll
    for (int gt = 0; gt < 4; ++gt) {
        gcol[gt] = g_half * 64 + gt * 16 + ln15;
        bmv[gt] = b_mix[gcol[gt]];
        pacc[gt] = 0.f;
    }
#pragma unroll
    for (int lt = 0; lt < 4; ++lt) {
#pragma unroll
        for (int r = 0; r < 4; ++r) {
            int l = l0 + l_half * 64 + lt * 16 + (lq4 << 2) + r;
            float mkv = mask[(size_t)b * LL + l];
            float* orow = out + ((size_t)b * LL + l) * HD;
#pragma unroll
            for (int gt = 0; gt < 4; ++gt) {
                float v = gelu_exact(acc[lt][gt][r] + bmv[gt]) * mkv;
                orow[gcol[gt]] = v;
                pacc[gt] = fmaf(v, mkv, pacc[gt]);
            }
        }
    }
#pragma unroll
    for (int gt = 0; gt < 4; ++gt) {
        pacc[gt] += __shfl_xor(pacc[gt], 16);
        pacc[gt] += __shfl_xor(pacc[gt], 32);
    }
    if (lane < 16) {
#pragma unroll
        for (int gt = 0; gt < 4; ++gt)
            pbuf[l_half][g_half * 64 + gt * 16 + lane] = pacc[gt];
    }
    __syncthreads();
    if (tid < HD)
        pool_part[((size_t)(b * 32 + lt128)) * HD + tid] = pbuf[0][tid] + pbuf[1][tid];
}

// ---------------- finalize: pool + lam mean/max ----------------

__global__ void finalize_kernel(const float* __restrict__ pool_part,
                                const float* __restrict__ denom,
                                const float* __restrict__ lam_ws,
                                float* __restrict__ d_out) {
    const size_t OUT1 = (size_t)BB * LL * HD;
    const size_t OUT2 = OUT1 + (size_t)BB * HD;
    const size_t OUT3 = OUT2 + BB;
    int b = blockIdx.x, tid = threadIdx.x;
    __shared__ float rsum[256], rmax[256];
    if (tid < 128) {
        float s = 0.f;
        for (int blk = 0; blk < 32; ++blk)
            s += pool_part[((size_t)(b * 32 + blk)) * HD + tid];
        d_out[OUT1 + (size_t)b * HD + tid] = s / denom[b];
    }
    float v0 = lam_ws[(size_t)b * 512 + tid];
    float v1 = lam_ws[(size_t)b * 512 + 256 + tid];
    rsum[tid] = v0 + v1;
    rmax[tid] = fmaxf(v0, v1);
    __syncthreads();
    for (int st = 128; st > 0; st >>= 1) {
        if (tid < st) {
            rsum[tid] += rsum[tid + st];
            rmax[tid] = fmaxf(rmax[tid], rmax[tid + st]);
        }
        __syncthreads();
    }
    if (tid == 0) {
        d_out[OUT2 + b] = rsum[0] / 512.0f;
        d_out[OUT3 + b] = rmax[0];
    }
}

// ---------------- launch ----------------

extern "C" void kernel_launch(void* const* d_in, const int* in_sizes, int n_in,
                              void* d_out, int out_size, void* d_ws, size_t ws_size,
                              hipStream_t stream) {
    (void)in_sizes; (void)n_in; (void)out_size; (void)ws_size;
    const float* x      = (const float*)d_in[0];
    const float* mask   = (const float*)d_in[1];
    const float* flow   = (const float*)d_in[2];
    const float* W_in   = (const float*)d_in[3];
    const float* b_in   = (const float*)d_in[4];
    const float* W_mix  = (const float*)d_in[5];
    const float* b_mix  = (const float*)d_in[6];
    const float* lam_raw= (const float*)d_in[7];
    const float* Wgb    = (const float*)d_in[8];
    const float* bgb    = (const float*)d_in[9];
    const float* Wg     = (const float*)d_in[10];
    const float* bg     = (const float*)d_in[11];

    unsigned short* z_bf = (unsigned short*)d_ws;                 // 8388608 ushort
    unsigned short* s_bf = z_bf + (size_t)BB * HD * LL;           // 8388608 ushort
    float* film_ws   = (float*)(s_bf + (size_t)BB * HD * LL);     // 16384
    float* gate_ws   = film_ws + BB * 4 * 256;                    // 64
    float* lam_ws    = gate_ws + 64;                              // 8192
    float* denom_ws  = lam_ws + BB * 4 * 128;                     // 16
    float* pool_part = denom_ws + 16;                             // 16*32*128 = 65536
    unsigned short* Ain  = (unsigned short*)(pool_part + BB * 32 * HD);  // 8192 ushort
    unsigned short* Bmix = Ain + HD * CC;                                // 16384 ushort

    float* out = (float*)d_out;

    hipLaunchKernelGGL(prep_kernel, dim3(176), dim3(256), 0, stream,
                       W_in, Ain, W_mix, Bmix, flow, Wgb, bgb, Wg, bg,
                       film_ws, gate_ws, mask, denom_ws);
    hipLaunchKernelGGL(zproj_kernel, dim3(BB * (LL / 64)), dim3(256), 0, stream,
                       x, mask, Ain, b_in, z_bf);
    hipLaunchKernelGGL(wavelet_kernel, dim3(BB * HD), dim3(256), 0, stream,
                       z_bf, s_bf, film_ws, gate_ws, lam_raw, lam_ws);
    hipLaunchKernelGGL(mix_kernel, dim3(BB * (LL / 128)), dim3(256), 0, stream,
                       s_bf, Bmix, b_mix, mask, out, pool_part);
    hipLaunchKernelGGL(finalize_kernel, dim3(BB), dim3(256), 0, stream,
                       pool_part, denom_ws, lam_ws, out);
}

// Round 6
// 74.169 us; speedup vs baseline: 2.2271x; 1.0112x over previous
//
#include <hip/hip_runtime.h>
#include <math.h>

#define BB 16
#define LL 4096
#define CC 64
#define HD 128

typedef __attribute__((ext_vector_type(8))) short short8;
typedef __attribute__((ext_vector_type(8))) unsigned short ushort8;
typedef __attribute__((ext_vector_type(4))) float floatx4;

__constant__ float c_lo[8] = {
    -0.010597401784997278f, 0.032883011666982945f, 0.030841381835986965f,
    -0.18703481171888114f, -0.02798376941698385f, 0.6308807679295904f,
    0.7148465705525415f, 0.23037781330885523f};
__constant__ float c_hi[8] = {
    -0.23037781330885523f, 0.7148465705525415f, -0.6308807679295904f,
    -0.02798376941698385f, 0.18703481171888114f, 0.030841381835986965f,
    -0.032883011666982945f, -0.010597401784997278f};

__device__ __forceinline__ float gelu_exact(float x) {
    return 0.5f * x * (1.0f + erff(x * 0.70710678118654752440f));
}
__device__ __forceinline__ unsigned short f2b(float f) {   // f32 -> bf16 RNE
    unsigned int u = __float_as_uint(f);
    u = u + 0x7FFFu + ((u >> 16) & 1u);
    return (unsigned short)(u >> 16);
}
__device__ __forceinline__ float b2f(unsigned short s) {
    return __uint_as_float(((unsigned int)s) << 16);
}

// ---------------- zproj (+ fused pack blocks for Bmix / FiLM) ----------------
// blocks [0, 1024):   z_bf[b][h][l] = bf16(W_in @ (x*mask) + b_in), MFMA, A-frags
//                     built inline from W_in (rows contiguous in k=c).
// blocks [1024,1088): Bmix pack  (consumer: mix, a later kernel -> safe)
// blocks [1088,1152): FiLM gamma/beta/gate (consumer: wavelet -> safe)

__global__ __launch_bounds__(256) void zproj_kernel(
    const float* __restrict__ x, const float* __restrict__ mask,
    const float* __restrict__ W_in, const float* __restrict__ b_in,
    unsigned short* __restrict__ z_bf,
    const float* __restrict__ W_mix, unsigned short* __restrict__ Bmix,
    const float* __restrict__ flow, const float* __restrict__ Wgb,
    const float* __restrict__ bgb, const float* __restrict__ Wg,
    const float* __restrict__ bg, float* __restrict__ film_ws,
    float* __restrict__ gate_ws) {
    int blk = blockIdx.x;
    int tid = threadIdx.x;

    if (blk >= BB * 64) {
        int e = blk - BB * 64;
        if (e < 64) {                               // Bmix pack: idx = ((h>>3)*128+g)*8+(h&7)
            int q = e * 256 + tid;                  // 16384
            int g = (q >> 3) & 127;
            int h = ((q >> 10) << 3) | (q & 7);
            Bmix[q] = f2b(W_mix[g * HD + h]);
        } else {                                    // FiLM
            int bf = e - 64;                        // b*4 + f
            int f = bf & 3;
            int b = bf >> 2;
            const float* fl = flow + b * 24;
            const float* wrow = Wgb + ((size_t)(f * 256 + tid)) * 24;
            float acc = bgb[f * 256 + tid];
#pragma unroll
            for (int j = 0; j < 24; ++j) acc = fmaf(wrow[j], fl[j], acc);
            film_ws[(size_t)bf * 256 + tid] = acc;
            if (tid == 0) {
                float g = bg[f];
#pragma unroll
                for (int j = 0; j < 24; ++j) g = fmaf(Wg[f * 24 + j], fl[j], g);
                gate_ws[bf] = 1.0f / (1.0f + expf(-g));
            }
        }
        return;
    }

    int b = blk >> 6;
    int l0 = (blk & 63) << 6;
    int lane = tid & 63;
    int w = tid >> 6;
    int h_half = w >> 1;
    int l_q = w & 1;
    int ln15 = lane & 15, lq4 = lane >> 4;

    int lr0 = l0 + l_q * 32 + ln15;
    int lr1 = lr0 + 16;
    float mk0 = mask[(size_t)b * LL + lr0];
    float mk1 = mask[(size_t)b * LL + lr1];

    floatx4 acc[4][2];
#pragma unroll
    for (int i = 0; i < 4; ++i)
#pragma unroll
        for (int j = 0; j < 2; ++j) acc[i][j] = (floatx4){0.f, 0.f, 0.f, 0.f};

#pragma unroll
    for (int ks = 0; ks < 2; ++ks) {
        int c0 = ks * 32 + (lq4 << 3);
        short8 bf0, bf1;
        {
            const float* xp = x + ((size_t)b * LL + lr0) * CC + c0;
            float4 xa = *(const float4*)xp;
            float4 xb = *(const float4*)(xp + 4);
            bf0[0] = (short)f2b(xa.x * mk0); bf0[1] = (short)f2b(xa.y * mk0);
            bf0[2] = (short)f2b(xa.z * mk0); bf0[3] = (short)f2b(xa.w * mk0);
            bf0[4] = (short)f2b(xb.x * mk0); bf0[5] = (short)f2b(xb.y * mk0);
            bf0[6] = (short)f2b(xb.z * mk0); bf0[7] = (short)f2b(xb.w * mk0);
        }
        {
            const float* xp = x + ((size_t)b * LL + lr1) * CC + c0;
            float4 xa = *(const float4*)xp;
            float4 xb = *(const float4*)(xp + 4);
            bf1[0] = (short)f2b(xa.x * mk1); bf1[1] = (short)f2b(xa.y * mk1);
            bf1[2] = (short)f2b(xa.z * mk1); bf1[3] = (short)f2b(xa.w * mk1);
            bf1[4] = (short)f2b(xb.x * mk1); bf1[5] = (short)f2b(xb.y * mk1);
            bf1[6] = (short)f2b(xb.z * mk1); bf1[7] = (short)f2b(xb.w * mk1);
        }
        int c8 = ks * 32 + (lq4 << 3);              // koct*8
        const float* wb = W_in + (size_t)(h_half * 64 + ln15) * CC + c8;
#pragma unroll
        for (int ht = 0; ht < 4; ++ht) {
            const float* wr = wb + (size_t)ht * 16 * CC;
            float4 wa = *(const float4*)wr;
            float4 wc = *(const float4*)(wr + 4);
            short8 af;
            af[0] = (short)f2b(wa.x); af[1] = (short)f2b(wa.y);
            af[2] = (short)f2b(wa.z); af[3] = (short)f2b(wa.w);
            af[4] = (short)f2b(wc.x); af[5] = (short)f2b(wc.y);
            af[6] = (short)f2b(wc.z); af[7] = (short)f2b(wc.w);
            acc[ht][0] = __builtin_amdgcn_mfma_f32_16x16x32_bf16(af, bf0, acc[ht][0], 0, 0, 0);
            acc[ht][1] = __builtin_amdgcn_mfma_f32_16x16x32_bf16(af, bf1, acc[ht][1], 0, 0, 0);
        }
    }

#pragma unroll
    for (int ht = 0; ht < 4; ++ht) {
#pragma unroll
        for (int r = 0; r < 4; ++r) {
            int h = h_half * 64 + ht * 16 + (lq4 << 2) + r;
            float bi = b_in[h];
            z_bf[((size_t)(b * HD + h)) * LL + lr0] = f2b(acc[ht][0][r] + bi);
            z_bf[((size_t)(b * HD + h)) * LL + lr1] = f2b(acc[ht][1][r] + bi);
        }
    }
}

// ---------------- wavelet helpers: vectorized analysis / synthesis ----------------

__device__ __forceinline__ void analysis_step(const float* __restrict__ src,
                                              float* __restrict__ lo_dst,
                                              float* __restrict__ hi_dst,
                                              int half, int tid) {
    int len = half << 1;
    for (int q = tid; q < (half >> 2); q += 256) {
        int n0 = q << 2;
        float lo[4], hi[4];
        if (n0 + 4 == half) {                       // only quad that wraps
#pragma unroll
            for (int i = 0; i < 4; ++i) {
                float l = 0.f, hh = 0.f;
#pragma unroll
                for (int k = 0; k < 8; ++k) {
                    float v = src[(2 * (n0 + i) + k) & (len - 1)];
                    l = fmaf(c_lo[k], v, l);
                    hh = fmaf(c_hi[k], v, hh);
                }
                lo[i] = l; hi[i] = hh;
            }
        } else {
            float sv[16];
            const float* sp = src + (n0 << 1);
            *(float4*)&sv[0]  = *(const float4*)(sp);
            *(float4*)&sv[4]  = *(const float4*)(sp + 4);
            *(float4*)&sv[8]  = *(const float4*)(sp + 8);
            *(float4*)&sv[12] = *(const float4*)(sp + 12);
#pragma unroll
            for (int i = 0; i < 4; ++i) {
                float l = 0.f, hh = 0.f;
#pragma unroll
                for (int k = 0; k < 8; ++k) {
                    l = fmaf(c_lo[k], sv[2 * i + k], l);
                    hh = fmaf(c_hi[k], sv[2 * i + k], hh);
                }
                lo[i] = l; hi[i] = hh;
            }
        }
        *(float4*)&lo_dst[n0] = make_float4(lo[0], lo[1], lo[2], lo[3]);
        *(float4*)&hi_dst[n0] = make_float4(hi[0], hi[1], hi[2], hi[3]);
    }
}

__device__ __forceinline__ void synth_oct(const float* __restrict__ A,
                                          const float* __restrict__ D,
                                          int m0, int half, float* ov) {
    if (m0 == 0) {                                  // only oct that wraps (backward)
        int mask2 = (half << 1) - 1;
#pragma unroll
        for (int t = 0; t < 8; ++t) {
            int par = t & 1;
            float s = 0.f;
#pragma unroll
            for (int j = 0; j < 4; ++j) {
                int k = 2 * j + par;
                int idx = ((t - k) & mask2) >> 1;
                s = fmaf(c_lo[k], A[idx], s);
                s = fmaf(c_hi[k], D[idx], s);
            }
            ov[t] = s;
        }
    } else {
        float av[8], dv[8];
        *(float4*)&av[0] = *(const float4*)(A + m0 - 4);
        *(float4*)&av[4] = *(const float4*)(A + m0);
        *(float4*)&dv[0] = *(const float4*)(D + m0 - 4);
        *(float4*)&dv[4] = *(const float4*)(D + m0);
#pragma unroll
        for (int t = 0; t < 4; ++t) {
            float e = 0.f, o = 0.f;
#pragma unroll
            for (int j = 0; j < 4; ++j) {
                float xa = av[t + 4 - j], xd = dv[t + 4 - j];
                e = fmaf(c_lo[2 * j], xa, e);     e = fmaf(c_hi[2 * j], xd, e);
                o = fmaf(c_lo[2 * j + 1], xa, o); o = fmaf(c_hi[2 * j + 1], xd, o);
            }
            ov[2 * t] = e;
            ov[2 * t + 1] = o;
        }
    }
}

__device__ __forceinline__ void synth_step(const float* __restrict__ A,
                                           const float* __restrict__ D,
                                           float* __restrict__ dst,
                                           int half, int tid) {
    for (int q = tid; q < (half >> 2); q += 256) {
        int m0 = q << 2;
        int i0 = m0 << 1;
        float ov[8];
        synth_oct(A, D, m0, half, ov);
        *(float4*)&dst[i0]     = make_float4(ov[0], ov[1], ov[2], ov[3]);
        *(float4*)&dst[i0 + 4] = make_float4(ov[4], ov[5], ov[6], ov[7]);
    }
}

// ---------------- per-row wavelet (bf16 I/O), writes s_bf = bf16(z + z_rec) ----------------

__global__ __launch_bounds__(256) void wavelet_kernel(const unsigned short* __restrict__ z_bf,
                                                      unsigned short* __restrict__ s_bf,
                                                      const float* __restrict__ film_ws,
                                                      const float* __restrict__ gate_ws,
                                                      const float* __restrict__ lam_raw,
                                                      float* __restrict__ lam_ws) {
    __shared__ float zrow[4096];
    __shared__ float d1[2048];
    __shared__ float d2[1024];
    __shared__ float Aq[2048];
    __shared__ float Bq[1024];

    int blk = blockIdx.x;
    int b = blk >> 7;
    int h = blk & 127;
    int tid = threadIdx.x;
    const unsigned short* zg = z_bf + ((size_t)(b * HD + h)) * LL;
    unsigned short* sg = s_bf + ((size_t)(b * HD + h)) * LL;

    for (int i = tid; i < 512; i += 256) {
        ushort8 v = *(const ushort8*)(zg + (i << 3));
        *(float4*)&zrow[i << 3] =
            make_float4(b2f(v[0]), b2f(v[1]), b2f(v[2]), b2f(v[3]));
        *(float4*)&zrow[(i << 3) + 4] =
            make_float4(b2f(v[4]), b2f(v[5]), b2f(v[6]), b2f(v[7]));
    }
    __syncthreads();

    analysis_step(zrow, Aq, d1, 2048, tid);      // L1
    __syncthreads();
    analysis_step(Aq, Bq, d2, 1024, tid);        // L2
    __syncthreads();
    analysis_step(Bq, Aq, Aq + 512, 512, tid);   // L3: approx3 -> Aq[0:512], d3 -> Aq[512:1024]
    __syncthreads();

    float sc0, sh0, sc1, sh1, sc2, sh2, sc3, sh3;
    {
        int base = b * 4;
#define FILM_COEF(bd, SC, SH)                                              \
        {   float ga = film_ws[((size_t)(base + bd)) * 256 + h];           \
            float be = film_ws[((size_t)(base + bd)) * 256 + 128 + h];     \
            float gt = gate_ws[base + bd];                                 \
            SC = 1.0f + gt * ga; SH = gt * be; }
        FILM_COEF(0, sc0, sh0) FILM_COEF(1, sc1, sh1)
        FILM_COEF(2, sc2, sh2) FILM_COEF(3, sc3, sh3)
#undef FILM_COEF
    }
    float s0 = 0.f, s1 = 0.f, s2 = 0.f, s3 = 0.f;
#define FILM4(P, LEN, SC, SH, SUM)                                         \
    for (int qq = tid; qq < ((LEN) >> 2); qq += 256) {                     \
        float4 v = *(float4*)&(P)[qq << 2];                                \
        v.x = fmaf(v.x, SC, SH); v.y = fmaf(v.y, SC, SH);                  \
        v.z = fmaf(v.z, SC, SH); v.w = fmaf(v.w, SC, SH);                  \
        *(float4*)&(P)[qq << 2] = v;                                       \
        SUM += fabsf(v.x) + fabsf(v.y) + fabsf(v.z) + fabsf(v.w);          \
    }
    FILM4(Aq, 512, sc0, sh0, s0)
    FILM4(d1, 2048, sc1, sh1, s1)
    FILM4(d2, 1024, sc2, sh2, s2)
    FILM4((Aq + 512), 512, sc3, sh3, s3)
#undef FILM4
#pragma unroll
    for (int off = 32; off > 0; off >>= 1) {
        s0 += __shfl_xor(s0, off);
        s1 += __shfl_xor(s1, off);
        s2 += __shfl_xor(s2, off);
        s3 += __shfl_xor(s3, off);
    }
    if ((tid & 63) == 0)
        ((float4*)Bq)[tid >> 6] = make_float4(s0, s1, s2, s3);   // Bq dead after L3
    __syncthreads();
    float4 r0 = ((const float4*)Bq)[0];
    float4 r1 = ((const float4*)Bq)[1];
    float4 r2 = ((const float4*)Bq)[2];
    float4 r3 = ((const float4*)Bq)[3];
    float lam0 = log1pf(expf(lam_raw[0])) * ((r0.x + r1.x + r2.x + r3.x) * (1.0f / 512.f));
    float lam1 = log1pf(expf(lam_raw[1])) * ((r0.y + r1.y + r2.y + r3.y) * (1.0f / 2048.f));
    float lam2 = log1pf(expf(lam_raw[2])) * ((r0.z + r1.z + r2.z + r3.z) * (1.0f / 1024.f));
    float lam3 = log1pf(expf(lam_raw[3])) * ((r0.w + r1.w + r2.w + r3.w) * (1.0f / 512.f));
    if (tid < 4) {
        float lam = (tid == 0) ? lam0 : (tid == 1) ? lam1 : (tid == 2) ? lam2 : lam3;
        lam_ws[((size_t)(b * 4 + tid)) * 128 + h] = lam;
    }
#define STHR4(P, LEN, LAM)                                                 \
    for (int qq = tid; qq < ((LEN) >> 2); qq += 256) {                     \
        float4 v = *(float4*)&(P)[qq << 2];                                \
        float a;                                                           \
        a = fabsf(v.x) - (LAM); v.x = (a > 0.f) ? copysignf(a, v.x) : 0.f; \
        a = fabsf(v.y) - (LAM); v.y = (a > 0.f) ? copysignf(a, v.y) : 0.f; \
        a = fabsf(v.z) - (LAM); v.z = (a > 0.f) ? copysignf(a, v.z) : 0.f; \
        a = fabsf(v.w) - (LAM); v.w = (a > 0.f) ? copysignf(a, v.w) : 0.f; \
        *(float4*)&(P)[qq << 2] = v;                                       \
    }
    STHR4(Aq, 512, lam0)
    STHR4(d1, 2048, lam1)
    STHR4(d2, 1024, lam2)
    STHR4((Aq + 512), 512, lam3)
#undef STHR4
    __syncthreads();

    synth_step(Aq, Aq + 512, Bq, 512, tid);      // R1 -> Bq[0:1024]
    __syncthreads();
    synth_step(Bq, d2, Aq, 1024, tid);           // R2 -> Aq[0:2048]
    __syncthreads();
    for (int q = tid; q < 512; q += 256) {       // R3 fused with zrow add + bf16 store
        int m0 = q << 2;
        int i0 = m0 << 1;
        float ov[8];
        synth_oct(Aq, d1, m0, 2048, ov);
        float zr[8];
        *(float4*)&zr[0] = *(float4*)&zrow[i0];
        *(float4*)&zr[4] = *(float4*)&zrow[i0 + 4];
        ushort8 o8;
#pragma unroll
        for (int t = 0; t < 8; ++t) o8[t] = f2b(ov[t] + zr[t]);
        *(ushort8*)(sg + i0) = o8;
    }
}

// ---------------- mix: MFMA GEMM, 64-l tiles (grid 1024) with in-LDS transpose ----------------

union U32x4S8 { unsigned int u[4]; short8 s; };

__global__ __launch_bounds__(256) void mix_kernel(const unsigned short* __restrict__ s_bf,
                                                  const unsigned short* __restrict__ Bmix,
                                                  const float* __restrict__ b_mix,
                                                  const float* __restrict__ mask,
                                                  float* __restrict__ out,
                                                  float* __restrict__ pool_part) {
    __shared__ unsigned int T[HD * 32];   // 16 KB, [h][lp^ (h&31)]
    __shared__ float pbuf[2][HD];

    int blk = blockIdx.x;
    int b = blk >> 6;
    int lt64 = blk & 63;
    int l0 = lt64 << 6;
    int tid = threadIdx.x;
    int lane = tid & 63;
    int w = tid >> 6;
    int l_half = w >> 1, g_half = w & 1;
    int ln15 = lane & 15, lq4 = lane >> 4;

    // stage 128h x 64l bf16 tile (32 u32/row), swizzled
    {
        const unsigned int* src = (const unsigned int*)s_bf;
#pragma unroll
        for (int r = 0; r < 4; ++r) {
            int q = (r << 8) + tid;              // 0..1023
            int hh = q >> 3;                     // 0..127
            int k = q & 7;                       // 16B chunk
            uint4 v = *(const uint4*)(src + (size_t)(b * HD + hh) * (LL / 2) +
                                      (l0 >> 1) + (k << 2));
            int sw = hh & 31;
            unsigned int* tp = T + hh * 32;
            tp[((k << 2) + 0) ^ sw] = v.x;
            tp[((k << 2) + 1) ^ sw] = v.y;
            tp[((k << 2) + 2) ^ sw] = v.z;
            tp[((k << 2) + 3) ^ sw] = v.w;
        }
    }
    __syncthreads();

    floatx4 acc[2][4];
#pragma unroll
    for (int i = 0; i < 2; ++i)
#pragma unroll
        for (int j = 0; j < 4; ++j) acc[i][j] = (floatx4){0.f, 0.f, 0.f, 0.f};

    const unsigned short* Bb = Bmix + (g_half * 64 + ln15) * 8;

#pragma unroll 2
    for (int ks = 0; ks < 4; ++ks) {
        int koct = ks * 4 + lq4;
        short8 a[2], bb[4];
#pragma unroll
        for (int lt = 0; lt < 2; ++lt) {
            int l_loc = l_half * 32 + lt * 16 + ln15;
            int lp = l_loc >> 1;
            int odd = l_loc & 1;
            U32x4S8 cv;
#pragma unroll
            for (int qq = 0; qq < 4; ++qq) {
                int h0 = koct * 8 + 2 * qq;
                unsigned int w0 = T[h0 * 32 + (lp ^ (h0 & 31))];
                unsigned int w1 = T[(h0 + 1) * 32 + (lp ^ ((h0 + 1) & 31))];
                unsigned int e0 = odd ? (w0 >> 16) : (w0 & 0xffffu);
                unsigned int e1 = odd ? (w1 >> 16) : (w1 & 0xffffu);
                cv.u[qq] = e0 | (e1 << 16);
            }
            a[lt] = cv.s;
        }
#pragma unroll
        for (int gt = 0; gt < 4; ++gt)
            bb[gt] = *(const short8*)(Bb + (size_t)koct * 1024 + gt * 128);
#pragma unroll
        for (int lt = 0; lt < 2; ++lt)
#pragma unroll
            for (int gt = 0; gt < 4; ++gt)
                acc[lt][gt] = __builtin_amdgcn_mfma_f32_16x16x32_bf16(a[lt], bb[gt], acc[lt][gt], 0, 0, 0);
    }

    int gcol[4]; float bmv[4]; float pacc[4];
#pragma unroll
    for (int gt = 0; gt < 4; ++gt) {
        gcol[gt] = g_half * 64 + gt * 16 + ln15;
        bmv[gt] = b_mix[gcol[gt]];
        pacc[gt] = 0.f;
    }
#pragma unroll
    for (int lt = 0; lt < 2; ++lt) {
#pragma unroll
        for (int r = 0; r < 4; ++r) {
            int l = l0 + l_half * 32 + lt * 16 + (lq4 << 2) + r;
            float mkv = mask[(size_t)b * LL + l];
            float* orow = out + ((size_t)b * LL + l) * HD;
#pragma unroll
            for (int gt = 0; gt < 4; ++gt) {
                float v = gelu_exact(acc[lt][gt][r] + bmv[gt]) * mkv;
                orow[gcol[gt]] = v;
                pacc[gt] = fmaf(v, mkv, pacc[gt]);
            }
        }
    }
#pragma unroll
    for (int gt = 0; gt < 4; ++gt) {
        pacc[gt] += __shfl_xor(pacc[gt], 16);
        pacc[gt] += __shfl_xor(pacc[gt], 32);
    }
    if (lane < 16) {
#pragma unroll
        for (int gt = 0; gt < 4; ++gt)
            pbuf[l_half][g_half * 64 + gt * 16 + lane] = pacc[gt];
    }
    __syncthreads();
    if (tid < HD)
        pool_part[((size_t)(b * 64 + lt64)) * HD + tid] = pbuf[0][tid] + pbuf[1][tid];
}

// ---------------- finalize: denom + pool + lam mean/max ----------------

__global__ void finalize_kernel(const float* __restrict__ pool_part,
                                const float* __restrict__ mask,
                                const float* __restrict__ lam_ws,
                                float* __restrict__ d_out) {
    const size_t OUT1 = (size_t)BB * LL * HD;
    const size_t OUT2 = OUT1 + (size_t)BB * HD;
    const size_t OUT3 = OUT2 + BB;
    int b = blockIdx.x, tid = threadIdx.x;
    __shared__ float rsum[256], rmax[256];
    __shared__ float dsh;

    // denom = max(1, sum(mask[b]))
    float ms = 0.f;
    const float4* mp = (const float4*)(mask + (size_t)b * LL);
    for (int i = tid; i < LL / 4; i += 256) {
        float4 m = mp[i];
        ms += m.x + m.y + m.z + m.w;
    }
    rsum[tid] = ms; __syncthreads();
    for (int st = 128; st > 0; st >>= 1) {
        if (tid < st) rsum[tid] += rsum[tid + st];
        __syncthreads();
    }
    if (tid == 0) dsh = fmaxf(rsum[0], 1.0f);
    __syncthreads();
    float denom = dsh;

    if (tid < 128) {
        float s = 0.f;
        for (int blk = 0; blk < 64; ++blk)
            s += pool_part[((size_t)(b * 64 + blk)) * HD + tid];
        d_out[OUT1 + (size_t)b * HD + tid] = s / denom;
    }

    float v0 = lam_ws[(size_t)b * 512 + tid];
    float v1 = lam_ws[(size_t)b * 512 + 256 + tid];
    rsum[tid] = v0 + v1;
    rmax[tid] = fmaxf(v0, v1);
    __syncthreads();
    for (int st = 128; st > 0; st >>= 1) {
        if (tid < st) {
            rsum[tid] += rsum[tid + st];
            rmax[tid] = fmaxf(rmax[tid], rmax[tid + st]);
        }
        __syncthreads();
    }
    if (tid == 0) {
        d_out[OUT2 + b] = rsum[0] / 512.0f;
        d_out[OUT3 + b] = rmax[0];
    }
}

// ---------------- launch ----------------

extern "C" void kernel_launch(void* const* d_in, const int* in_sizes, int n_in,
                              void* d_out, int out_size, void* d_ws, size_t ws_size,
                              hipStream_t stream) {
    (void)in_sizes; (void)n_in; (void)out_size; (void)ws_size;
    const float* x      = (const float*)d_in[0];
    const float* mask   = (const float*)d_in[1];
    const float* flow   = (const float*)d_in[2];
    const float* W_in   = (const float*)d_in[3];
    const float* b_in   = (const float*)d_in[4];
    const float* W_mix  = (const float*)d_in[5];
    const float* b_mix  = (const float*)d_in[6];
    const float* lam_raw= (const float*)d_in[7];
    const float* Wgb    = (const float*)d_in[8];
    const float* bgb    = (const float*)d_in[9];
    const float* Wg     = (const float*)d_in[10];
    const float* bg     = (const float*)d_in[11];

    unsigned short* z_bf = (unsigned short*)d_ws;                 // 8388608 ushort
    unsigned short* s_bf = z_bf + (size_t)BB * HD * LL;           // 8388608 ushort
    float* film_ws   = (float*)(s_bf + (size_t)BB * HD * LL);     // 16384
    float* gate_ws   = film_ws + BB * 4 * 256;                    // 64
    float* lam_ws    = gate_ws + 64;                              // 8192
    float* pool_part = lam_ws + BB * 4 * 128;                     // 16*64*128 = 131072
    unsigned short* Bmix = (unsigned short*)(pool_part + BB * 64 * HD);  // 16384 ushort

    float* out = (float*)d_out;

    hipLaunchKernelGGL(zproj_kernel, dim3(BB * 64 + 128), dim3(256), 0, stream,
                       x, mask, W_in, b_in, z_bf,
                       W_mix, Bmix, flow, Wgb, bgb, Wg, bg, film_ws, gate_ws);
    hipLaunchKernelGGL(wavelet_kernel, dim3(BB * HD), dim3(256), 0, stream,
                       z_bf, s_bf, film_ws, gate_ws, lam_raw, lam_ws);
    hipLaunchKernelGGL(mix_kernel, dim3(BB * (LL / 64)), dim3(256), 0, stream,
                       s_bf, Bmix, b_mix, mask, out, pool_part);
    hipLaunchKernelGGL(finalize_kernel, dim3(BB), dim3(256), 0, stream,
                       pool_part, mask, lam_ws, out);
}

// Round 7
// 71.719 us; speedup vs baseline: 2.3031x; 1.0342x over previous
//
#include <hip/hip_runtime.h>
#include <math.h>

#define BB 16
#define LL 4096
#define CC 64
#define HD 128

typedef __attribute__((ext_vector_type(8))) short short8;
typedef __attribute__((ext_vector_type(8))) unsigned short ushort8;
typedef __attribute__((ext_vector_type(4))) float floatx4;

__constant__ float c_lo[8] = {
    -0.010597401784997278f, 0.032883011666982945f, 0.030841381835986965f,
    -0.18703481171888114f, -0.02798376941698385f, 0.6308807679295904f,
    0.7148465705525415f, 0.23037781330885523f};
__constant__ float c_hi[8] = {
    -0.23037781330885523f, 0.7148465705525415f, -0.6308807679295904f,
    -0.02798376941698385f, 0.18703481171888114f, 0.030841381835986965f,
    -0.032883011666982945f, -0.010597401784997278f};

__device__ __forceinline__ float gelu_exact(float x) {
    return 0.5f * x * (1.0f + erff(x * 0.70710678118654752440f));
}
__device__ __forceinline__ unsigned short f2b(float f) {   // f32 -> bf16 RNE
    unsigned int u = __float_as_uint(f);
    u = u + 0x7FFFu + ((u >> 16) & 1u);
    return (unsigned short)(u >> 16);
}
__device__ __forceinline__ float b2f(unsigned short s) {
    return __uint_as_float(((unsigned int)s) << 16);
}

// ---------------- zproj (+ fused pack blocks for Bmix / FiLM) ----------------

__global__ __launch_bounds__(256) void zproj_kernel(
    const float* __restrict__ x, const float* __restrict__ mask,
    const float* __restrict__ W_in, const float* __restrict__ b_in,
    unsigned short* __restrict__ z_bf,
    const float* __restrict__ W_mix, unsigned short* __restrict__ Bmix,
    const float* __restrict__ flow, const float* __restrict__ Wgb,
    const float* __restrict__ bgb, const float* __restrict__ Wg,
    const float* __restrict__ bg, float* __restrict__ film_ws,
    float* __restrict__ gate_ws) {
    int blk = blockIdx.x;
    int tid = threadIdx.x;

    if (blk >= BB * 64) {
        int e = blk - BB * 64;
        if (e < 64) {                               // Bmix pack: idx = ((h>>3)*128+g)*8+(h&7)
            int q = e * 256 + tid;                  // 16384
            int g = (q >> 3) & 127;
            int h = ((q >> 10) << 3) | (q & 7);
            Bmix[q] = f2b(W_mix[g * HD + h]);
        } else {                                    // FiLM
            int bf = e - 64;                        // b*4 + f
            int f = bf & 3;
            int b = bf >> 2;
            const float* fl = flow + b * 24;
            const float* wrow = Wgb + ((size_t)(f * 256 + tid)) * 24;
            float acc = bgb[f * 256 + tid];
#pragma unroll
            for (int j = 0; j < 24; ++j) acc = fmaf(wrow[j], fl[j], acc);
            film_ws[(size_t)bf * 256 + tid] = acc;
            if (tid == 0) {
                float g = bg[f];
#pragma unroll
                for (int j = 0; j < 24; ++j) g = fmaf(Wg[f * 24 + j], fl[j], g);
                gate_ws[bf] = 1.0f / (1.0f + expf(-g));
            }
        }
        return;
    }

    int b = blk >> 6;
    int l0 = (blk & 63) << 6;
    int lane = tid & 63;
    int w = tid >> 6;
    int h_half = w >> 1;
    int l_q = w & 1;
    int ln15 = lane & 15, lq4 = lane >> 4;

    int lr0 = l0 + l_q * 32 + ln15;
    int lr1 = lr0 + 16;
    float mk0 = mask[(size_t)b * LL + lr0];
    float mk1 = mask[(size_t)b * LL + lr1];

    floatx4 acc[4][2];
#pragma unroll
    for (int i = 0; i < 4; ++i)
#pragma unroll
        for (int j = 0; j < 2; ++j) acc[i][j] = (floatx4){0.f, 0.f, 0.f, 0.f};

#pragma unroll
    for (int ks = 0; ks < 2; ++ks) {
        int c0 = ks * 32 + (lq4 << 3);
        short8 bf0, bf1;
        {
            const float* xp = x + ((size_t)b * LL + lr0) * CC + c0;
            float4 xa = *(const float4*)xp;
            float4 xb = *(const float4*)(xp + 4);
            bf0[0] = (short)f2b(xa.x * mk0); bf0[1] = (short)f2b(xa.y * mk0);
            bf0[2] = (short)f2b(xa.z * mk0); bf0[3] = (short)f2b(xa.w * mk0);
            bf0[4] = (short)f2b(xb.x * mk0); bf0[5] = (short)f2b(xb.y * mk0);
            bf0[6] = (short)f2b(xb.z * mk0); bf0[7] = (short)f2b(xb.w * mk0);
        }
        {
            const float* xp = x + ((size_t)b * LL + lr1) * CC + c0;
            float4 xa = *(const float4*)xp;
            float4 xb = *(const float4*)(xp + 4);
            bf1[0] = (short)f2b(xa.x * mk1); bf1[1] = (short)f2b(xa.y * mk1);
            bf1[2] = (short)f2b(xa.z * mk1); bf1[3] = (short)f2b(xa.w * mk1);
            bf1[4] = (short)f2b(xb.x * mk1); bf1[5] = (short)f2b(xb.y * mk1);
            bf1[6] = (short)f2b(xb.z * mk1); bf1[7] = (short)f2b(xb.w * mk1);
        }
        int c8 = ks * 32 + (lq4 << 3);
        const float* wb = W_in + (size_t)(h_half * 64 + ln15) * CC + c8;
#pragma unroll
        for (int ht = 0; ht < 4; ++ht) {
            const float* wr = wb + (size_t)ht * 16 * CC;
            float4 wa = *(const float4*)wr;
            float4 wc = *(const float4*)(wr + 4);
            short8 af;
            af[0] = (short)f2b(wa.x); af[1] = (short)f2b(wa.y);
            af[2] = (short)f2b(wa.z); af[3] = (short)f2b(wa.w);
            af[4] = (short)f2b(wc.x); af[5] = (short)f2b(wc.y);
            af[6] = (short)f2b(wc.z); af[7] = (short)f2b(wc.w);
            acc[ht][0] = __builtin_amdgcn_mfma_f32_16x16x32_bf16(af, bf0, acc[ht][0], 0, 0, 0);
            acc[ht][1] = __builtin_amdgcn_mfma_f32_16x16x32_bf16(af, bf1, acc[ht][1], 0, 0, 0);
        }
    }

#pragma unroll
    for (int ht = 0; ht < 4; ++ht) {
#pragma unroll
        for (int r = 0; r < 4; ++r) {
            int h = h_half * 64 + ht * 16 + (lq4 << 2) + r;
            float bi = b_in[h];
            z_bf[((size_t)(b * HD + h)) * LL + lr0] = f2b(acc[ht][0][r] + bi);
            z_bf[((size_t)(b * HD + h)) * LL + lr1] = f2b(acc[ht][1][r] + bi);
        }
    }
}

// ---------------- wavelet helpers ----------------

__device__ __forceinline__ void analysis_step(const float* __restrict__ src,
                                              float* __restrict__ lo_dst,
                                              float* __restrict__ hi_dst,
                                              int half, int tid) {
    int len = half << 1;
    for (int q = tid; q < (half >> 2); q += 256) {
        int n0 = q << 2;
        float lo[4], hi[4];
        if (n0 + 4 == half) {                       // only quad that wraps
#pragma unroll
            for (int i = 0; i < 4; ++i) {
                float l = 0.f, hh = 0.f;
#pragma unroll
                for (int k = 0; k < 8; ++k) {
                    float v = src[(2 * (n0 + i) + k) & (len - 1)];
                    l = fmaf(c_lo[k], v, l);
                    hh = fmaf(c_hi[k], v, hh);
                }
                lo[i] = l; hi[i] = hh;
            }
        } else {
            float sv[16];
            const float* sp = src + (n0 << 1);
            *(float4*)&sv[0]  = *(const float4*)(sp);
            *(float4*)&sv[4]  = *(const float4*)(sp + 4);
            *(float4*)&sv[8]  = *(const float4*)(sp + 8);
            *(float4*)&sv[12] = *(const float4*)(sp + 12);
#pragma unroll
            for (int i = 0; i < 4; ++i) {
                float l = 0.f, hh = 0.f;
#pragma unroll
                for (int k = 0; k < 8; ++k) {
                    l = fmaf(c_lo[k], sv[2 * i + k], l);
                    hh = fmaf(c_hi[k], sv[2 * i + k], hh);
                }
                lo[i] = l; hi[i] = hh;
            }
        }
        *(float4*)&lo_dst[n0] = make_float4(lo[0], lo[1], lo[2], lo[3]);
        *(float4*)&hi_dst[n0] = make_float4(hi[0], hi[1], hi[2], hi[3]);
    }
}

__device__ __forceinline__ void synth_oct(const float* __restrict__ A,
                                          const float* __restrict__ D,
                                          int m0, int half, float* ov) {
    if (m0 == 0) {                                  // only oct that wraps (backward)
        int mask2 = (half << 1) - 1;
#pragma unroll
        for (int t = 0; t < 8; ++t) {
            int par = t & 1;
            float s = 0.f;
#pragma unroll
            for (int j = 0; j < 4; ++j) {
                int k = 2 * j + par;
                int idx = ((t - k) & mask2) >> 1;
                s = fmaf(c_lo[k], A[idx], s);
                s = fmaf(c_hi[k], D[idx], s);
            }
            ov[t] = s;
        }
    } else {
        float av[8], dv[8];
        *(float4*)&av[0] = *(const float4*)(A + m0 - 4);
        *(float4*)&av[4] = *(const float4*)(A + m0);
        *(float4*)&dv[0] = *(const float4*)(D + m0 - 4);
        *(float4*)&dv[4] = *(const float4*)(D + m0);
#pragma unroll
        for (int t = 0; t < 4; ++t) {
            float e = 0.f, o = 0.f;
#pragma unroll
            for (int j = 0; j < 4; ++j) {
                float xa = av[t + 4 - j], xd = dv[t + 4 - j];
                e = fmaf(c_lo[2 * j], xa, e);     e = fmaf(c_hi[2 * j], xd, e);
                o = fmaf(c_lo[2 * j + 1], xa, o); o = fmaf(c_hi[2 * j + 1], xd, o);
            }
            ov[2 * t] = e;
            ov[2 * t + 1] = o;
        }
    }
}

__device__ __forceinline__ void synth_step(const float* __restrict__ A,
                                           const float* __restrict__ D,
                                           float* __restrict__ dst,
                                           int half, int tid) {
    for (int q = tid; q < (half >> 2); q += 256) {
        int m0 = q << 2;
        int i0 = m0 << 1;
        float ov[8];
        synth_oct(A, D, m0, half, ov);
        *(float4*)&dst[i0]     = make_float4(ov[0], ov[1], ov[2], ov[3]);
        *(float4*)&dst[i0 + 4] = make_float4(ov[4], ov[5], ov[6], ov[7]);
    }
}

// ---------------- per-row wavelet: packed-bf16 row, register film/thresh ----------------
// LDS 32 KB -> 5 blocks/CU. zpk = raw row as u32 bf16-pairs (L1 reads optimal-stride
// b128 and traffic halves); film+|.|-reduce+threshold in 16 regs/thread (1 LDS read
// + 1 write instead of 2+2).

__global__ __launch_bounds__(256) void wavelet_kernel(const unsigned short* __restrict__ z_bf,
                                                      unsigned short* __restrict__ s_bf,
                                                      const float* __restrict__ film_ws,
                                                      const float* __restrict__ gate_ws,
                                                      const float* __restrict__ lam_raw,
                                                      float* __restrict__ lam_ws) {
    __shared__ unsigned int zpk[2048];   // 8 KB packed bf16 row
    __shared__ float d1[2048];           // 8 KB
    __shared__ float d2[1024];           // 4 KB
    __shared__ float Aq[2048];           // 8 KB  (a1 -> a3[0:512]+d3[512:1024] -> recon2048)
    __shared__ float Bq[1024];           // 4 KB  (a2 -> reduce scratch -> recon1024)

    int blk = blockIdx.x;
    int b = blk >> 7;
    int h = blk & 127;
    int tid = threadIdx.x;
    const uint4* zg4 = (const uint4*)(z_bf + ((size_t)(b * HD + h)) * LL);
    unsigned short* sg = s_bf + ((size_t)(b * HD + h)) * LL;

    for (int i = tid; i < 512; i += 256)
        ((uint4*)zpk)[i] = zg4[i];
    __syncthreads();

    // L1 from packed row: quad of outputs n0..n0+3 needs words n0..n0+6
    for (int q = tid; q < 512; q += 256) {
        int n0 = q << 2;
        float sv[16];
        if (n0 == 2044) {                           // the wrapping quad
#pragma unroll
            for (int j = 0; j < 14; ++j) {
                int idx = (2 * n0 + j) & 4095;
                unsigned int wv = zpk[idx >> 1];
                sv[j] = b2f((unsigned short)((idx & 1) ? (wv >> 16) : (wv & 0xffffu)));
            }
            sv[14] = 0.f; sv[15] = 0.f;
        } else {
            uint4 wa = *(const uint4*)(zpk + n0);
            uint4 wb = *(const uint4*)(zpk + n0 + 4);
            unsigned int ww[8] = {wa.x, wa.y, wa.z, wa.w, wb.x, wb.y, wb.z, wb.w};
#pragma unroll
            for (int j = 0; j < 8; ++j) {
                sv[2 * j]     = b2f((unsigned short)(ww[j] & 0xffffu));
                sv[2 * j + 1] = b2f((unsigned short)(ww[j] >> 16));
            }
        }
        float lo[4], hi[4];
#pragma unroll
        for (int i = 0; i < 4; ++i) {
            float l = 0.f, hh = 0.f;
#pragma unroll
            for (int k = 0; k < 8; ++k) {
                l = fmaf(c_lo[k], sv[2 * i + k], l);
                hh = fmaf(c_hi[k], sv[2 * i + k], hh);
            }
            lo[i] = l; hi[i] = hh;
        }
        *(float4*)&Aq[n0] = make_float4(lo[0], lo[1], lo[2], lo[3]);
        *(float4*)&d1[n0] = make_float4(hi[0], hi[1], hi[2], hi[3]);
    }
    __syncthreads();
    analysis_step(Aq, Bq, d2, 1024, tid);        // L2
    __syncthreads();
    analysis_step(Bq, Aq, Aq + 512, 512, tid);   // L3: a3 -> Aq[0:512], d3 -> Aq[512:1024]
    __syncthreads();

    float sc0, sh0, sc1, sh1, sc2, sh2, sc3, sh3;
    {
        int base = b * 4;
#define FILM_COEF(bd, SC, SH)                                              \
        {   float ga = film_ws[((size_t)(base + bd)) * 256 + h];           \
            float be = film_ws[((size_t)(base + bd)) * 256 + 128 + h];     \
            float gt = gate_ws[base + bd];                                 \
            SC = 1.0f + gt * ga; SH = gt * be; }
        FILM_COEF(0, sc0, sh0) FILM_COEF(1, sc1, sh1)
        FILM_COEF(2, sc2, sh2) FILM_COEF(3, sc3, sh3)
#undef FILM_COEF
    }

    // film in registers: p0 covers Aq[0:1024) (a3 | d3), p1/p2 cover d1, p3 covers d2
    float* p0 = &Aq[tid << 2];
    float* p1 = &d1[tid << 2];
    float* p2 = &d1[1024 + (tid << 2)];
    float* p3 = &d2[tid << 2];
    bool lowhalf = (tid < 128);                 // wave-uniform
    float scA = lowhalf ? sc0 : sc3, shA = lowhalf ? sh0 : sh3;

    float4 f0 = *(float4*)p0, f1 = *(float4*)p1, f2v = *(float4*)p2, f3 = *(float4*)p3;
#define FILMV(V, SC, SH)                                                   \
    { V.x = fmaf(V.x, SC, SH); V.y = fmaf(V.y, SC, SH);                    \
      V.z = fmaf(V.z, SC, SH); V.w = fmaf(V.w, SC, SH); }
    FILMV(f0, scA, shA) FILMV(f1, sc1, sh1) FILMV(f2v, sc1, sh1) FILMV(f3, sc2, sh2)
#undef FILMV
    float sA = fabsf(f0.x) + fabsf(f0.y) + fabsf(f0.z) + fabsf(f0.w);
    float s1 = fabsf(f1.x) + fabsf(f1.y) + fabsf(f1.z) + fabsf(f1.w)
             + fabsf(f2v.x) + fabsf(f2v.y) + fabsf(f2v.z) + fabsf(f2v.w);
    float s2 = fabsf(f3.x) + fabsf(f3.y) + fabsf(f3.z) + fabsf(f3.w);
#pragma unroll
    for (int off = 32; off > 0; off >>= 1) {
        sA += __shfl_xor(sA, off);
        s1 += __shfl_xor(s1, off);
        s2 += __shfl_xor(s2, off);
    }
    if ((tid & 63) == 0)
        ((float4*)Bq)[tid >> 6] = make_float4(lowhalf ? sA : 0.f, s1, s2,
                                              lowhalf ? 0.f : sA);
    __syncthreads();
    float4 r0 = ((const float4*)Bq)[0];
    float4 r1 = ((const float4*)Bq)[1];
    float4 r2 = ((const float4*)Bq)[2];
    float4 r3 = ((const float4*)Bq)[3];
    float lam0 = log1pf(expf(lam_raw[0])) * ((r0.x + r1.x + r2.x + r3.x) * (1.0f / 512.f));
    float lam1 = log1pf(expf(lam_raw[1])) * ((r0.y + r1.y + r2.y + r3.y) * (1.0f / 2048.f));
    float lam2 = log1pf(expf(lam_raw[2])) * ((r0.z + r1.z + r2.z + r3.z) * (1.0f / 1024.f));
    float lam3 = log1pf(expf(lam_raw[3])) * ((r0.w + r1.w + r2.w + r3.w) * (1.0f / 512.f));
    if (tid < 4) {
        float lam = (tid == 0) ? lam0 : (tid == 1) ? lam1 : (tid == 2) ? lam2 : lam3;
        lam_ws[((size_t)(b * 4 + tid)) * 128 + h] = lam;
    }
    float lamA = lowhalf ? lam0 : lam3;
#define THRV(V, LAM)                                                       \
    { float a;                                                             \
      a = fabsf(V.x) - (LAM); V.x = (a > 0.f) ? copysignf(a, V.x) : 0.f;   \
      a = fabsf(V.y) - (LAM); V.y = (a > 0.f) ? copysignf(a, V.y) : 0.f;   \
      a = fabsf(V.z) - (LAM); V.z = (a > 0.f) ? copysignf(a, V.z) : 0.f;   \
      a = fabsf(V.w) - (LAM); V.w = (a > 0.f) ? copysignf(a, V.w) : 0.f; }
    THRV(f0, lamA) THRV(f1, lam1) THRV(f2v, lam1) THRV(f3, lam2)
#undef THRV
    *(float4*)p0 = f0; *(float4*)p1 = f1; *(float4*)p2 = f2v; *(float4*)p3 = f3;
    __syncthreads();

    synth_step(Aq, Aq + 512, Bq, 512, tid);      // R1 -> Bq[0:1024]
    __syncthreads();
    synth_step(Bq, d2, Aq, 1024, tid);           // R2 -> Aq[0:2048]
    __syncthreads();
    for (int q = tid; q < 512; q += 256) {       // R3 + z add (from packed row) + bf16 store
        int m0 = q << 2;
        int i0 = m0 << 1;
        float ov[8];
        synth_oct(Aq, d1, m0, 2048, ov);
        uint4 zw = *(const uint4*)(zpk + (i0 >> 1));
        unsigned int zz[4] = {zw.x, zw.y, zw.z, zw.w};
        ushort8 o8;
#pragma unroll
        for (int t2 = 0; t2 < 4; ++t2) {
            float ze = b2f((unsigned short)(zz[t2] & 0xffffu));
            float zo = b2f((unsigned short)(zz[t2] >> 16));
            o8[2 * t2]     = f2b(ov[2 * t2] + ze);
            o8[2 * t2 + 1] = f2b(ov[2 * t2 + 1] + zo);
        }
        *(ushort8*)(sg + i0) = o8;
    }
}

// ---------------- mix: MFMA GEMM, 64-l tiles with in-LDS transpose ----------------

union U32x4S8 { unsigned int u[4]; short8 s; };

__global__ __launch_bounds__(256) void mix_kernel(const unsigned short* __restrict__ s_bf,
                                                  const unsigned short* __restrict__ Bmix,
                                                  const float* __restrict__ b_mix,
                                                  const float* __restrict__ mask,
                                                  float* __restrict__ out,
                                                  float* __restrict__ pool_part) {
    __shared__ unsigned int T[HD * 32];   // 16 KB, [h][lp ^ (h&31)]
    __shared__ float pbuf[2][HD];

    int blk = blockIdx.x;
    int b = blk >> 6;
    int lt64 = blk & 63;
    int l0 = lt64 << 6;
    int tid = threadIdx.x;
    int lane = tid & 63;
    int w = tid >> 6;
    int l_half = w >> 1, g_half = w & 1;
    int ln15 = lane & 15, lq4 = lane >> 4;

    {
        const unsigned int* src = (const unsigned int*)s_bf;
#pragma unroll
        for (int r = 0; r < 4; ++r) {
            int q = (r << 8) + tid;              // 0..1023
            int hh = q >> 3;                     // 0..127
            int k = q & 7;                       // 16B chunk
            uint4 v = *(const uint4*)(src + (size_t)(b * HD + hh) * (LL / 2) +
                                      (l0 >> 1) + (k << 2));
            int sw = hh & 31;
            unsigned int* tp = T + hh * 32;
            tp[((k << 2) + 0) ^ sw] = v.x;
            tp[((k << 2) + 1) ^ sw] = v.y;
            tp[((k << 2) + 2) ^ sw] = v.z;
            tp[((k << 2) + 3) ^ sw] = v.w;
        }
    }
    __syncthreads();

    floatx4 acc[2][4];
#pragma unroll
    for (int i = 0; i < 2; ++i)
#pragma unroll
        for (int j = 0; j < 4; ++j) acc[i][j] = (floatx4){0.f, 0.f, 0.f, 0.f};

    const unsigned short* Bb = Bmix + (g_half * 64 + ln15) * 8;

#pragma unroll 2
    for (int ks = 0; ks < 4; ++ks) {
        int koct = ks * 4 + lq4;
        short8 a[2], bb[4];
#pragma unroll
        for (int lt = 0; lt < 2; ++lt) {
            int l_loc = l_half * 32 + lt * 16 + ln15;
            int lp = l_loc >> 1;
            int odd = l_loc & 1;
            U32x4S8 cv;
#pragma unroll
            for (int qq = 0; qq < 4; ++qq) {
                int h0 = koct * 8 + 2 * qq;
                unsigned int w0 = T[h0 * 32 + (lp ^ (h0 & 31))];
                unsigned int w1 = T[(h0 + 1) * 32 + (lp ^ ((h0 + 1) & 31))];
                unsigned int e0 = odd ? (w0 >> 16) : (w0 & 0xffffu);
                unsigned int e1 = odd ? (w1 >> 16) : (w1 & 0xffffu);
                cv.u[qq] = e0 | (e1 << 16);
            }
            a[lt] = cv.s;
        }
#pragma unroll
        for (int gt = 0; gt < 4; ++gt)
            bb[gt] = *(const short8*)(Bb + (size_t)koct * 1024 + gt * 128);
#pragma unroll
        for (int lt = 0; lt < 2; ++lt)
#pragma unroll
            for (int gt = 0; gt < 4; ++gt)
                acc[lt][gt] = __builtin_amdgcn_mfma_f32_16x16x32_bf16(a[lt], bb[gt], acc[lt][gt], 0, 0, 0);
    }

    int gcol[4]; float bmv[4]; float pacc[4];
#pragma unroll
    for (int gt = 0; gt < 4; ++gt) {
        gcol[gt] = g_half * 64 + gt * 16 + ln15;
        bmv[gt] = b_mix[gcol[gt]];
        pacc[gt] = 0.f;
    }
#pragma unroll
    for (int lt = 0; lt < 2; ++lt) {
#pragma unroll
        for (int r = 0; r < 4; ++r) {
            int l = l0 + l_half * 32 + lt * 16 + (lq4 << 2) + r;
            float mkv = mask[(size_t)b * LL + l];
            float* orow = out + ((size_t)b * LL + l) * HD;
#pragma unroll
            for (int gt = 0; gt < 4; ++gt) {
                float v = gelu_exact(acc[lt][gt][r] + bmv[gt]) * mkv;
                orow[gcol[gt]] = v;
                pacc[gt] = fmaf(v, mkv, pacc[gt]);
            }
        }
    }
#pragma unroll
    for (int gt = 0; gt < 4; ++gt) {
        pacc[gt] += __shfl_xor(pacc[gt], 16);
        pacc[gt] += __shfl_xor(pacc[gt], 32);
    }
    if (lane < 16) {
#pragma unroll
        for (int gt = 0; gt < 4; ++gt)
            pbuf[l_half][g_half * 64 + gt * 16 + lane] = pacc[gt];
    }
    __syncthreads();
    if (tid < HD)
        pool_part[((size_t)(b * 64 + lt64)) * HD + tid] = pbuf[0][tid] + pbuf[1][tid];
}

// ---------------- finalize: denom + pool + lam mean/max ----------------

__global__ void finalize_kernel(const float* __restrict__ pool_part,
                                const float* __restrict__ mask,
                                const float* __restrict__ lam_ws,
                                float* __restrict__ d_out) {
    const size_t OUT1 = (size_t)BB * LL * HD;
    const size_t OUT2 = OUT1 + (size_t)BB * HD;
    const size_t OUT3 = OUT2 + BB;
    int b = blockIdx.x, tid = threadIdx.x;
    __shared__ float rsum[256], rmax[256];
    __shared__ float dsh;

    float ms = 0.f;
    const float4* mp = (const float4*)(mask + (size_t)b * LL);
    for (int i = tid; i < LL / 4; i += 256) {
        float4 m = mp[i];
        ms += m.x + m.y + m.z + m.w;
    }
    rsum[tid] = ms; __syncthreads();
    for (int st = 128; st > 0; st >>= 1) {
        if (tid < st) rsum[tid] += rsum[tid + st];
        __syncthreads();
    }
    if (tid == 0) dsh = fmaxf(rsum[0], 1.0f);
    __syncthreads();
    float denom = dsh;

    if (tid < 128) {
        float s = 0.f;
        for (int blk = 0; blk < 64; ++blk)
            s += pool_part[((size_t)(b * 64 + blk)) * HD + tid];
        d_out[OUT1 + (size_t)b * HD + tid] = s / denom;
    }

    float v0 = lam_ws[(size_t)b * 512 + tid];
    float v1 = lam_ws[(size_t)b * 512 + 256 + tid];
    rsum[tid] = v0 + v1;
    rmax[tid] = fmaxf(v0, v1);
    __syncthreads();
    for (int st = 128; st > 0; st >>= 1) {
        if (tid < st) {
            rsum[tid] += rsum[tid + st];
            rmax[tid] = fmaxf(rmax[tid], rmax[tid + st]);
        }
        __syncthreads();
    }
    if (tid == 0) {
        d_out[OUT2 + b] = rsum[0] / 512.0f;
        d_out[OUT3 + b] = rmax[0];
    }
}

// ---------------- launch ----------------

extern "C" void kernel_launch(void* const* d_in, const int* in_sizes, int n_in,
                              void* d_out, int out_size, void* d_ws, size_t ws_size,
                              hipStream_t stream) {
    (void)in_sizes; (void)n_in; (void)out_size; (void)ws_size;
    const float* x      = (const float*)d_in[0];
    const float* mask   = (const float*)d_in[1];
    const float* flow   = (const float*)d_in[2];
    const float* W_in   = (const float*)d_in[3];
    const float* b_in   = (const float*)d_in[4];
    const float* W_mix  = (const float*)d_in[5];
    const float* b_mix  = (const float*)d_in[6];
    const float* lam_raw= (const float*)d_in[7];
    const float* Wgb    = (const float*)d_in[8];
    const float* bgb    = (const float*)d_in[9];
    const float* Wg     = (const float*)d_in[10];
    const float* bg     = (const float*)d_in[11];

    unsigned short* z_bf = (unsigned short*)d_ws;                 // 8388608 ushort
    unsigned short* s_bf = z_bf + (size_t)BB * HD * LL;           // 8388608 ushort
    float* film_ws   = (float*)(s_bf + (size_t)BB * HD * LL);     // 16384
    float* gate_ws   = film_ws + BB * 4 * 256;                    // 64
    float* lam_ws    = gate_ws + 64;                              // 8192
    float* pool_part = lam_ws + BB * 4 * 128;                     // 16*64*128 = 131072
    unsigned short* Bmix = (unsigned short*)(pool_part + BB * 64 * HD);  // 16384 ushort

    float* out = (float*)d_out;

    hipLaunchKernelGGL(zproj_kernel, dim3(BB * 64 + 128), dim3(256), 0, stream,
                       x, mask, W_in, b_in, z_bf,
                       W_mix, Bmix, flow, Wgb, bgb, Wg, bg, film_ws, gate_ws);
    hipLaunchKernelGGL(wavelet_kernel, dim3(BB * HD), dim3(256), 0, stream,
                       z_bf, s_bf, film_ws, gate_ws, lam_raw, lam_ws);
    hipLaunchKernelGGL(mix_kernel, dim3(BB * (LL / 64)), dim3(256), 0, stream,
                       s_bf, Bmix, b_mix, mask, out, pool_part);
    hipLaunchKernelGGL(finalize_kernel, dim3(BB), dim3(256), 0, stream,
                       pool_part, mask, lam_ws, out);
}

// Round 8
// 69.103 us; speedup vs baseline: 2.3903x; 1.0379x over previous
//
#include <hip/hip_runtime.h>
#include <math.h>

#define BB 16
#define LL 4096
#define CC 64
#define HD 128

typedef __attribute__((ext_vector_type(8))) short short8;
typedef __attribute__((ext_vector_type(8))) unsigned short ushort8;
typedef __attribute__((ext_vector_type(4))) float floatx4;

__constant__ float c_lo[8] = {
    -0.010597401784997278f, 0.032883011666982945f, 0.030841381835986965f,
    -0.18703481171888114f, -0.02798376941698385f, 0.6308807679295904f,
    0.7148465705525415f, 0.23037781330885523f};
__constant__ float c_hi[8] = {
    -0.23037781330885523f, 0.7148465705525415f, -0.6308807679295904f,
    -0.02798376941698385f, 0.18703481171888114f, 0.030841381835986965f,
    -0.032883011666982945f, -0.010597401784997278f};

// tanh-GELU in sigmoid form: gelu(x) ~= x * sigmoid(1.5957691*(x + 0.044715 x^3))
// max abs error vs exact erf-GELU ~3e-4 (<< 0.12 threshold slack)
__device__ __forceinline__ float gelu_fast(float x) {
    float u = x * fmaf(0.044715f * x, x, 1.0f) * 1.5957691216057308f;
    return x / (1.0f + __expf(-u));
}
__device__ __forceinline__ unsigned short f2b(float f) {   // f32 -> bf16 RNE
    unsigned int u = __float_as_uint(f);
    u = u + 0x7FFFu + ((u >> 16) & 1u);
    return (unsigned short)(u >> 16);
}
__device__ __forceinline__ float b2f(unsigned short s) {
    return __uint_as_float(((unsigned int)s) << 16);
}

// ---------------- zproj (+ fused pack blocks for Bmix / FiLM) ----------------
// Operand-swapped MFMA: D[l][h] (lane = fixed h, regs = 4 consecutive l)
// -> epilogue is 8x ushort4 stores instead of 32 scalar 2B stores.

__global__ __launch_bounds__(256) void zproj_kernel(
    const float* __restrict__ x, const float* __restrict__ mask,
    const float* __restrict__ W_in, const float* __restrict__ b_in,
    unsigned short* __restrict__ z_bf,
    const float* __restrict__ W_mix, unsigned short* __restrict__ Bmix,
    const float* __restrict__ flow, const float* __restrict__ Wgb,
    const float* __restrict__ bgb, const float* __restrict__ Wg,
    const float* __restrict__ bg, float* __restrict__ film_ws,
    float* __restrict__ gate_ws) {
    int blk = blockIdx.x;
    int tid = threadIdx.x;

    if (blk >= BB * 64) {
        int e = blk - BB * 64;
        if (e < 64) {                               // Bmix pack: idx = ((h>>3)*128+g)*8+(h&7)
            int q = e * 256 + tid;                  // 16384
            int g = (q >> 3) & 127;
            int h = ((q >> 10) << 3) | (q & 7);
            Bmix[q] = f2b(W_mix[g * HD + h]);
        } else {                                    // FiLM
            int bf = e - 64;                        // b*4 + f
            int f = bf & 3;
            int b = bf >> 2;
            const float* fl = flow + b * 24;
            const float* wrow = Wgb + ((size_t)(f * 256 + tid)) * 24;
            float acc = bgb[f * 256 + tid];
#pragma unroll
            for (int j = 0; j < 24; ++j) acc = fmaf(wrow[j], fl[j], acc);
            film_ws[(size_t)bf * 256 + tid] = acc;
            if (tid == 0) {
                float g = bg[f];
#pragma unroll
                for (int j = 0; j < 24; ++j) g = fmaf(Wg[f * 24 + j], fl[j], g);
                gate_ws[bf] = 1.0f / (1.0f + expf(-g));
            }
        }
        return;
    }

    int b = blk >> 6;
    int l0 = (blk & 63) << 6;
    int lane = tid & 63;
    int w = tid >> 6;
    int h_half = w >> 1;
    int l_q = w & 1;
    int ln15 = lane & 15, lq4 = lane >> 4;

    int lr0 = l0 + l_q * 32 + ln15;
    int lr1 = lr0 + 16;
    float mk0 = mask[(size_t)b * LL + lr0];
    float mk1 = mask[(size_t)b * LL + lr1];

    floatx4 acc[4][2];
#pragma unroll
    for (int i = 0; i < 4; ++i)
#pragma unroll
        for (int j = 0; j < 2; ++j) acc[i][j] = (floatx4){0.f, 0.f, 0.f, 0.f};

#pragma unroll
    for (int ks = 0; ks < 2; ++ks) {
        int c0 = ks * 32 + (lq4 << 3);
        short8 bf0, bf1;
        {
            const float* xp = x + ((size_t)b * LL + lr0) * CC + c0;
            float4 xa = *(const float4*)xp;
            float4 xb = *(const float4*)(xp + 4);
            bf0[0] = (short)f2b(xa.x * mk0); bf0[1] = (short)f2b(xa.y * mk0);
            bf0[2] = (short)f2b(xa.z * mk0); bf0[3] = (short)f2b(xa.w * mk0);
            bf0[4] = (short)f2b(xb.x * mk0); bf0[5] = (short)f2b(xb.y * mk0);
            bf0[6] = (short)f2b(xb.z * mk0); bf0[7] = (short)f2b(xb.w * mk0);
        }
        {
            const float* xp = x + ((size_t)b * LL + lr1) * CC + c0;
            float4 xa = *(const float4*)xp;
            float4 xb = *(const float4*)(xp + 4);
            bf1[0] = (short)f2b(xa.x * mk1); bf1[1] = (short)f2b(xa.y * mk1);
            bf1[2] = (short)f2b(xa.z * mk1); bf1[3] = (short)f2b(xa.w * mk1);
            bf1[4] = (short)f2b(xb.x * mk1); bf1[5] = (short)f2b(xb.y * mk1);
            bf1[6] = (short)f2b(xb.z * mk1); bf1[7] = (short)f2b(xb.w * mk1);
        }
        const float* wb = W_in + (size_t)(h_half * 64 + ln15) * CC + c0;
#pragma unroll
        for (int ht = 0; ht < 4; ++ht) {
            const float* wr = wb + (size_t)ht * 16 * CC;
            float4 wa = *(const float4*)wr;
            float4 wc = *(const float4*)(wr + 4);
            short8 af;
            af[0] = (short)f2b(wa.x); af[1] = (short)f2b(wa.y);
            af[2] = (short)f2b(wa.z); af[3] = (short)f2b(wa.w);
            af[4] = (short)f2b(wc.x); af[5] = (short)f2b(wc.y);
            af[6] = (short)f2b(wc.z); af[7] = (short)f2b(wc.w);
            // swapped operands: D[l][h] = x . W^T
            acc[ht][0] = __builtin_amdgcn_mfma_f32_16x16x32_bf16(bf0, af, acc[ht][0], 0, 0, 0);
            acc[ht][1] = __builtin_amdgcn_mfma_f32_16x16x32_bf16(bf1, af, acc[ht][1], 0, 0, 0);
        }
    }

#pragma unroll
    for (int ht = 0; ht < 4; ++ht) {
        int h = h_half * 64 + ht * 16 + ln15;        // fixed per lane
        float bi = b_in[h];
        unsigned short* zr = z_bf + ((size_t)(b * HD + h)) * LL;
#pragma unroll
        for (int j = 0; j < 2; ++j) {
            int lbase = l0 + l_q * 32 + j * 16 + (lq4 << 2);
            ushort4 o;
            o.x = f2b(acc[ht][j][0] + bi);
            o.y = f2b(acc[ht][j][1] + bi);
            o.z = f2b(acc[ht][j][2] + bi);
            o.w = f2b(acc[ht][j][3] + bi);
            *(ushort4*)(zr + lbase) = o;
        }
    }
}

// ---------------- wavelet helpers ----------------

__device__ __forceinline__ void analysis_step(const float* __restrict__ src,
                                              float* __restrict__ lo_dst,
                                              float* __restrict__ hi_dst,
                                              int half, int tid) {
    int len = half << 1;
    for (int q = tid; q < (half >> 2); q += 256) {
        int n0 = q << 2;
        float lo[4], hi[4];
        if (n0 + 4 == half) {                       // only quad that wraps
#pragma unroll
            for (int i = 0; i < 4; ++i) {
                float l = 0.f, hh = 0.f;
#pragma unroll
                for (int k = 0; k < 8; ++k) {
                    float v = src[(2 * (n0 + i) + k) & (len - 1)];
                    l = fmaf(c_lo[k], v, l);
                    hh = fmaf(c_hi[k], v, hh);
                }
                lo[i] = l; hi[i] = hh;
            }
        } else {
            float sv[16];
            const float* sp = src + (n0 << 1);
            *(float4*)&sv[0]  = *(const float4*)(sp);
            *(float4*)&sv[4]  = *(const float4*)(sp + 4);
            *(float4*)&sv[8]  = *(const float4*)(sp + 8);
            *(float4*)&sv[12] = *(const float4*)(sp + 12);
#pragma unroll
            for (int i = 0; i < 4; ++i) {
                float l = 0.f, hh = 0.f;
#pragma unroll
                for (int k = 0; k < 8; ++k) {
                    l = fmaf(c_lo[k], sv[2 * i + k], l);
                    hh = fmaf(c_hi[k], sv[2 * i + k], hh);
                }
                lo[i] = l; hi[i] = hh;
            }
        }
        *(float4*)&lo_dst[n0] = make_float4(lo[0], lo[1], lo[2], lo[3]);
        *(float4*)&hi_dst[n0] = make_float4(hi[0], hi[1], hi[2], hi[3]);
    }
}

__device__ __forceinline__ void synth_oct(const float* __restrict__ A,
                                          const float* __restrict__ D,
                                          int m0, int half, float* ov) {
    if (m0 == 0) {                                  // only oct that wraps (backward)
        int mask2 = (half << 1) - 1;
#pragma unroll
        for (int t = 0; t < 8; ++t) {
            int par = t & 1;
            float s = 0.f;
#pragma unroll
            for (int j = 0; j < 4; ++j) {
                int k = 2 * j + par;
                int idx = ((t - k) & mask2) >> 1;
                s = fmaf(c_lo[k], A[idx], s);
                s = fmaf(c_hi[k], D[idx], s);
            }
            ov[t] = s;
        }
    } else {
        float av[8], dv[8];
        *(float4*)&av[0] = *(const float4*)(A + m0 - 4);
        *(float4*)&av[4] = *(const float4*)(A + m0);
        *(float4*)&dv[0] = *(const float4*)(D + m0 - 4);
        *(float4*)&dv[4] = *(const float4*)(D + m0);
#pragma unroll
        for (int t = 0; t < 4; ++t) {
            float e = 0.f, o = 0.f;
#pragma unroll
            for (int j = 0; j < 4; ++j) {
                float xa = av[t + 4 - j], xd = dv[t + 4 - j];
                e = fmaf(c_lo[2 * j], xa, e);     e = fmaf(c_hi[2 * j], xd, e);
                o = fmaf(c_lo[2 * j + 1], xa, o); o = fmaf(c_hi[2 * j + 1], xd, o);
            }
            ov[2 * t] = e;
            ov[2 * t + 1] = o;
        }
    }
}

__device__ __forceinline__ void synth_step(const float* __restrict__ A,
                                           const float* __restrict__ D,
                                           float* __restrict__ dst,
                                           int half, int tid) {
    for (int q = tid; q < (half >> 2); q += 256) {
        int m0 = q << 2;
        int i0 = m0 << 1;
        float ov[8];
        synth_oct(A, D, m0, half, ov);
        *(float4*)&dst[i0]     = make_float4(ov[0], ov[1], ov[2], ov[3]);
        *(float4*)&dst[i0 + 4] = make_float4(ov[4], ov[5], ov[6], ov[7]);
    }
}

// ---------------- per-row wavelet: packed-bf16 row, register film/thresh ----------------

__global__ __launch_bounds__(256) void wavelet_kernel(const unsigned short* __restrict__ z_bf,
                                                      unsigned short* __restrict__ s_bf,
                                                      const float* __restrict__ film_ws,
                                                      const float* __restrict__ gate_ws,
                                                      const float* __restrict__ lam_raw,
                                                      float* __restrict__ lam_ws) {
    __shared__ unsigned int zpk[2048];   // 8 KB packed bf16 row
    __shared__ float d1[2048];           // 8 KB
    __shared__ float d2[1024];           // 4 KB
    __shared__ float Aq[2048];           // 8 KB
    __shared__ float Bq[1024];           // 4 KB

    int blk = blockIdx.x;
    int b = blk >> 7;
    int h = blk & 127;
    int tid = threadIdx.x;
    const uint4* zg4 = (const uint4*)(z_bf + ((size_t)(b * HD + h)) * LL);
    unsigned short* sg = s_bf + ((size_t)(b * HD + h)) * LL;

    for (int i = tid; i < 512; i += 256)
        ((uint4*)zpk)[i] = zg4[i];
    __syncthreads();

    for (int q = tid; q < 512; q += 256) {
        int n0 = q << 2;
        float sv[16];
        if (n0 == 2044) {                           // the wrapping quad
#pragma unroll
            for (int j = 0; j < 14; ++j) {
                int idx = (2 * n0 + j) & 4095;
                unsigned int wv = zpk[idx >> 1];
                sv[j] = b2f((unsigned short)((idx & 1) ? (wv >> 16) : (wv & 0xffffu)));
            }
            sv[14] = 0.f; sv[15] = 0.f;
        } else {
            uint4 wa = *(const uint4*)(zpk + n0);
            uint4 wb = *(const uint4*)(zpk + n0 + 4);
            unsigned int ww[8] = {wa.x, wa.y, wa.z, wa.w, wb.x, wb.y, wb.z, wb.w};
#pragma unroll
            for (int j = 0; j < 8; ++j) {
                sv[2 * j]     = b2f((unsigned short)(ww[j] & 0xffffu));
                sv[2 * j + 1] = b2f((unsigned short)(ww[j] >> 16));
            }
        }
        float lo[4], hi[4];
#pragma unroll
        for (int i = 0; i < 4; ++i) {
            float l = 0.f, hh = 0.f;
#pragma unroll
            for (int k = 0; k < 8; ++k) {
                l = fmaf(c_lo[k], sv[2 * i + k], l);
                hh = fmaf(c_hi[k], sv[2 * i + k], hh);
            }
            lo[i] = l; hi[i] = hh;
        }
        *(float4*)&Aq[n0] = make_float4(lo[0], lo[1], lo[2], lo[3]);
        *(float4*)&d1[n0] = make_float4(hi[0], hi[1], hi[2], hi[3]);
    }
    __syncthreads();
    analysis_step(Aq, Bq, d2, 1024, tid);        // L2
    __syncthreads();
    analysis_step(Bq, Aq, Aq + 512, 512, tid);   // L3
    __syncthreads();

    float sc0, sh0, sc1, sh1, sc2, sh2, sc3, sh3;
    {
        int base = b * 4;
#define FILM_COEF(bd, SC, SH)                                              \
        {   float ga = film_ws[((size_t)(base + bd)) * 256 + h];           \
            float be = film_ws[((size_t)(base + bd)) * 256 + 128 + h];     \
            float gt = gate_ws[base + bd];                                 \
            SC = 1.0f + gt * ga; SH = gt * be; }
        FILM_COEF(0, sc0, sh0) FILM_COEF(1, sc1, sh1)
        FILM_COEF(2, sc2, sh2) FILM_COEF(3, sc3, sh3)
#undef FILM_COEF
    }

    float* p0 = &Aq[tid << 2];
    float* p1 = &d1[tid << 2];
    float* p2 = &d1[1024 + (tid << 2)];
    float* p3 = &d2[tid << 2];
    bool lowhalf = (tid < 128);
    float scA = lowhalf ? sc0 : sc3, shA = lowhalf ? sh0 : sh3;

    float4 f0 = *(float4*)p0, f1 = *(float4*)p1, f2v = *(float4*)p2, f3 = *(float4*)p3;
#define FILMV(V, SC, SH)                                                   \
    { V.x = fmaf(V.x, SC, SH); V.y = fmaf(V.y, SC, SH);                    \
      V.z = fmaf(V.z, SC, SH); V.w = fmaf(V.w, SC, SH); }
    FILMV(f0, scA, shA) FILMV(f1, sc1, sh1) FILMV(f2v, sc1, sh1) FILMV(f3, sc2, sh2)
#undef FILMV
    float sA = fabsf(f0.x) + fabsf(f0.y) + fabsf(f0.z) + fabsf(f0.w);
    float s1 = fabsf(f1.x) + fabsf(f1.y) + fabsf(f1.z) + fabsf(f1.w)
             + fabsf(f2v.x) + fabsf(f2v.y) + fabsf(f2v.z) + fabsf(f2v.w);
    float s2 = fabsf(f3.x) + fabsf(f3.y) + fabsf(f3.z) + fabsf(f3.w);
#pragma unroll
    for (int off = 32; off > 0; off >>= 1) {
        sA += __shfl_xor(sA, off);
        s1 += __shfl_xor(s1, off);
        s2 += __shfl_xor(s2, off);
    }
    if ((tid & 63) == 0)
        ((float4*)Bq)[tid >> 6] = make_float4(lowhalf ? sA : 0.f, s1, s2,
                                              lowhalf ? 0.f : sA);
    __syncthreads();
    float4 r0 = ((const float4*)Bq)[0];
    float4 r1 = ((const float4*)Bq)[1];
    float4 r2 = ((const float4*)Bq)[2];
    float4 r3 = ((const float4*)Bq)[3];
    float lam0 = log1pf(expf(lam_raw[0])) * ((r0.x + r1.x + r2.x + r3.x) * (1.0f / 512.f));
    float lam1 = log1pf(expf(lam_raw[1])) * ((r0.y + r1.y + r2.y + r3.y) * (1.0f / 2048.f));
    float lam2 = log1pf(expf(lam_raw[2])) * ((r0.z + r1.z + r2.z + r3.z) * (1.0f / 1024.f));
    float lam3 = log1pf(expf(lam_raw[3])) * ((r0.w + r1.w + r2.w + r3.w) * (1.0f / 512.f));
    if (tid < 4) {
        float lam = (tid == 0) ? lam0 : (tid == 1) ? lam1 : (tid == 2) ? lam2 : lam3;
        lam_ws[((size_t)(b * 4 + tid)) * 128 + h] = lam;
    }
    float lamA = lowhalf ? lam0 : lam3;
#define THRV(V, LAM)                                                       \
    { float a;                                                             \
      a = fabsf(V.x) - (LAM); V.x = (a > 0.f) ? copysignf(a, V.x) : 0.f;   \
      a = fabsf(V.y) - (LAM); V.y = (a > 0.f) ? copysignf(a, V.y) : 0.f;   \
      a = fabsf(V.z) - (LAM); V.z = (a > 0.f) ? copysignf(a, V.z) : 0.f;   \
      a = fabsf(V.w) - (LAM); V.w = (a > 0.f) ? copysignf(a, V.w) : 0.f; }
    THRV(f0, lamA) THRV(f1, lam1) THRV(f2v, lam1) THRV(f3, lam2)
#undef THRV
    *(float4*)p0 = f0; *(float4*)p1 = f1; *(float4*)p2 = f2v; *(float4*)p3 = f3;
    __syncthreads();

    synth_step(Aq, Aq + 512, Bq, 512, tid);      // R1 -> Bq[0:1024]
    __syncthreads();
    synth_step(Bq, d2, Aq, 1024, tid);           // R2 -> Aq[0:2048]
    __syncthreads();
    for (int q = tid; q < 512; q += 256) {       // R3 + z add + bf16 store
        int m0 = q << 2;
        int i0 = m0 << 1;
        float ov[8];
        synth_oct(Aq, d1, m0, 2048, ov);
        uint4 zw = *(const uint4*)(zpk + (i0 >> 1));
        unsigned int zz[4] = {zw.x, zw.y, zw.z, zw.w};
        ushort8 o8;
#pragma unroll
        for (int t2 = 0; t2 < 4; ++t2) {
            float ze = b2f((unsigned short)(zz[t2] & 0xffffu));
            float zo = b2f((unsigned short)(zz[t2] >> 16));
            o8[2 * t2]     = f2b(ov[2 * t2] + ze);
            o8[2 * t2 + 1] = f2b(ov[2 * t2 + 1] + zo);
        }
        *(ushort8*)(sg + i0) = o8;
    }
}

// ---------------- mix: MFMA GEMM, 64-l tiles with in-LDS transpose ----------------

union U32x4S8 { unsigned int u[4]; short8 s; };

__global__ __launch_bounds__(256) void mix_kernel(const unsigned short* __restrict__ s_bf,
                                                  const unsigned short* __restrict__ Bmix,
                                                  const float* __restrict__ b_mix,
                                                  const float* __restrict__ mask,
                                                  float* __restrict__ out,
                                                  float* __restrict__ pool_part) {
    __shared__ unsigned int T[HD * 32];   // 16 KB, [h][lp ^ (h&31)]
    __shared__ float pbuf[2][HD];

    int blk = blockIdx.x;
    int b = blk >> 6;
    int lt64 = blk & 63;
    int l0 = lt64 << 6;
    int tid = threadIdx.x;
    int lane = tid & 63;
    int w = tid >> 6;
    int l_half = w >> 1, g_half = w & 1;
    int ln15 = lane & 15, lq4 = lane >> 4;

    {
        const unsigned int* src = (const unsigned int*)s_bf;
#pragma unroll
        for (int r = 0; r < 4; ++r) {
            int q = (r << 8) + tid;              // 0..1023
            int hh = q >> 3;                     // 0..127
            int k = q & 7;                       // 16B chunk
            uint4 v = *(const uint4*)(src + (size_t)(b * HD + hh) * (LL / 2) +
                                      (l0 >> 1) + (k << 2));
            int sw = hh & 31;
            unsigned int* tp = T + hh * 32;
            tp[((k << 2) + 0) ^ sw] = v.x;
            tp[((k << 2) + 1) ^ sw] = v.y;
            tp[((k << 2) + 2) ^ sw] = v.z;
            tp[((k << 2) + 3) ^ sw] = v.w;
        }
    }
    __syncthreads();

    floatx4 acc[2][4];
#pragma unroll
    for (int i = 0; i < 2; ++i)
#pragma unroll
        for (int j = 0; j < 4; ++j) acc[i][j] = (floatx4){0.f, 0.f, 0.f, 0.f};

    const unsigned short* Bb = Bmix + (g_half * 64 + ln15) * 8;

#pragma unroll 2
    for (int ks = 0; ks < 4; ++ks) {
        int koct = ks * 4 + lq4;
        short8 a[2], bb[4];
#pragma unroll
        for (int lt = 0; lt < 2; ++lt) {
            int l_loc = l_half * 32 + lt * 16 + ln15;
            int lp = l_loc >> 1;
            int odd = l_loc & 1;
            U32x4S8 cv;
#pragma unroll
            for (int qq = 0; qq < 4; ++qq) {
                int h0 = koct * 8 + 2 * qq;
                unsigned int w0 = T[h0 * 32 + (lp ^ (h0 & 31))];
                unsigned int w1 = T[(h0 + 1) * 32 + (lp ^ ((h0 + 1) & 31))];
                unsigned int e0 = odd ? (w0 >> 16) : (w0 & 0xffffu);
                unsigned int e1 = odd ? (w1 >> 16) : (w1 & 0xffffu);
                cv.u[qq] = e0 | (e1 << 16);
            }
            a[lt] = cv.s;
        }
#pragma unroll
        for (int gt = 0; gt < 4; ++gt)
            bb[gt] = *(const short8*)(Bb + (size_t)koct * 1024 + gt * 128);
#pragma unroll
        for (int lt = 0; lt < 2; ++lt)
#pragma unroll
            for (int gt = 0; gt < 4; ++gt)
                acc[lt][gt] = __builtin_amdgcn_mfma_f32_16x16x32_bf16(a[lt], bb[gt], acc[lt][gt], 0, 0, 0);
    }

    int gcol[4]; float bmv[4]; float pacc[4];
#pragma unroll
    for (int gt = 0; gt < 4; ++gt) {
        gcol[gt] = g_half * 64 + gt * 16 + ln15;
        bmv[gt] = b_mix[gcol[gt]];
        pacc[gt] = 0.f;
    }
#pragma unroll
    for (int lt = 0; lt < 2; ++lt) {
#pragma unroll
        for (int r = 0; r < 4; ++r) {
            int l = l0 + l_half * 32 + lt * 16 + (lq4 << 2) + r;
            float mkv = mask[(size_t)b * LL + l];
            float* orow = out + ((size_t)b * LL + l) * HD;
#pragma unroll
            for (int gt = 0; gt < 4; ++gt) {
                float v = gelu_fast(acc[lt][gt][r] + bmv[gt]) * mkv;
                orow[gcol[gt]] = v;
                pacc[gt] = fmaf(v, mkv, pacc[gt]);
            }
        }
    }
#pragma unroll
    for (int gt = 0; gt < 4; ++gt) {
        pacc[gt] += __shfl_xor(pacc[gt], 16);
        pacc[gt] += __shfl_xor(pacc[gt], 32);
    }
    if (lane < 16) {
#pragma unroll
        for (int gt = 0; gt < 4; ++gt)
            pbuf[l_half][g_half * 64 + gt * 16 + lane] = pacc[gt];
    }
    __syncthreads();
    if (tid < HD)
        pool_part[((size_t)(b * 64 + lt64)) * HD + tid] = pbuf[0][tid] + pbuf[1][tid];
}

// ---------------- finalize: denom + pool + lam mean/max ----------------

__global__ void finalize_kernel(const float* __restrict__ pool_part,
                                const float* __restrict__ mask,
                                const float* __restrict__ lam_ws,
                                float* __restrict__ d_out) {
    const size_t OUT1 = (size_t)BB * LL * HD;
    const size_t OUT2 = OUT1 + (size_t)BB * HD;
    const size_t OUT3 = OUT2 + BB;
    int b = blockIdx.x, tid = threadIdx.x;
    __shared__ float rsum[256], rmax[256];
    __shared__ float dsh;

    float ms = 0.f;
    const float4* mp = (const float4*)(mask + (size_t)b * LL);
    for (int i = tid; i < LL / 4; i += 256) {
        float4 m = mp[i];
        ms += m.x + m.y + m.z + m.w;
    }
    rsum[tid] = ms; __syncthreads();
    for (int st = 128; st > 0; st >>= 1) {
        if (tid < st) rsum[tid] += rsum[tid + st];
        __syncthreads();
    }
    if (tid == 0) dsh = fmaxf(rsum[0], 1.0f);
    __syncthreads();
    float denom = dsh;

    if (tid < 128) {
        float s = 0.f;
        for (int blk = 0; blk < 64; ++blk)
            s += pool_part[((size_t)(b * 64 + blk)) * HD + tid];
        d_out[OUT1 + (size_t)b * HD + tid] = s / denom;
    }

    float v0 = lam_ws[(size_t)b * 512 + tid];
    float v1 = lam_ws[(size_t)b * 512 + 256 + tid];
    rsum[tid] = v0 + v1;
    rmax[tid] = fmaxf(v0, v1);
    __syncthreads();
    for (int st = 128; st > 0; st >>= 1) {
        if (tid < st) {
            rsum[tid] += rsum[tid + st];
            rmax[tid] = fmaxf(rmax[tid], rmax[tid + st]);
        }
        __syncthreads();
    }
    if (tid == 0) {
        d_out[OUT2 + b] = rsum[0] / 512.0f;
        d_out[OUT3 + b] = rmax[0];
    }
}

// ---------------- launch ----------------

extern "C" void kernel_launch(void* const* d_in, const int* in_sizes, int n_in,
                              void* d_out, int out_size, void* d_ws, size_t ws_size,
                              hipStream_t stream) {
    (void)in_sizes; (void)n_in; (void)out_size; (void)ws_size;
    const float* x      = (const float*)d_in[0];
    const float* mask   = (const float*)d_in[1];
    const float* flow   = (const float*)d_in[2];
    const float* W_in   = (const float*)d_in[3];
    const float* b_in   = (const float*)d_in[4];
    const float* W_mix  = (const float*)d_in[5];
    const float* b_mix  = (const float*)d_in[6];
    const float* lam_raw= (const float*)d_in[7];
    const float* Wgb    = (const float*)d_in[8];
    const float* bgb    = (const float*)d_in[9];
    const float* Wg     = (const float*)d_in[10];
    const float* bg     = (const float*)d_in[11];

    unsigned short* z_bf = (unsigned short*)d_ws;                 // 8388608 ushort
    unsigned short* s_bf = z_bf + (size_t)BB * HD * LL;           // 8388608 ushort
    float* film_ws   = (float*)(s_bf + (size_t)BB * HD * LL);     // 16384
    float* gate_ws   = film_ws + BB * 4 * 256;                    // 64
    float* lam_ws    = gate_ws + 64;                              // 8192
    float* pool_part = lam_ws + BB * 4 * 128;                     // 16*64*128 = 131072
    unsigned short* Bmix = (unsigned short*)(pool_part + BB * 64 * HD);  // 16384 ushort

    float* out = (float*)d_out;

    hipLaunchKernelGGL(zproj_kernel, dim3(BB * 64 + 128), dim3(256), 0, stream,
                       x, mask, W_in, b_in, z_bf,
                       W_mix, Bmix, flow, Wgb, bgb, Wg, bg, film_ws, gate_ws);
    hipLaunchKernelGGL(wavelet_kernel, dim3(BB * HD), dim3(256), 0, stream,
                       z_bf, s_bf, film_ws, gate_ws, lam_raw, lam_ws);
    hipLaunchKernelGGL(mix_kernel, dim3(BB * (LL / 64)), dim3(256), 0, stream,
                       s_bf, Bmix, b_mix, mask, out, pool_part);
    hipLaunchKernelGGL(finalize_kernel, dim3(BB), dim3(256), 0, stream,
                       pool_part, mask, lam_ws, out);
}

// Round 9
// 66.701 us; speedup vs baseline: 2.4764x; 1.0360x over previous
//
#include <hip/hip_runtime.h>
#include <math.h>

#define BB 16
#define LL 4096
#define CC 64
#define HD 128

typedef __attribute__((ext_vector_type(8))) short short8;
typedef __attribute__((ext_vector_type(8))) unsigned short ushort8;
typedef __attribute__((ext_vector_type(4))) float floatx4;

__constant__ float c_lo[8] = {
    -0.010597401784997278f, 0.032883011666982945f, 0.030841381835986965f,
    -0.18703481171888114f, -0.02798376941698385f, 0.6308807679295904f,
    0.7148465705525415f, 0.23037781330885523f};
__constant__ float c_hi[8] = {
    -0.23037781330885523f, 0.7148465705525415f, -0.6308807679295904f,
    -0.02798376941698385f, 0.18703481171888114f, 0.030841381835986965f,
    -0.032883011666982945f, -0.010597401784997278f};

// tanh-GELU in sigmoid form, max abs err vs erf-GELU ~3e-4
__device__ __forceinline__ float gelu_fast(float x) {
    float u = x * fmaf(0.044715f * x, x, 1.0f) * 1.5957691216057308f;
    return x / (1.0f + __expf(-u));
}
__device__ __forceinline__ unsigned short f2b(float f) {   // f32 -> bf16 RNE
    unsigned int u = __float_as_uint(f);
    u = u + 0x7FFFu + ((u >> 16) & 1u);
    return (unsigned short)(u >> 16);
}
__device__ __forceinline__ float b2f(unsigned short s) {
    return __uint_as_float(((unsigned int)s) << 16);
}

// ---------------- zproj (+ fused pack blocks for Bmix / FiLM) ----------------
// Operand-swapped MFMA: D[l][h] -> 8x ushort4 stores.

__global__ __launch_bounds__(256) void zproj_kernel(
    const float* __restrict__ x, const float* __restrict__ mask,
    const float* __restrict__ W_in, const float* __restrict__ b_in,
    unsigned short* __restrict__ z_bf,
    const float* __restrict__ W_mix, unsigned short* __restrict__ Bmix,
    const float* __restrict__ flow, const float* __restrict__ Wgb,
    const float* __restrict__ bgb, const float* __restrict__ Wg,
    const float* __restrict__ bg, float* __restrict__ film_ws,
    float* __restrict__ gate_ws) {
    int blk = blockIdx.x;
    int tid = threadIdx.x;

    if (blk >= BB * 64) {
        int e = blk - BB * 64;
        if (e < 64) {                               // Bmix pack: idx = ((h>>3)*128+g)*8+(h&7)
            int q = e * 256 + tid;                  // 16384
            int g = (q >> 3) & 127;
            int h = ((q >> 10) << 3) | (q & 7);
            Bmix[q] = f2b(W_mix[g * HD + h]);
        } else {                                    // FiLM
            int bf = e - 64;                        // b*4 + f
            int f = bf & 3;
            int b = bf >> 2;
            const float* fl = flow + b * 24;
            const float* wrow = Wgb + ((size_t)(f * 256 + tid)) * 24;
            float acc = bgb[f * 256 + tid];
#pragma unroll
            for (int j = 0; j < 24; ++j) acc = fmaf(wrow[j], fl[j], acc);
            film_ws[(size_t)bf * 256 + tid] = acc;
            if (tid == 0) {
                float g = bg[f];
#pragma unroll
                for (int j = 0; j < 24; ++j) g = fmaf(Wg[f * 24 + j], fl[j], g);
                gate_ws[bf] = 1.0f / (1.0f + expf(-g));
            }
        }
        return;
    }

    int b = blk >> 6;
    int l0 = (blk & 63) << 6;
    int lane = tid & 63;
    int w = tid >> 6;
    int h_half = w >> 1;
    int l_q = w & 1;
    int ln15 = lane & 15, lq4 = lane >> 4;

    int lr0 = l0 + l_q * 32 + ln15;
    int lr1 = lr0 + 16;
    float mk0 = mask[(size_t)b * LL + lr0];
    float mk1 = mask[(size_t)b * LL + lr1];

    floatx4 acc[4][2];
#pragma unroll
    for (int i = 0; i < 4; ++i)
#pragma unroll
        for (int j = 0; j < 2; ++j) acc[i][j] = (floatx4){0.f, 0.f, 0.f, 0.f};

#pragma unroll
    for (int ks = 0; ks < 2; ++ks) {
        int c0 = ks * 32 + (lq4 << 3);
        short8 bf0, bf1;
        {
            const float* xp = x + ((size_t)b * LL + lr0) * CC + c0;
            float4 xa = *(const float4*)xp;
            float4 xb = *(const float4*)(xp + 4);
            bf0[0] = (short)f2b(xa.x * mk0); bf0[1] = (short)f2b(xa.y * mk0);
            bf0[2] = (short)f2b(xa.z * mk0); bf0[3] = (short)f2b(xa.w * mk0);
            bf0[4] = (short)f2b(xb.x * mk0); bf0[5] = (short)f2b(xb.y * mk0);
            bf0[6] = (short)f2b(xb.z * mk0); bf0[7] = (short)f2b(xb.w * mk0);
        }
        {
            const float* xp = x + ((size_t)b * LL + lr1) * CC + c0;
            float4 xa = *(const float4*)xp;
            float4 xb = *(const float4*)(xp + 4);
            bf1[0] = (short)f2b(xa.x * mk1); bf1[1] = (short)f2b(xa.y * mk1);
            bf1[2] = (short)f2b(xa.z * mk1); bf1[3] = (short)f2b(xa.w * mk1);
            bf1[4] = (short)f2b(xb.x * mk1); bf1[5] = (short)f2b(xb.y * mk1);
            bf1[6] = (short)f2b(xb.z * mk1); bf1[7] = (short)f2b(xb.w * mk1);
        }
        const float* wb = W_in + (size_t)(h_half * 64 + ln15) * CC + c0;
#pragma unroll
        for (int ht = 0; ht < 4; ++ht) {
            const float* wr = wb + (size_t)ht * 16 * CC;
            float4 wa = *(const float4*)wr;
            float4 wc = *(const float4*)(wr + 4);
            short8 af;
            af[0] = (short)f2b(wa.x); af[1] = (short)f2b(wa.y);
            af[2] = (short)f2b(wa.z); af[3] = (short)f2b(wa.w);
            af[4] = (short)f2b(wc.x); af[5] = (short)f2b(wc.y);
            af[6] = (short)f2b(wc.z); af[7] = (short)f2b(wc.w);
            acc[ht][0] = __builtin_amdgcn_mfma_f32_16x16x32_bf16(bf0, af, acc[ht][0], 0, 0, 0);
            acc[ht][1] = __builtin_amdgcn_mfma_f32_16x16x32_bf16(bf1, af, acc[ht][1], 0, 0, 0);
        }
    }

#pragma unroll
    for (int ht = 0; ht < 4; ++ht) {
        int h = h_half * 64 + ht * 16 + ln15;        // fixed per lane
        float bi = b_in[h];
        unsigned short* zr = z_bf + ((size_t)(b * HD + h)) * LL;
#pragma unroll
        for (int j = 0; j < 2; ++j) {
            int lbase = l0 + l_q * 32 + j * 16 + (lq4 << 2);
            ushort4 o;
            o.x = f2b(acc[ht][j][0] + bi);
            o.y = f2b(acc[ht][j][1] + bi);
            o.z = f2b(acc[ht][j][2] + bi);
            o.w = f2b(acc[ht][j][3] + bi);
            *(ushort4*)(zr + lbase) = o;
        }
    }
}

// ---------------- wavelet helpers ----------------

__device__ __forceinline__ void analysis_step(const float* __restrict__ src,
                                              float* __restrict__ lo_dst,
                                              float* __restrict__ hi_dst,
                                              int half, int tid) {
    int len = half << 1;
    for (int q = tid; q < (half >> 2); q += 256) {
        int n0 = q << 2;
        float lo[4], hi[4];
        if (n0 + 4 == half) {                       // only quad that wraps
#pragma unroll
            for (int i = 0; i < 4; ++i) {
                float l = 0.f, hh = 0.f;
#pragma unroll
                for (int k = 0; k < 8; ++k) {
                    float v = src[(2 * (n0 + i) + k) & (len - 1)];
                    l = fmaf(c_lo[k], v, l);
                    hh = fmaf(c_hi[k], v, hh);
                }
                lo[i] = l; hi[i] = hh;
            }
        } else {
            float sv[16];
            const float* sp = src + (n0 << 1);
            *(float4*)&sv[0]  = *(const float4*)(sp);
            *(float4*)&sv[4]  = *(const float4*)(sp + 4);
            *(float4*)&sv[8]  = *(const float4*)(sp + 8);
            *(float4*)&sv[12] = *(const float4*)(sp + 12);
#pragma unroll
            for (int i = 0; i < 4; ++i) {
                float l = 0.f, hh = 0.f;
#pragma unroll
                for (int k = 0; k < 8; ++k) {
                    l = fmaf(c_lo[k], sv[2 * i + k], l);
                    hh = fmaf(c_hi[k], sv[2 * i + k], hh);
                }
                lo[i] = l; hi[i] = hh;
            }
        }
        *(float4*)&lo_dst[n0] = make_float4(lo[0], lo[1], lo[2], lo[3]);
        *(float4*)&hi_dst[n0] = make_float4(hi[0], hi[1], hi[2], hi[3]);
    }
}

__device__ __forceinline__ void synth_oct(const float* __restrict__ A,
                                          const float* __restrict__ D,
                                          int m0, int half, float* ov) {
    if (m0 == 0) {                                  // only oct that wraps (backward)
        int mask2 = (half << 1) - 1;
#pragma unroll
        for (int t = 0; t < 8; ++t) {
            int par = t & 1;
            float s = 0.f;
#pragma unroll
            for (int j = 0; j < 4; ++j) {
                int k = 2 * j + par;
                int idx = ((t - k) & mask2) >> 1;
                s = fmaf(c_lo[k], A[idx], s);
                s = fmaf(c_hi[k], D[idx], s);
            }
            ov[t] = s;
        }
    } else {
        float av[8], dv[8];
        *(float4*)&av[0] = *(const float4*)(A + m0 - 4);
        *(float4*)&av[4] = *(const float4*)(A + m0);
        *(float4*)&dv[0] = *(const float4*)(D + m0 - 4);
        *(float4*)&dv[4] = *(const float4*)(D + m0);
#pragma unroll
        for (int t = 0; t < 4; ++t) {
            float e = 0.f, o = 0.f;
#pragma unroll
            for (int j = 0; j < 4; ++j) {
                float xa = av[t + 4 - j], xd = dv[t + 4 - j];
                e = fmaf(c_lo[2 * j], xa, e);     e = fmaf(c_hi[2 * j], xd, e);
                o = fmaf(c_lo[2 * j + 1], xa, o); o = fmaf(c_hi[2 * j + 1], xd, o);
            }
            ov[2 * t] = e;
            ov[2 * t + 1] = o;
        }
    }
}

__device__ __forceinline__ void synth_step(const float* __restrict__ A,
                                           const float* __restrict__ D,
                                           float* __restrict__ dst,
                                           int half, int tid) {
    for (int q = tid; q < (half >> 2); q += 256) {
        int m0 = q << 2;
        int i0 = m0 << 1;
        float ov[8];
        synth_oct(A, D, m0, half, ov);
        *(float4*)&dst[i0]     = make_float4(ov[0], ov[1], ov[2], ov[3]);
        *(float4*)&dst[i0 + 4] = make_float4(ov[4], ov[5], ov[6], ov[7]);
    }
}

// ---------------- per-row wavelet: 24 KB LDS (6 blocks/CU), direct-global z reads ----------------

__global__ __launch_bounds__(256) void wavelet_kernel(const unsigned short* __restrict__ z_bf,
                                                      unsigned short* __restrict__ s_bf,
                                                      const float* __restrict__ film_ws,
                                                      const float* __restrict__ gate_ws,
                                                      const float* __restrict__ lam_raw,
                                                      float* __restrict__ lam_ws) {
    __shared__ float d1[2048];           // 8 KB
    __shared__ float d2[1024];           // 4 KB
    __shared__ float Aq[2048];           // 8 KB (a1 -> a3[0:512]+d3[512:1024] -> recon2048)
    __shared__ float Bq[1024];           // 4 KB (a2 -> reduce scratch -> recon1024)

    int blk = blockIdx.x;
    int b = blk >> 7;
    int h = blk & 127;
    int tid = threadIdx.x;
    const unsigned short* zg = z_bf + ((size_t)(b * HD + h)) * LL;
    unsigned short* sg = s_bf + ((size_t)(b * HD + h)) * LL;

    // L1 analysis straight from global bf16 (each quad reads a disjoint 32B slice)
    for (int q = tid; q < 512; q += 256) {
        int n0 = q << 2;
        float sv[16];
        if (n0 == 2044) {                           // the wrapping quad
#pragma unroll
            for (int j = 0; j < 14; ++j)
                sv[j] = b2f(zg[(2 * n0 + j) & 4095]);
            sv[14] = 0.f; sv[15] = 0.f;
        } else {
            ushort8 va = *(const ushort8*)(zg + (n0 << 1));
            ushort8 vb = *(const ushort8*)(zg + (n0 << 1) + 8);
#pragma unroll
            for (int j = 0; j < 8; ++j) {
                sv[j]     = b2f(va[j]);
                sv[8 + j] = b2f(vb[j]);
            }
        }
        float lo[4], hi[4];
#pragma unroll
        for (int i = 0; i < 4; ++i) {
            float l = 0.f, hh = 0.f;
#pragma unroll
            for (int k = 0; k < 8; ++k) {
                l = fmaf(c_lo[k], sv[2 * i + k], l);
                hh = fmaf(c_hi[k], sv[2 * i + k], hh);
            }
            lo[i] = l; hi[i] = hh;
        }
        *(float4*)&Aq[n0] = make_float4(lo[0], lo[1], lo[2], lo[3]);
        *(float4*)&d1[n0] = make_float4(hi[0], hi[1], hi[2], hi[3]);
    }
    __syncthreads();
    analysis_step(Aq, Bq, d2, 1024, tid);        // L2
    __syncthreads();
    analysis_step(Bq, Aq, Aq + 512, 512, tid);   // L3
    __syncthreads();

    float sc0, sh0, sc1, sh1, sc2, sh2, sc3, sh3;
    {
        int base = b * 4;
#define FILM_COEF(bd, SC, SH)                                              \
        {   float ga = film_ws[((size_t)(base + bd)) * 256 + h];           \
            float be = film_ws[((size_t)(base + bd)) * 256 + 128 + h];     \
            float gt = gate_ws[base + bd];                                 \
            SC = 1.0f + gt * ga; SH = gt * be; }
        FILM_COEF(0, sc0, sh0) FILM_COEF(1, sc1, sh1)
        FILM_COEF(2, sc2, sh2) FILM_COEF(3, sc3, sh3)
#undef FILM_COEF
    }

    float* p0 = &Aq[tid << 2];
    float* p1 = &d1[tid << 2];
    float* p2 = &d1[1024 + (tid << 2)];
    float* p3 = &d2[tid << 2];
    bool lowhalf = (tid < 128);
    float scA = lowhalf ? sc0 : sc3, shA = lowhalf ? sh0 : sh3;

    float4 f0 = *(float4*)p0, f1 = *(float4*)p1, f2v = *(float4*)p2, f3 = *(float4*)p3;
#define FILMV(V, SC, SH)                                                   \
    { V.x = fmaf(V.x, SC, SH); V.y = fmaf(V.y, SC, SH);                    \
      V.z = fmaf(V.z, SC, SH); V.w = fmaf(V.w, SC, SH); }
    FILMV(f0, scA, shA) FILMV(f1, sc1, sh1) FILMV(f2v, sc1, sh1) FILMV(f3, sc2, sh2)
#undef FILMV
    float sA = fabsf(f0.x) + fabsf(f0.y) + fabsf(f0.z) + fabsf(f0.w);
    float s1 = fabsf(f1.x) + fabsf(f1.y) + fabsf(f1.z) + fabsf(f1.w)
             + fabsf(f2v.x) + fabsf(f2v.y) + fabsf(f2v.z) + fabsf(f2v.w);
    float s2 = fabsf(f3.x) + fabsf(f3.y) + fabsf(f3.z) + fabsf(f3.w);
#pragma unroll
    for (int off = 32; off > 0; off >>= 1) {
        sA += __shfl_xor(sA, off);
        s1 += __shfl_xor(s1, off);
        s2 += __shfl_xor(s2, off);
    }
    if ((tid & 63) == 0)
        ((float4*)Bq)[tid >> 6] = make_float4(lowhalf ? sA : 0.f, s1, s2,
                                              lowhalf ? 0.f : sA);
    __syncthreads();
    float4 r0 = ((const float4*)Bq)[0];
    float4 r1 = ((const float4*)Bq)[1];
    float4 r2 = ((const float4*)Bq)[2];
    float4 r3 = ((const float4*)Bq)[3];
    float lam0 = log1pf(expf(lam_raw[0])) * ((r0.x + r1.x + r2.x + r3.x) * (1.0f / 512.f));
    float lam1 = log1pf(expf(lam_raw[1])) * ((r0.y + r1.y + r2.y + r3.y) * (1.0f / 2048.f));
    float lam2 = log1pf(expf(lam_raw[2])) * ((r0.z + r1.z + r2.z + r3.z) * (1.0f / 1024.f));
    float lam3 = log1pf(expf(lam_raw[3])) * ((r0.w + r1.w + r2.w + r3.w) * (1.0f / 512.f));
    if (tid < 4) {
        float lam = (tid == 0) ? lam0 : (tid == 1) ? lam1 : (tid == 2) ? lam2 : lam3;
        lam_ws[((size_t)(b * 4 + tid)) * 128 + h] = lam;
    }
    float lamA = lowhalf ? lam0 : lam3;
#define THRV(V, LAM)                                                       \
    { float a;                                                             \
      a = fabsf(V.x) - (LAM); V.x = (a > 0.f) ? copysignf(a, V.x) : 0.f;   \
      a = fabsf(V.y) - (LAM); V.y = (a > 0.f) ? copysignf(a, V.y) : 0.f;   \
      a = fabsf(V.z) - (LAM); V.z = (a > 0.f) ? copysignf(a, V.z) : 0.f;   \
      a = fabsf(V.w) - (LAM); V.w = (a > 0.f) ? copysignf(a, V.w) : 0.f; }
    THRV(f0, lamA) THRV(f1, lam1) THRV(f2v, lam1) THRV(f3, lam2)
#undef THRV
    *(float4*)p0 = f0; *(float4*)p1 = f1; *(float4*)p2 = f2v; *(float4*)p3 = f3;
    __syncthreads();

    synth_step(Aq, Aq + 512, Bq, 512, tid);      // R1 -> Bq[0:1024]
    __syncthreads();
    synth_step(Bq, d2, Aq, 1024, tid);           // R2 -> Aq[0:2048]
    __syncthreads();
    for (int q = tid; q < 512; q += 256) {       // R3 + residual (global re-read) + store
        int m0 = q << 2;
        int i0 = m0 << 1;
        float ov[8];
        synth_oct(Aq, d1, m0, 2048, ov);
        ushort8 zin = *(const ushort8*)(zg + i0);
        ushort8 o8;
#pragma unroll
        for (int t = 0; t < 8; ++t) o8[t] = f2b(ov[t] + b2f(zin[t]));
        *(ushort8*)(sg + i0) = o8;
    }
}

// ---------------- mix: operand-swapped MFMA -> D[g][l], float4 out stores ----------------

union U32x4S8 { unsigned int u[4]; short8 s; };

__global__ __launch_bounds__(256) void mix_kernel(const unsigned short* __restrict__ s_bf,
                                                  const unsigned short* __restrict__ Bmix,
                                                  const float* __restrict__ b_mix,
                                                  const float* __restrict__ mask,
                                                  float* __restrict__ out,
                                                  float* __restrict__ pool_part) {
    __shared__ unsigned int T[HD * 32];   // 16 KB, [h][lp ^ (h&31)]
    __shared__ float pbuf[2][HD];

    int blk = blockIdx.x;
    int b = blk >> 6;
    int lt64 = blk & 63;
    int l0 = lt64 << 6;
    int tid = threadIdx.x;
    int lane = tid & 63;
    int w = tid >> 6;
    int l_half = w >> 1, g_half = w & 1;
    int ln15 = lane & 15, lq4 = lane >> 4;

    {
        const unsigned int* src = (const unsigned int*)s_bf;
#pragma unroll
        for (int r = 0; r < 4; ++r) {
            int q = (r << 8) + tid;              // 0..1023
            int hh = q >> 3;                     // 0..127
            int k = q & 7;                       // 16B chunk
            uint4 v = *(const uint4*)(src + (size_t)(b * HD + hh) * (LL / 2) +
                                      (l0 >> 1) + (k << 2));
            int sw = hh & 31;
            unsigned int* tp = T + hh * 32;
            tp[((k << 2) + 0) ^ sw] = v.x;
            tp[((k << 2) + 1) ^ sw] = v.y;
            tp[((k << 2) + 2) ^ sw] = v.z;
            tp[((k << 2) + 3) ^ sw] = v.w;
        }
    }
    __syncthreads();

    floatx4 acc[2][4];
#pragma unroll
    for (int i = 0; i < 2; ++i)
#pragma unroll
        for (int j = 0; j < 4; ++j) acc[i][j] = (floatx4){0.f, 0.f, 0.f, 0.f};

    const unsigned short* Bb = Bmix + (g_half * 64 + ln15) * 8;

#pragma unroll 2
    for (int ks = 0; ks < 4; ++ks) {
        int koct = ks * 4 + lq4;
        short8 a[2], bb[4];
#pragma unroll
        for (int lt = 0; lt < 2; ++lt) {
            int l_loc = l_half * 32 + lt * 16 + ln15;
            int lp = l_loc >> 1;
            int odd = l_loc & 1;
            U32x4S8 cv;
#pragma unroll
            for (int qq = 0; qq < 4; ++qq) {
                int h0 = koct * 8 + 2 * qq;
                unsigned int w0 = T[h0 * 32 + (lp ^ (h0 & 31))];
                unsigned int w1 = T[(h0 + 1) * 32 + (lp ^ ((h0 + 1) & 31))];
                unsigned int e0 = odd ? (w0 >> 16) : (w0 & 0xffffu);
                unsigned int e1 = odd ? (w1 >> 16) : (w1 & 0xffffu);
                cv.u[qq] = e0 | (e1 << 16);
            }
            a[lt] = cv.s;
        }
#pragma unroll
        for (int gt = 0; gt < 4; ++gt)
            bb[gt] = *(const short8*)(Bb + (size_t)koct * 1024 + gt * 128);
        // swapped operands: D[g][l]
#pragma unroll
        for (int lt = 0; lt < 2; ++lt)
#pragma unroll
            for (int gt = 0; gt < 4; ++gt)
                acc[lt][gt] = __builtin_amdgcn_mfma_f32_16x16x32_bf16(bb[gt], a[lt], acc[lt][gt], 0, 0, 0);
    }

    // epilogue: lane = fixed l (ln15), regs = 4 consecutive g
    float4 pacc4[4];
#pragma unroll
    for (int gt = 0; gt < 4; ++gt) pacc4[gt] = make_float4(0.f, 0.f, 0.f, 0.f);

#pragma unroll
    for (int lt = 0; lt < 2; ++lt) {
        int l = l0 + l_half * 32 + lt * 16 + ln15;
        float mkv = mask[(size_t)b * LL + l];
        float* orow = out + ((size_t)b * LL + l) * HD;
#pragma unroll
        for (int gt = 0; gt < 4; ++gt) {
            int g0q = g_half * 64 + gt * 16 + (lq4 << 2);
            float4 bm = *(const float4*)&b_mix[g0q];
            float4 v;
            v.x = gelu_fast(acc[lt][gt][0] + bm.x) * mkv;
            v.y = gelu_fast(acc[lt][gt][1] + bm.y) * mkv;
            v.z = gelu_fast(acc[lt][gt][2] + bm.z) * mkv;
            v.w = gelu_fast(acc[lt][gt][3] + bm.w) * mkv;
            *(float4*)&orow[g0q] = v;
            pacc4[gt].x = fmaf(v.x, mkv, pacc4[gt].x);
            pacc4[gt].y = fmaf(v.y, mkv, pacc4[gt].y);
            pacc4[gt].z = fmaf(v.z, mkv, pacc4[gt].z);
            pacc4[gt].w = fmaf(v.w, mkv, pacc4[gt].w);
        }
    }
    // reduce over the 16 l-lanes (ln15 groups)
#pragma unroll
    for (int gt = 0; gt < 4; ++gt) {
#pragma unroll
        for (int off = 1; off <= 8; off <<= 1) {
            pacc4[gt].x += __shfl_xor(pacc4[gt].x, off);
            pacc4[gt].y += __shfl_xor(pacc4[gt].y, off);
            pacc4[gt].z += __shfl_xor(pacc4[gt].z, off);
            pacc4[gt].w += __shfl_xor(pacc4[gt].w, off);
        }
    }
    if (ln15 == 0) {
#pragma unroll
        for (int gt = 0; gt < 4; ++gt)
            *(float4*)&pbuf[l_half][g_half * 64 + gt * 16 + (lq4 << 2)] = pacc4[gt];
    }
    __syncthreads();
    if (tid < HD)
        pool_part[((size_t)(b * 64 + lt64)) * HD + tid] = pbuf[0][tid] + pbuf[1][tid];
}

// ---------------- finalize: denom + pool + lam mean/max ----------------

__global__ void finalize_kernel(const float* __restrict__ pool_part,
                                const float* __restrict__ mask,
                                const float* __restrict__ lam_ws,
                                float* __restrict__ d_out) {
    const size_t OUT1 = (size_t)BB * LL * HD;
    const size_t OUT2 = OUT1 + (size_t)BB * HD;
    const size_t OUT3 = OUT2 + BB;
    int b = blockIdx.x, tid = threadIdx.x;
    __shared__ float rsum[256], rmax[256];
    __shared__ float dsh;

    float ms = 0.f;
    const float4* mp = (const float4*)(mask + (size_t)b * LL);
    for (int i = tid; i < LL / 4; i += 256) {
        float4 m = mp[i];
        ms += m.x + m.y + m.z + m.w;
    }
    rsum[tid] = ms; __syncthreads();
    for (int st = 128; st > 0; st >>= 1) {
        if (tid < st) rsum[tid] += rsum[tid + st];
        __syncthreads();
    }
    if (tid == 0) dsh = fmaxf(rsum[0], 1.0f);
    __syncthreads();
    float denom = dsh;
    __syncthreads();

    // pool: 256 threads = 128 h x 2 halves (coalesced h-major reads, 32-deep chains)
    {
        int hh = tid & 127, half = tid >> 7;
        float s = 0.f;
        for (int blk = half * 32; blk < half * 32 + 32; ++blk)
            s += pool_part[((size_t)(b * 64 + blk)) * HD + hh];
        rsum[tid] = s;
        __syncthreads();
        if (tid < 128)
            d_out[OUT1 + (size_t)b * HD + tid] = (rsum[tid] + rsum[tid + 128]) / denom;
        __syncthreads();
    }

    float v0 = lam_ws[(size_t)b * 512 + tid];
    float v1 = lam_ws[(size_t)b * 512 + 256 + tid];
    rsum[tid] = v0 + v1;
    rmax[tid] = fmaxf(v0, v1);
    __syncthreads();
    for (int st = 128; st > 0; st >>= 1) {
        if (tid < st) {
            rsum[tid] += rsum[tid + st];
            rmax[tid] = fmaxf(rmax[tid], rmax[tid + st]);
        }
        __syncthreads();
    }
    if (tid == 0) {
        d_out[OUT2 + b] = rsum[0] / 512.0f;
        d_out[OUT3 + b] = rmax[0];
    }
}

// ---------------- launch ----------------

extern "C" void kernel_launch(void* const* d_in, const int* in_sizes, int n_in,
                              void* d_out, int out_size, void* d_ws, size_t ws_size,
                              hipStream_t stream) {
    (void)in_sizes; (void)n_in; (void)out_size; (void)ws_size;
    const float* x      = (const float*)d_in[0];
    const float* mask   = (const float*)d_in[1];
    const float* flow   = (const float*)d_in[2];
    const float* W_in   = (const float*)d_in[3];
    const float* b_in   = (const float*)d_in[4];
    const float* W_mix  = (const float*)d_in[5];
    const float* b_mix  = (const float*)d_in[6];
    const float* lam_raw= (const float*)d_in[7];
    const float* Wgb    = (const float*)d_in[8];
    const float* bgb    = (const float*)d_in[9];
    const float* Wg     = (const float*)d_in[10];
    const float* bg     = (const float*)d_in[11];

    unsigned short* z_bf = (unsigned short*)d_ws;                 // 8388608 ushort
    unsigned short* s_bf = z_bf + (size_t)BB * HD * LL;           // 8388608 ushort
    float* film_ws   = (float*)(s_bf + (size_t)BB * HD * LL);     // 16384
    float* gate_ws   = film_ws + BB * 4 * 256;                    // 64
    float* lam_ws    = gate_ws + 64;                              // 8192
    float* pool_part = lam_ws + BB * 4 * 128;                     // 16*64*128 = 131072
    unsigned short* Bmix = (unsigned short*)(pool_part + BB * 64 * HD);  // 16384 ushort

    float* out = (float*)d_out;

    hipLaunchKernelGGL(zproj_kernel, dim3(BB * 64 + 128), dim3(256), 0, stream,
                       x, mask, W_in, b_in, z_bf,
                       W_mix, Bmix, flow, Wgb, bgb, Wg, bg, film_ws, gate_ws);
    hipLaunchKernelGGL(wavelet_kernel, dim3(BB * HD), dim3(256), 0, stream,
                       z_bf, s_bf, film_ws, gate_ws, lam_raw, lam_ws);
    hipLaunchKernelGGL(mix_kernel, dim3(BB * (LL / 64)), dim3(256), 0, stream,
                       s_bf, Bmix, b_mix, mask, out, pool_part);
    hipLaunchKernelGGL(finalize_kernel, dim3(BB), dim3(256), 0, stream,
                       pool_part, mask, lam_ws, out);
}